// Round 8
// baseline (306.986 us; speedup 1.0000x reference)
//
#include <hip/hip_runtime.h>
#include <hip/hip_bf16.h>
#include <cstdint>
#include <cstddef>

#define AS1 __attribute__((address_space(1)))
#define AS3 __attribute__((address_space(3)))

typedef __attribute__((ext_vector_type(8))) short bf16x8;
typedef __attribute__((ext_vector_type(4))) float f32x4;

__device__ __forceinline__ void gload_lds16(const void* g, void* l) {
  __builtin_amdgcn_global_load_lds((const AS1 void*)g, (AS3 void*)l, 16, 0, 0);
}

#define MFMA_BF16(A, B, C) __builtin_amdgcn_mfma_f32_16x16x32_bf16((A), (B), (C), 0, 0, 0)

// (1/sqrt(128)) * log2(e) — folded into q at rope time; softmax runs in exp2 domain.
#define QSCALE 0.12751744f

__device__ __forceinline__ uint32_t pk2(float a, float b) {
  uint32_t ua = (uint32_t)__builtin_bit_cast(unsigned short, __float2bfloat16(a));
  uint32_t ub = (uint32_t)__builtin_bit_cast(unsigned short, __float2bfloat16(b));
  return ua | (ub << 16);
}
__device__ __forceinline__ float b2f(unsigned short u) {
  return __builtin_bit_cast(float, (uint32_t)u << 16);
}

// ---------------- cast f32 -> bf16 ----------------
__global__ __launch_bounds__(256) void cast_bf16_kernel(const float* __restrict__ in,
                                                        __hip_bfloat16* __restrict__ out,
                                                        int n4) {
  int i = blockIdx.x * 256 + threadIdx.x;
  if (i < n4) {
    float4 v = ((const float4*)in)[i];
    __hip_bfloat16* o = out + (size_t)i * 4;
    o[0] = __float2bfloat16(v.x);
    o[1] = __float2bfloat16(v.y);
    o[2] = __float2bfloat16(v.z);
    o[3] = __float2bfloat16(v.w);
  }
}

// ---------------- merged weight transpose+cast (Wq,Wk,Wv,Wp in one launch) ----------------
__global__ __launch_bounds__(256) void wtrans_kernel(const float* __restrict__ Wq,
                                                     const float* __restrict__ Wk,
                                                     const float* __restrict__ Wv,
                                                     const float* __restrict__ Wp,
                                                     __hip_bfloat16* __restrict__ WTa,
                                                     __hip_bfloat16* __restrict__ WpT) {
  __shared__ float tile[32][33];
  int id = blockIdx.x;
  const float* in; __hip_bfloat16* out; int is, os, bx, by;
  if (id < 4096)      { in = Wq; out = WTa;                          is = 2048; os = 2048; bx = id & 63; by = id >> 6; }
  else if (id < 5120) { int t = id - 4096; in = Wk; out = WTa + (size_t)2048 * 2048; is = 512; os = 2048; bx = t & 15; by = t >> 4; }
  else if (id < 6144) { int t = id - 5120; in = Wv; out = WTa + (size_t)2560 * 2048; is = 512; os = 2048; bx = t & 15; by = t >> 4; }
  else                { int t = id - 6144; in = Wp; out = WpT;       is = 2048; os = 2048; bx = t & 63; by = t >> 6; }
  int c0 = bx * 32, r0 = by * 32;
  int tx = threadIdx.x, ty = threadIdx.y;
#pragma unroll
  for (int i = 0; i < 32; i += 8)
    tile[ty + i][tx] = in[(size_t)(r0 + ty + i) * is + c0 + tx];
  __syncthreads();
#pragma unroll
  for (int i = 0; i < 32; i += 8)
    out[(size_t)(c0 + ty + i) * os + r0 + tx] = __float2bfloat16(tile[tx][ty + i]);
}

// ---------------- qkv GEMM with fused RoPE+RMS epilogue ----------------
// C(4096x3072) = xb @ WTa^T, tile 128x128; col tile == one head.
// q/k tiles: acc -> LDS bf16 [128][136] -> rope+rms -> qT/kT (q gets QSCALE).
// v tiles: acc -> vtb (B,HK,HD,T) directly (transposed packed stores).
__global__ __launch_bounds__(256) void gemm_qkv_rope_kernel(
    const __hip_bfloat16* __restrict__ A,
    const __hip_bfloat16* __restrict__ Bt,
    const float* __restrict__ cosb,
    const float* __restrict__ sinb,
    __hip_bfloat16* __restrict__ qT,
    __hip_bfloat16* __restrict__ kT,
    __hip_bfloat16* __restrict__ vt) {
  __shared__ __align__(16) char smem[34816];          // As|Bs during loop; CL after
  __hip_bfloat16* As = (__hip_bfloat16*)smem;
  __hip_bfloat16* Bs = (__hip_bfloat16*)(smem + 8192);
  __hip_bfloat16* CL = (__hip_bfloat16*)smem;         // [128][136]
  const int K = 2048;
  const int tid = threadIdx.x;
  const int lane = tid & 63;
  const int wid = tid >> 6;
  const int wm = wid >> 1, wn = wid & 1;
  const int nwg = gridDim.x;
  const int bid = blockIdx.x;
  const int swz = (bid & 7) * (nwg >> 3) + (bid >> 3);
  const int tm = swz / 24, tn = swz % 24;
  const int row0 = tm << 7, col0 = tn << 7;
  const int fr = lane & 15;
  const int kg = (lane >> 4) * 8;

  f32x4 acc[4][4] = {};
  for (int k0 = 0; k0 < K; k0 += 32) {
    __syncthreads();
#pragma unroll
    for (int i = 0; i < 2; ++i) {
      int f = i * 256 + tid;
      int r = f >> 2, s = f & 3;
      gload_lds16(A + (size_t)(row0 + r) * K + k0 + s * 8,
                  (char*)As + (i * 256 + wid * 64) * 16);
      gload_lds16(Bt + (size_t)(col0 + r) * K + k0 + s * 8,
                  (char*)Bs + (i * 256 + wid * 64) * 16);
    }
    __syncthreads();
    bf16x8 af[4], bfr[4];
#pragma unroll
    for (int m = 0; m < 4; ++m)
      af[m] = *(const bf16x8*)(As + (wm * 64 + m * 16 + fr) * 32 + kg);
#pragma unroll
    for (int n = 0; n < 4; ++n)
      bfr[n] = *(const bf16x8*)(Bs + (wn * 64 + n * 16 + fr) * 32 + kg);
#pragma unroll
    for (int m = 0; m < 4; ++m)
#pragma unroll
      for (int n = 0; n < 4; ++n)
        acc[m][n] = MFMA_BF16(af[m], bfr[n], acc[m][n]);
  }
  __syncthreads();                                    // LDS free for reuse

  const int b = row0 >> 11;
  const int t0 = row0 & 2047;
  const int cr = (lane >> 4) * 4;

  if (col0 >= 2560) {
    // ---- V: direct transposed store to (B,HK,HD,T) ----
    const int hv = (col0 - 2560) >> 7;
    __hip_bfloat16* vb = vt + (size_t)(b * 4 + hv) * 128 * 2048;
#pragma unroll
    for (int m = 0; m < 4; ++m)
#pragma unroll
      for (int n = 0; n < 4; ++n) {
        int d = wn * 64 + n * 16 + fr;
        int t = t0 + wm * 64 + m * 16 + cr;
        *(uint2*)(vb + (size_t)d * 2048 + t) =
            make_uint2(pk2(acc[m][n][0], acc[m][n][1]), pk2(acc[m][n][2], acc[m][n][3]));
      }
    return;
  }

  // ---- q/k: acc -> LDS (bf16) ----
#pragma unroll
  for (int m = 0; m < 4; ++m)
#pragma unroll
    for (int n = 0; n < 4; ++n) {
      int col = wn * 64 + n * 16 + fr;
#pragma unroll
      for (int r = 0; r < 4; ++r)
        CL[(wm * 64 + m * 16 + cr + r) * 136 + col] = __float2bfloat16(acc[m][n][r]);
    }
  __syncthreads();

  // ---- rope + rms: 2 threads per row ----
  const int row = tid >> 1, p = tid & 1;
  const int t = t0 + row;
  const __hip_bfloat16* CLr = CL + row * 136;
  const float* cb = cosb + t * 64;
  const float* sb = sinb + t * 64;
  float ss = 0.f;
#pragma unroll
  for (int c4 = 0; c4 < 4; ++c4) {
    int dd = p * 32 + c4 * 8;
    bf16x8 X1 = *(const bf16x8*)(CLr + dd);
    bf16x8 X2 = *(const bf16x8*)(CLr + 64 + dd);
#pragma unroll
    for (int i = 0; i < 8; ++i) {
      float cc = cb[dd + i], sn = sb[dd + i];
      float x1 = b2f((unsigned short)X1[i]);
      float x2 = b2f((unsigned short)X2[i]);
      float a = x1 * cc - x2 * sn;
      float bb = x1 * sn + x2 * cc;
      ss += a * a + bb * bb;
    }
  }
  ss += __shfl_xor(ss, 1);
  const float oscale = (col0 < 2048) ? QSCALE : 1.0f;
  const float rn = rsqrtf(ss * (1.f / 128.f) + 1e-6f) * oscale;
  __hip_bfloat16* dst;
  if (col0 < 2048) dst = qT + ((size_t)(b * 16 + (col0 >> 7)) * 2048 + t) * 128;
  else             dst = kT + ((size_t)(b * 4 + ((col0 - 2048) >> 7)) * 2048 + t) * 128;
#pragma unroll
  for (int c4 = 0; c4 < 4; ++c4) {
    int dd = p * 32 + c4 * 8;
    bf16x8 X1 = *(const bf16x8*)(CLr + dd);
    bf16x8 X2 = *(const bf16x8*)(CLr + 64 + dd);
    bf16x8 O1, O2;
#pragma unroll
    for (int i = 0; i < 8; ++i) {
      float cc = cb[dd + i], sn = sb[dd + i];
      float x1 = b2f((unsigned short)X1[i]);
      float x2 = b2f((unsigned short)X2[i]);
      O1[i] = (short)__builtin_bit_cast(unsigned short,
                  __float2bfloat16((x1 * cc - x2 * sn) * rn));
      O2[i] = (short)__builtin_bit_cast(unsigned short,
                  __float2bfloat16((x1 * sn + x2 * cc) * rn));
    }
    *(bf16x8*)(dst + dd) = O1;
    *(bf16x8*)(dst + 64 + dd) = O2;
  }
}

// ---------------- generic bf16 GEMM (m97 structure, f32 out) ----------------
__global__ __launch_bounds__(256) void gemm_bf16_kernel(const __hip_bfloat16* __restrict__ A,
                                                        const __hip_bfloat16* __restrict__ Bt,
                                                        float* __restrict__ C,
                                                        int M, int N, int K) {
  __shared__ __align__(16) __hip_bfloat16 As[128 * 32];
  __shared__ __align__(16) __hip_bfloat16 Bs[128 * 32];
  const int tid = threadIdx.x;
  const int lane = tid & 63;
  const int wid = tid >> 6;
  const int wm = wid >> 1, wn = wid & 1;
  const int nwg = gridDim.x;
  const int bid = blockIdx.x;
  const int swz = (bid & 7) * (nwg >> 3) + (bid >> 3);
  const int ntile = N >> 7;
  const int tm = swz / ntile, tn = swz % ntile;
  const int row0 = tm << 7, col0 = tn << 7;

  const int fr = lane & 15;
  const int kg = (lane >> 4) * 8;

  f32x4 acc[4][4] = {};

  for (int k0 = 0; k0 < K; k0 += 32) {
    __syncthreads();
#pragma unroll
    for (int i = 0; i < 2; ++i) {
      int f = i * 256 + tid;
      int r = f >> 2, s = f & 3;
      gload_lds16(A + (size_t)(row0 + r) * K + k0 + s * 8,
                  (char*)As + (i * 256 + wid * 64) * 16);
      gload_lds16(Bt + (size_t)(col0 + r) * K + k0 + s * 8,
                  (char*)Bs + (i * 256 + wid * 64) * 16);
    }
    __syncthreads();
    bf16x8 af[4], bfr[4];
#pragma unroll
    for (int m = 0; m < 4; ++m)
      af[m] = *(const bf16x8*)(As + (wm * 64 + m * 16 + fr) * 32 + kg);
#pragma unroll
    for (int n = 0; n < 4; ++n)
      bfr[n] = *(const bf16x8*)(Bs + (wn * 64 + n * 16 + fr) * 32 + kg);
#pragma unroll
    for (int m = 0; m < 4; ++m)
#pragma unroll
      for (int n = 0; n < 4; ++n)
        acc[m][n] = MFMA_BF16(af[m], bfr[n], acc[m][n]);
  }

  const int cr = (lane >> 4) * 4;
#pragma unroll
  for (int m = 0; m < 4; ++m)
#pragma unroll
    for (int n = 0; n < 4; ++n) {
      int col = col0 + wn * 64 + n * 16 + fr;
#pragma unroll
      for (int r = 0; r < 4; ++r) {
        int row = row0 + wm * 64 + m * 16 + cr + r;
        C[(size_t)row * N + col] = acc[m][n][r];
      }
    }
}

// block decode (both passes): bi in [0,512): u=bi&255, half=bi>>8. g=u&7 = (b*4+kvh).
// bi and bi+256 (two halves of a balanced 34-step pair) land on the same CU under rr
// dispatch: per-CU balance at 2 blocks/CU.

// ---------------- attention pass 1: y1 = softmax(qk^T) v ; writes u = mix1*v + mix2*y1 ----------------
__global__ __launch_bounds__(256, 2) void attn_pass1_kernel(
    const __hip_bfloat16* __restrict__ qT,   // (B,H,T,HD), q pre-scaled
    const __hip_bfloat16* __restrict__ kT,   // (B,HK,T,HD)
    const __hip_bfloat16* __restrict__ vt,   // (B,HK,HD,T)
    __hip_bfloat16* __restrict__ y1u,        // (B,H,HD,T)  u = mix1*v + mix2*y1
    float* __restrict__ Mb,                  // (B,H,T)  (exp2 domain)
    float* __restrict__ Lb,
    const float* __restrict__ mix1p,
    const float* __restrict__ mix2p) {
  __shared__ __align__(16) __hip_bfloat16 Ks[2][64 * 128];
  __shared__ __align__(16) __hip_bfloat16 Vs[2][128 * 64];
  __shared__ __align__(16) char Ps[4][32 * 128];
  const int tid = threadIdx.x, lane = tid & 63, wid = tid >> 6;   // wid 0..3
  const int bi = blockIdx.x;
  const int u = bi & 255, half = bi >> 8;
  const int g = u & 7;
  const int pslot = (u >> 3) & 7;
  const int bh = g * 4 + (u >> 6);
  const int j = half ? (15 - pslot) : pslot;
  const int q0 = j * 128;
  const int nt = 2 * j + 2;
  const int sd = 2 * j + (wid >> 1);         // wave's diagonal k-tile (rows wid*32..+31)
  const __hip_bfloat16* Kp = kT + (size_t)g * 2048 * 128;
  const __hip_bfloat16* Vp = vt + (size_t)g * 128 * 2048;
  const int fr = lane & 15, hi = lane >> 4;

  bf16x8 qf[2][4];
  {
    const __hip_bfloat16* Qp = qT + ((size_t)bh * 2048 + q0 + wid * 32) * 128;
#pragma unroll
    for (int rr = 0; rr < 2; ++rr)
#pragma unroll
      for (int dc = 0; dc < 4; ++dc)
        qf[rr][dc] = *(const bf16x8*)(Qp + (rr * 16 + fr) * 128 + dc * 32 + hi * 8);
  }

  f32x4 accO[2][8] = {};                     // accO[rr][f][r]: q=rr*16+hi*4+r, d=f*16+fr
  float m[2], l[2];                          // per q-row rr*16+fr (uniform across hi)
  m[0] = m[1] = -1e30f; l[0] = l[1] = 0.f;

  char* Pb = Ps[wid];

  auto STAGE = [&](int buf, int kt) {        // 8 global_load_lds (4 K + 4 V)
    const int k0 = kt * 64;
#pragma unroll
    for (int i = 0; i < 4; ++i) {
      int f = i * 256 + tid;
      int r = f >> 4, s = f & 15, sx = s ^ (r & 7);
      gload_lds16(Kp + (size_t)(k0 + r) * 128 + sx * 8,
                  (char*)Ks[buf] + (i * 256 + wid * 64) * 16);
    }
#pragma unroll
    for (int i = 0; i < 4; ++i) {
      int f = i * 256 + tid;
      int r = f >> 3, s = f & 7, sx = s ^ (r & 7);
      gload_lds16(Vp + (size_t)r * 2048 + k0 + sx * 8,
                  (char*)Vs[buf] + (i * 256 + wid * 64) * 16);
    }
  };

  STAGE(0, 0);
  int cur = 0;
  for (int s = 0; s < nt; ++s) {
    if (s > 0) __builtin_amdgcn_s_barrier();   // WAR: compute(s-1) closed
    __builtin_amdgcn_sched_barrier(0);
    if (s + 1 < nt) STAGE(cur ^ 1, s + 1);
    __builtin_amdgcn_sched_barrier(0);
    if (s + 1 < nt) asm volatile("s_waitcnt vmcnt(8)" ::: "memory");
    else            asm volatile("s_waitcnt vmcnt(0)" ::: "memory");
    __builtin_amdgcn_s_barrier();              // K(s),V(s) landed for all waves
    __builtin_amdgcn_sched_barrier(0);

    const bool active = (s <= sd);
    if (active) {
      // ---- QK (swapped): sf[rr][c][r] = S[q=rr*16+fr][k=c*16+hi*4+r] ----
      const char* Kc = (const char*)Ks[cur];
      f32x4 sf[2][4] = {};
      __builtin_amdgcn_s_setprio(1);
#pragma unroll
      for (int c = 0; c < 4; ++c) {
        const int krow = c * 16 + fr;
#pragma unroll
        for (int dc = 0; dc < 4; ++dc) {
          int slot = (dc * 4 + hi) ^ (krow & 7);
          bf16x8 kf = *(const bf16x8*)(Kc + krow * 256 + slot * 16);
          sf[0][c] = MFMA_BF16(kf, qf[0][dc], sf[0][c]);
          sf[1][c] = MFMA_BF16(kf, qf[1][dc], sf[1][c]);
        }
      }
      __builtin_amdgcn_s_setprio(0);
      // ---- mask (diagonal) + in-lane row max + cross-hi reduce ----
      float rmax[2];
#pragma unroll
      for (int rr = 0; rr < 2; ++rr) {
        if (s == sd) {
          const int qq = q0 + wid * 32 + rr * 16 + fr;
#pragma unroll
          for (int c = 0; c < 4; ++c) {
            const int kb = s * 64 + c * 16 + hi * 4;
#pragma unroll
            for (int r = 0; r < 4; ++r)
              if (kb + r > qq) sf[rr][c][r] = -1e30f;
          }
        }
        float v = -1e30f;
#pragma unroll
        for (int c = 0; c < 4; ++c)
#pragma unroll
          for (int r = 0; r < 4; ++r) v = fmaxf(v, sf[rr][c][r]);
        v = fmaxf(v, __shfl_xor(v, 16));
        v = fmaxf(v, __shfl_xor(v, 32));
        rmax[rr] = v;
      }
      // ---- T13 defer-max ----
      bool grow = (rmax[0] > m[0] + 8.f) | (rmax[1] > m[1] + 8.f);
      if (__any(grow)) {
        float a[2];
#pragma unroll
        for (int rr = 0; rr < 2; ++rr) {
          float mn = fmaxf(m[rr], rmax[rr]);
          a[rr] = __builtin_amdgcn_exp2f(m[rr] - mn);
          m[rr] = mn;
          l[rr] *= a[rr];
        }
#pragma unroll
        for (int rr = 0; rr < 2; ++rr)
#pragma unroll
          for (int r = 0; r < 4; ++r) {
            float aq = __shfl(a[rr], hi * 4 + r);   // a for q-row rr*16+hi*4+r
#pragma unroll
            for (int f = 0; f < 8; ++f) accO[rr][f][r] *= aq;
          }
      }
      // ---- exp2 + in-lane sum + cross-hi reduce ----
#pragma unroll
      for (int rr = 0; rr < 2; ++rr) {
        float rs = 0.f;
#pragma unroll
        for (int c = 0; c < 4; ++c)
#pragma unroll
          for (int r = 0; r < 4; ++r) {
            float p = __builtin_amdgcn_exp2f(sf[rr][c][r] - m[rr]);
            sf[rr][c][r] = p;
            rs += p;
          }
        rs += __shfl_xor(rs, 16);
        rs += __shfl_xor(rs, 32);
        l[rr] += rs;
      }
      // ---- P -> LDS: 8 packed b64 writes (swizzled 16B slots), read 4 b128 A-frags ----
#pragma unroll
      for (int rr = 0; rr < 2; ++rr) {
        const int row = rr * 16 + fr;
        char* Prow = Pb + row * 128;
#pragma unroll
        for (int c = 0; c < 4; ++c) {
          uint32_t w0 = pk2(sf[rr][c][0], sf[rr][c][1]);
          uint32_t w1 = pk2(sf[rr][c][2], sf[rr][c][3]);
          int sl = (c * 2 + (hi >> 1)) ^ (row & 7);
          *(uint2*)(Prow + sl * 16 + (hi & 1) * 8) = make_uint2(w0, w1);
        }
      }
      bf16x8 pf[2][2];
#pragma unroll
      for (int rr = 0; rr < 2; ++rr) {
        const int row = rr * 16 + fr;
#pragma unroll
        for (int kc = 0; kc < 2; ++kc) {
          int sl = (kc * 4 + hi) ^ (row & 7);
          pf[rr][kc] = *(const bf16x8*)(Pb + row * 128 + sl * 16);
        }
      }
      // ---- PV ----
      const __hip_bfloat16* Vc = Vs[cur];
      __builtin_amdgcn_s_setprio(1);
#pragma unroll
      for (int kc = 0; kc < 2; ++kc)
#pragma unroll
        for (int f = 0; f < 8; ++f) {
          int vrow = f * 16 + fr;
          int vslot = (kc * 4 + hi) ^ (fr & 7);
          bf16x8 vf = *(const bf16x8*)(Vc + vrow * 64 + vslot * 8);
          accO[0][f] = MFMA_BF16(pf[0][kc], vf, accO[0][f]);
          accO[1][f] = MFMA_BF16(pf[1][kc], vf, accO[1][f]);
        }
      __builtin_amdgcn_s_setprio(0);
    }
    cur ^= 1;
  }

  // ---- epilogue: u = mix1*v + mix2*(accO/l), d-major; store m,l ----
  const float m1v = mix1p[0], m2v = mix2p[0];
  float rlq[2][4];
#pragma unroll
  for (int rr = 0; rr < 2; ++rr) {
    float inv = 1.f / l[rr];
#pragma unroll
    for (int r = 0; r < 4; ++r) rlq[rr][r] = __shfl(inv, hi * 4 + r);
  }
  const int t0 = q0 + wid * 32;
#pragma unroll
  for (int rr = 0; rr < 2; ++rr) {
    const int tb = t0 + rr * 16 + hi * 4;
#pragma unroll
    for (int f = 0; f < 8; ++f) {
      const int d = f * 16 + fr;
      const ushort4 v4 = *(const ushort4*)(vt + ((size_t)g * 128 + d) * 2048 + tb);
      float u0 = m1v * b2f(v4.x) + m2v * (accO[rr][f][0] * rlq[rr][0]);
      float u1 = m1v * b2f(v4.y) + m2v * (accO[rr][f][1] * rlq[rr][1]);
      float u2 = m1v * b2f(v4.z) + m2v * (accO[rr][f][2] * rlq[rr][2]);
      float u3 = m1v * b2f(v4.w) + m2v * (accO[rr][f][3] * rlq[rr][3]);
      *(uint2*)(y1u + ((size_t)bh * 128 + d) * 2048 + tb) =
          make_uint2(pk2(u0, u1), pk2(u2, u3));
    }
  }
  if (hi == 0) {
#pragma unroll
    for (int rr = 0; rr < 2; ++rr) {
      Mb[(size_t)bh * 2048 + t0 + rr * 16 + fr] = m[rr];
      Lb[(size_t)bh * 2048 + t0 + rr * 16 + fr] = l[rr];
    }
  }
}

// ---------------- attention pass 2: ymix = att @ u  (direct final output) ----------------
__global__ __launch_bounds__(256, 2) void attn_pass2_kernel(
    const __hip_bfloat16* __restrict__ qT,
    const __hip_bfloat16* __restrict__ kT,
    const __hip_bfloat16* __restrict__ y1u,  // (B,H,HD,T)
    const float* __restrict__ Mb,
    const float* __restrict__ Lb,
    __hip_bfloat16* __restrict__ ymix) {     // (B,T,C)
  __shared__ __align__(16) __hip_bfloat16 Ks[2][64 * 128];
  __shared__ __align__(16) __hip_bfloat16 Vs[2][128 * 64];
  __shared__ __align__(16) char Ps[4][32 * 128];
  const int tid = threadIdx.x, lane = tid & 63, wid = tid >> 6;
  const int bi = blockIdx.x;
  const int u = bi & 255, half = bi >> 8;
  const int g = u & 7;
  const int pslot = (u >> 3) & 7;
  const int bh = g * 4 + (u >> 6);
  const int h = bh & 15, b = bh >> 4;
  const int j = half ? (15 - pslot) : pslot;
  const int q0 = j * 128;
  const int nt = 2 * j + 2;
  const int sd = 2 * j + (wid >> 1);
  const __hip_bfloat16* Kp = kT + (size_t)g * 2048 * 128;
  const __hip_bfloat16* Yp = y1u + (size_t)bh * 128 * 2048;
  const int fr = lane & 15, hi = lane >> 4;

  bf16x8 qf[2][4];
  float mr[2], rl[2];
  {
    const __hip_bfloat16* Qp = qT + ((size_t)bh * 2048 + q0 + wid * 32) * 128;
#pragma unroll
    for (int rr = 0; rr < 2; ++rr)
#pragma unroll
      for (int dc = 0; dc < 4; ++dc)
        qf[rr][dc] = *(const bf16x8*)(Qp + (rr * 16 + fr) * 128 + dc * 32 + hi * 8);
    const size_t qb = (size_t)bh * 2048 + q0 + wid * 32;
    mr[0] = Mb[qb + fr];        mr[1] = Mb[qb + 16 + fr];
    rl[0] = 1.f / Lb[qb + fr];  rl[1] = 1.f / Lb[qb + 16 + fr];
  }

  f32x4 accO[2][8] = {};
  char* Pb = Ps[wid];

  auto STAGE = [&](int buf, int kt) {
    const int k0 = kt * 64;
#pragma unroll
    for (int i = 0; i < 4; ++i) {
      int f = i * 256 + tid;
      int r = f >> 4, s = f & 15, sx = s ^ (r & 7);
      gload_lds16(Kp + (size_t)(k0 + r) * 128 + sx * 8,
                  (char*)Ks[buf] + (i * 256 + wid * 64) * 16);
    }
#pragma unroll
    for (int i = 0; i < 4; ++i) {
      int f = i * 256 + tid;
      int r = f >> 3, s = f & 7, sx = s ^ (r & 7);
      gload_lds16(Yp + (size_t)r * 2048 + k0 + sx * 8,
                  (char*)Vs[buf] + (i * 256 + wid * 64) * 16);
    }
  };

  STAGE(0, 0);
  int cur = 0;
  for (int s = 0; s < nt; ++s) {
    if (s > 0) __builtin_amdgcn_s_barrier();
    __builtin_amdgcn_sched_barrier(0);
    if (s + 1 < nt) STAGE(cur ^ 1, s + 1);
    __builtin_amdgcn_sched_barrier(0);
    if (s + 1 < nt) asm volatile("s_waitcnt vmcnt(8)" ::: "memory");
    else            asm volatile("s_waitcnt vmcnt(0)" ::: "memory");
    __builtin_amdgcn_s_barrier();
    __builtin_amdgcn_sched_barrier(0);

    const bool active = (s <= sd);
    if (active) {
      const char* Kc = (const char*)Ks[cur];
      f32x4 sf[2][4] = {};
      __builtin_amdgcn_s_setprio(1);
#pragma unroll
      for (int c = 0; c < 4; ++c) {
        const int krow = c * 16 + fr;
#pragma unroll
        for (int dc = 0; dc < 4; ++dc) {
          int slot = (dc * 4 + hi) ^ (krow & 7);
          bf16x8 kf = *(const bf16x8*)(Kc + krow * 256 + slot * 16);
          sf[0][c] = MFMA_BF16(kf, qf[0][dc], sf[0][c]);
          sf[1][c] = MFMA_BF16(kf, qf[1][dc], sf[1][c]);
        }
      }
      __builtin_amdgcn_s_setprio(0);
      // normalize P directly from stored stats (all fr-indexed, no shuffles)
#pragma unroll
      for (int rr = 0; rr < 2; ++rr) {
        if (s == sd) {
          const int qq = q0 + wid * 32 + rr * 16 + fr;
#pragma unroll
          for (int c = 0; c < 4; ++c) {
            const int kb = s * 64 + c * 16 + hi * 4;
#pragma unroll
            for (int r = 0; r < 4; ++r)
              if (kb + r > qq) sf[rr][c][r] = -1e30f;
          }
        }
#pragma unroll
        for (int c = 0; c < 4; ++c)
#pragma unroll
          for (int r = 0; r < 4; ++r)
            sf[rr][c][r] = __builtin_amdgcn_exp2f(sf[rr][c][r] - mr[rr]) * rl[rr];
      }
#pragma unroll
      for (int rr = 0; rr < 2; ++rr) {
        const int row = rr * 16 + fr;
        char* Prow = Pb + row * 128;
#pragma unroll
        for (int c = 0; c < 4; ++c) {
          uint32_t w0 = pk2(sf[rr][c][0], sf[rr][c][1]);
          uint32_t w1 = pk2(sf[rr][c][2], sf[rr][c][3]);
          int sl = (c * 2 + (hi >> 1)) ^ (row & 7);
          *(uint2*)(Prow + sl * 16 + (hi & 1) * 8) = make_uint2(w0, w1);
        }
      }
      bf16x8 pf[2][2];
#pragma unroll
      for (int rr = 0; rr < 2; ++rr) {
        const int row = rr * 16 + fr;
#pragma unroll
        for (int kc = 0; kc < 2; ++kc) {
          int sl = (kc * 4 + hi) ^ (row & 7);
          pf[rr][kc] = *(const bf16x8*)(Pb + row * 128 + sl * 16);
        }
      }
      const __hip_bfloat16* Vc = Vs[cur];
      __builtin_amdgcn_s_setprio(1);
#pragma unroll
      for (int kc = 0; kc < 2; ++kc)
#pragma unroll
        for (int f = 0; f < 8; ++f) {
          int vrow = f * 16 + fr;
          int vslot = (kc * 4 + hi) ^ (fr & 7);
          bf16x8 vf = *(const bf16x8*)(Vc + vrow * 64 + vslot * 8);
          accO[0][f] = MFMA_BF16(pf[0][kc], vf, accO[0][f]);
          accO[1][f] = MFMA_BF16(pf[1][kc], vf, accO[1][f]);
        }
      __builtin_amdgcn_s_setprio(0);
    }
    cur ^= 1;
  }

  // accO already IS the final mixed output (P pre-normalized, u pre-mixed)
#pragma unroll
  for (int rr = 0; rr < 2; ++rr) {
#pragma unroll
    for (int f = 0; f < 8; ++f) {
      const int d = f * 16 + fr;
#pragma unroll
      for (int r = 0; r < 4; ++r) {
        int q = q0 + wid * 32 + rr * 16 + hi * 4 + r;
        ymix[((size_t)b * 2048 + q) * 2048 + h * 128 + d] = __float2bfloat16(accO[rr][f][r]);
      }
    }
  }
}

// ---------------- launch ----------------
extern "C" void kernel_launch(void* const* d_in, const int* in_sizes, int n_in,
                              void* d_out, int out_size, void* d_ws, size_t ws_size,
                              hipStream_t stream) {
  const float* x    = (const float*)d_in[0];
  const float* cosb = (const float*)d_in[1];
  const float* sinb = (const float*)d_in[2];
  const float* Wq   = (const float*)d_in[3];
  const float* Wk   = (const float*)d_in[4];
  const float* Wv   = (const float*)d_in[5];
  const float* Wp   = (const float*)d_in[6];
  const float* mix1 = (const float*)d_in[7];
  const float* mix2 = (const float*)d_in[8];
  float* out = (float*)d_out;
  char* ws = (char*)d_ws;

  // workspace layout (bytes), peak ~80.2 MB
  __hip_bfloat16* xb   = (__hip_bfloat16*)(ws + 0);            // 16.78 MB; reused as ymix
  __hip_bfloat16* WTa  = (__hip_bfloat16*)(ws + 16777216);     // 12.58 MB
  __hip_bfloat16* WpT  = (__hip_bfloat16*)(ws + 29360128);     // 8.39 MB
  __hip_bfloat16* y1u  = (__hip_bfloat16*)(ws + 37748736);     // 16.78 MB
  float*          Mb   = (float*)(ws + 54525952);              // 0.26 MB
  float*          Lb   = (float*)(ws + 54788096);              // 0.26 MB
  __hip_bfloat16* qTb  = (__hip_bfloat16*)(ws + 55050240);     // 16.78 MB
  __hip_bfloat16* kTb  = (__hip_bfloat16*)(ws + 71827456);     // 4.19 MB
  __hip_bfloat16* vtb  = (__hip_bfloat16*)(ws + 76021760);     // 4.19 MB
  __hip_bfloat16* ymix = (__hip_bfloat16*)(ws + 0);

  dim3 tb(32, 8);
  cast_bf16_kernel<<<8192, 256, 0, stream>>>(x, xb, 2097152);
  wtrans_kernel<<<10240, tb, 0, stream>>>(Wq, Wk, Wv, Wp, WTa, WpT);

  // fused QKV projection + RoPE + RMS + V-transpose
  gemm_qkv_rope_kernel<<<768, 256, 0, stream>>>(xb, WTa, cosb, sinb, qTb, kTb, vtb);

  attn_pass1_kernel<<<512, 256, 0, stream>>>(qTb, kTb, vtb, y1u, Mb, Lb, mix1, mix2);
  attn_pass2_kernel<<<512, 256, 0, stream>>>(qTb, kTb, y1u, Mb, Lb, ymix);

  gemm_bf16_kernel<<<512, 256, 0, stream>>>(ymix, WpT, out, 4096, 2048, 2048);
}

// Round 9
// 296.698 us; speedup vs baseline: 1.0347x; 1.0347x over previous
//
#include <hip/hip_runtime.h>
#include <hip/hip_bf16.h>
#include <cstdint>
#include <cstddef>

#define AS1 __attribute__((address_space(1)))
#define AS3 __attribute__((address_space(3)))

typedef __attribute__((ext_vector_type(8))) short bf16x8;
typedef __attribute__((ext_vector_type(4))) float f32x4;

__device__ __forceinline__ void gload_lds16(const void* g, void* l) {
  __builtin_amdgcn_global_load_lds((const AS1 void*)g, (AS3 void*)l, 16, 0, 0);
}

#define MFMA_BF16(A, B, C) __builtin_amdgcn_mfma_f32_16x16x32_bf16((A), (B), (C), 0, 0, 0)

// (1/sqrt(128)) * log2(e) — folded into q at rope time; softmax runs in exp2 domain.
#define QSCALE 0.12751744f

__device__ __forceinline__ uint32_t pk2(float a, float b) {
  uint32_t ua = (uint32_t)__builtin_bit_cast(unsigned short, __float2bfloat16(a));
  uint32_t ub = (uint32_t)__builtin_bit_cast(unsigned short, __float2bfloat16(b));
  return ua | (ub << 16);
}
__device__ __forceinline__ float b2f(unsigned short u) {
  return __builtin_bit_cast(float, (uint32_t)u << 16);
}

// sum over 8 consecutive lanes (group-aligned): DPP xor1, xor2, half-mirror
__device__ __forceinline__ float red8_sum(float v) {
  int x;
  x = __builtin_amdgcn_update_dpp(0, __builtin_bit_cast(int, v), 0xB1, 0xF, 0xF, true);
  v += __builtin_bit_cast(float, x);
  x = __builtin_amdgcn_update_dpp(0, __builtin_bit_cast(int, v), 0x4E, 0xF, 0xF, true);
  v += __builtin_bit_cast(float, x);
  x = __builtin_amdgcn_update_dpp(0, __builtin_bit_cast(int, v), 0x141, 0xF, 0xF, true);
  v += __builtin_bit_cast(float, x);
  return v;
}

// ---------------- cast f32 -> bf16 ----------------
__global__ __launch_bounds__(256) void cast_bf16_kernel(const float* __restrict__ in,
                                                        __hip_bfloat16* __restrict__ out,
                                                        int n4) {
  int i = blockIdx.x * 256 + threadIdx.x;
  if (i < n4) {
    float4 v = ((const float4*)in)[i];
    __hip_bfloat16* o = out + (size_t)i * 4;
    o[0] = __float2bfloat16(v.x);
    o[1] = __float2bfloat16(v.y);
    o[2] = __float2bfloat16(v.z);
    o[3] = __float2bfloat16(v.w);
  }
}

// ---------------- merged weight transpose+cast (Wq,Wk,Wv,Wp in one launch) ----------------
__global__ __launch_bounds__(256) void wtrans_kernel(const float* __restrict__ Wq,
                                                     const float* __restrict__ Wk,
                                                     const float* __restrict__ Wv,
                                                     const float* __restrict__ Wp,
                                                     __hip_bfloat16* __restrict__ WTa,
                                                     __hip_bfloat16* __restrict__ WpT) {
  __shared__ float tile[32][33];
  int id = blockIdx.x;
  const float* in; __hip_bfloat16* out; int is, os, bx, by;
  if (id < 4096)      { in = Wq; out = WTa;                          is = 2048; os = 2048; bx = id & 63; by = id >> 6; }
  else if (id < 5120) { int t = id - 4096; in = Wk; out = WTa + (size_t)2048 * 2048; is = 512; os = 2048; bx = t & 15; by = t >> 4; }
  else if (id < 6144) { int t = id - 5120; in = Wv; out = WTa + (size_t)2560 * 2048; is = 512; os = 2048; bx = t & 15; by = t >> 4; }
  else                { int t = id - 6144; in = Wp; out = WpT;       is = 2048; os = 2048; bx = t & 63; by = t >> 6; }
  int c0 = bx * 32, r0 = by * 32;
  int tx = threadIdx.x, ty = threadIdx.y;
#pragma unroll
  for (int i = 0; i < 32; i += 8)
    tile[ty + i][tx] = in[(size_t)(r0 + ty + i) * is + c0 + tx];
  __syncthreads();
#pragma unroll
  for (int i = 0; i < 32; i += 8)
    out[(size_t)(c0 + ty + i) * os + r0 + tx] = __float2bfloat16(tile[tx][ty + i]);
}

// ---------------- qkv GEMM with fused RoPE+RMS epilogue (packed CL4 layout) ----------------
// C(4096x3072) = xb @ WTa^T, tile 128x128; col tile == one head.
// acc -> CL4 (row-quad interleaved: elem idx = (quad*133+col)*4 + (row&3)) as packed b64.
// q/k tiles: rope+rms threaded (row-quad x 8-col-slice), coalesced 16B stores.
// v tiles: column read from CL4, 128B-contiguous stores to vt (B,HK,HD,T).
__global__ __launch_bounds__(256) void gemm_qkv_rope_kernel(
    const __hip_bfloat16* __restrict__ A,
    const __hip_bfloat16* __restrict__ Bt,
    const float* __restrict__ cosb,
    const float* __restrict__ sinb,
    __hip_bfloat16* __restrict__ qT,
    __hip_bfloat16* __restrict__ kT,
    __hip_bfloat16* __restrict__ vt) {
  __shared__ __align__(16) char smem[34048];          // As|Bs during loop; CL4 after
  __hip_bfloat16* As = (__hip_bfloat16*)smem;
  __hip_bfloat16* Bs = (__hip_bfloat16*)(smem + 8192);
  __hip_bfloat16* CL4 = (__hip_bfloat16*)smem;        // (quad*133+col)*4 + rr
  const int K = 2048;
  const int tid = threadIdx.x;
  const int lane = tid & 63;
  const int wid = tid >> 6;
  const int wm = wid >> 1, wn = wid & 1;
  const int nwg = gridDim.x;
  const int bid = blockIdx.x;
  const int swz = (bid & 7) * (nwg >> 3) + (bid >> 3);
  const int tm = swz / 24, tn = swz % 24;
  const int row0 = tm << 7, col0 = tn << 7;
  const int fr = lane & 15;
  const int hi = lane >> 4;
  const int kg = hi * 8;

  f32x4 acc[4][4] = {};
  for (int k0 = 0; k0 < K; k0 += 32) {
    __syncthreads();
#pragma unroll
    for (int i = 0; i < 2; ++i) {
      int f = i * 256 + tid;
      int r = f >> 2, s = f & 3;
      gload_lds16(A + (size_t)(row0 + r) * K + k0 + s * 8,
                  (char*)As + (i * 256 + wid * 64) * 16);
      gload_lds16(Bt + (size_t)(col0 + r) * K + k0 + s * 8,
                  (char*)Bs + (i * 256 + wid * 64) * 16);
    }
    __syncthreads();
    bf16x8 af[4], bfr[4];
#pragma unroll
    for (int m = 0; m < 4; ++m)
      af[m] = *(const bf16x8*)(As + (wm * 64 + m * 16 + fr) * 32 + kg);
#pragma unroll
    for (int n = 0; n < 4; ++n)
      bfr[n] = *(const bf16x8*)(Bs + (wn * 64 + n * 16 + fr) * 32 + kg);
#pragma unroll
    for (int m = 0; m < 4; ++m)
#pragma unroll
      for (int n = 0; n < 4; ++n)
        acc[m][n] = MFMA_BF16(af[m], bfr[n], acc[m][n]);
  }
  __syncthreads();                                    // As/Bs reads done; reuse as CL4

  // ---- pack acc -> CL4: one b64 per fragment (4 consecutive rows, same col) ----
#pragma unroll
  for (int m = 0; m < 4; ++m)
#pragma unroll
    for (int n = 0; n < 4; ++n) {
      int q4 = wm * 16 + m * 4 + hi;                  // (row>>2)
      int col = wn * 64 + n * 16 + fr;
      *(uint2*)(CL4 + ((q4 * 133 + col) << 2)) =
          make_uint2(pk2(acc[m][n][0], acc[m][n][1]), pk2(acc[m][n][2], acc[m][n][3]));
    }
  __syncthreads();

  const int b = row0 >> 11;
  const int t0 = row0 & 2047;

  if (col0 >= 2560) {
    // ---- V: column gather from CL4, 128B-contiguous stores to (B,HK,HD,T) ----
    const int hv = (col0 - 2560) >> 7;
    __hip_bfloat16* vb = vt + (size_t)(b * 4 + hv) * 128 * 2048;
    const int col = tid >> 1, th = tid & 1;
    uint2 w[16];
#pragma unroll
    for (int qq = 0; qq < 16; ++qq)
      w[qq] = *(const uint2*)(CL4 + (((th * 16 + qq) * 133 + col) << 2));
    __hip_bfloat16* dstv = vb + (size_t)col * 2048 + t0 + th * 64;
#pragma unroll
    for (int e = 0; e < 8; ++e)
      *(uint4*)(dstv + e * 8) = make_uint4(w[2 * e].x, w[2 * e].y, w[2 * e + 1].x, w[2 * e + 1].y);
    return;
  }

  // ---- q/k: rope + rms. thread = (row-quad, 8-col-slice) ----
  const int quad = tid >> 3, cp = tid & 7;
  const int tb = t0 + quad * 4;
  bf16x8 lov[4], hiv[4];
#pragma unroll
  for (int e = 0; e < 4; ++e) {
    lov[e] = *(const bf16x8*)(CL4 + ((quad * 133 + cp * 8 + e * 2) << 2));
    hiv[e] = *(const bf16x8*)(CL4 + ((quad * 133 + 64 + cp * 8 + e * 2) << 2));
  }
  const float oscale = (col0 < 2048) ? QSCALE : 1.0f;
  __hip_bfloat16* dstq = (col0 < 2048)
      ? qT + (size_t)(b * 16 + (col0 >> 7)) * 2048 * 128
      : kT + (size_t)(b * 4 + ((col0 - 2048) >> 7)) * 2048 * 128;

  float o1v[4][8], o2v[4][8], ssum[4];
#pragma unroll
  for (int rr = 0; rr < 4; ++rr) {
    const float* cb = cosb + (size_t)(tb + rr) * 64 + cp * 8;
    const float* sb = sinb + (size_t)(tb + rr) * 64 + cp * 8;
    float4 c0 = *(const float4*)cb, c1 = *(const float4*)(cb + 4);
    float4 s0 = *(const float4*)sb, s1 = *(const float4*)(sb + 4);
    float cc[8] = {c0.x, c0.y, c0.z, c0.w, c1.x, c1.y, c1.z, c1.w};
    float sn[8] = {s0.x, s0.y, s0.z, s0.w, s1.x, s1.y, s1.z, s1.w};
    float ss = 0.f;
#pragma unroll
    for (int e = 0; e < 4; ++e)
#pragma unroll
      for (int w2 = 0; w2 < 2; ++w2) {
        int pd = e * 2 + w2;
        float x1 = b2f((unsigned short)lov[e][w2 * 4 + rr]);
        float x2 = b2f((unsigned short)hiv[e][w2 * 4 + rr]);
        float a = x1 * cc[pd] - x2 * sn[pd];
        float bb = x1 * sn[pd] + x2 * cc[pd];
        o1v[rr][pd] = a;
        o2v[rr][pd] = bb;
        ss += a * a + bb * bb;
      }
    ssum[rr] = ss;
  }
#pragma unroll
  for (int rr = 0; rr < 4; ++rr) {
    float rn = rsqrtf(red8_sum(ssum[rr]) * (1.f / 128.f) + 1e-6f) * oscale;
    __hip_bfloat16* dr = dstq + (size_t)(tb + rr) * 128 + cp * 8;
    *(uint4*)dr = make_uint4(pk2(o1v[rr][0] * rn, o1v[rr][1] * rn),
                             pk2(o1v[rr][2] * rn, o1v[rr][3] * rn),
                             pk2(o1v[rr][4] * rn, o1v[rr][5] * rn),
                             pk2(o1v[rr][6] * rn, o1v[rr][7] * rn));
    *(uint4*)(dr + 64) = make_uint4(pk2(o2v[rr][0] * rn, o2v[rr][1] * rn),
                                    pk2(o2v[rr][2] * rn, o2v[rr][3] * rn),
                                    pk2(o2v[rr][4] * rn, o2v[rr][5] * rn),
                                    pk2(o2v[rr][6] * rn, o2v[rr][7] * rn));
  }
}

// ---------------- generic bf16 GEMM (m97 structure, f32 out) ----------------
__global__ __launch_bounds__(256) void gemm_bf16_kernel(const __hip_bfloat16* __restrict__ A,
                                                        const __hip_bfloat16* __restrict__ Bt,
                                                        float* __restrict__ C,
                                                        int M, int N, int K) {
  __shared__ __align__(16) __hip_bfloat16 As[128 * 32];
  __shared__ __align__(16) __hip_bfloat16 Bs[128 * 32];
  const int tid = threadIdx.x;
  const int lane = tid & 63;
  const int wid = tid >> 6;
  const int wm = wid >> 1, wn = wid & 1;
  const int nwg = gridDim.x;
  const int bid = blockIdx.x;
  const int swz = (bid & 7) * (nwg >> 3) + (bid >> 3);
  const int ntile = N >> 7;
  const int tm = swz / ntile, tn = swz % ntile;
  const int row0 = tm << 7, col0 = tn << 7;

  const int fr = lane & 15;
  const int kg = (lane >> 4) * 8;

  f32x4 acc[4][4] = {};

  for (int k0 = 0; k0 < K; k0 += 32) {
    __syncthreads();
#pragma unroll
    for (int i = 0; i < 2; ++i) {
      int f = i * 256 + tid;
      int r = f >> 2, s = f & 3;
      gload_lds16(A + (size_t)(row0 + r) * K + k0 + s * 8,
                  (char*)As + (i * 256 + wid * 64) * 16);
      gload_lds16(Bt + (size_t)(col0 + r) * K + k0 + s * 8,
                  (char*)Bs + (i * 256 + wid * 64) * 16);
    }
    __syncthreads();
    bf16x8 af[4], bfr[4];
#pragma unroll
    for (int m = 0; m < 4; ++m)
      af[m] = *(const bf16x8*)(As + (wm * 64 + m * 16 + fr) * 32 + kg);
#pragma unroll
    for (int n = 0; n < 4; ++n)
      bfr[n] = *(const bf16x8*)(Bs + (wn * 64 + n * 16 + fr) * 32 + kg);
#pragma unroll
    for (int m = 0; m < 4; ++m)
#pragma unroll
      for (int n = 0; n < 4; ++n)
        acc[m][n] = MFMA_BF16(af[m], bfr[n], acc[m][n]);
  }

  const int cr = (lane >> 4) * 4;
#pragma unroll
  for (int m = 0; m < 4; ++m)
#pragma unroll
    for (int n = 0; n < 4; ++n) {
      int col = col0 + wn * 64 + n * 16 + fr;
#pragma unroll
      for (int r = 0; r < 4; ++r) {
        int row = row0 + wm * 64 + m * 16 + cr + r;
        C[(size_t)row * N + col] = acc[m][n][r];
      }
    }
}

// block decode (both passes): bi in [0,512): u=bi&255, half=bi>>8. g=u&7 = (b*4+kvh).
// bi and bi+256 (two halves of a balanced 34-step pair) land on the same CU under rr
// dispatch: per-CU balance at 2 blocks/CU.

// ---------------- attention pass 1: y1 = softmax(qk^T) v ; writes u = mix1*v + mix2*y1 ----------------
__global__ __launch_bounds__(256, 2) void attn_pass1_kernel(
    const __hip_bfloat16* __restrict__ qT,   // (B,H,T,HD), q pre-scaled
    const __hip_bfloat16* __restrict__ kT,   // (B,HK,T,HD)
    const __hip_bfloat16* __restrict__ vt,   // (B,HK,HD,T)
    __hip_bfloat16* __restrict__ y1u,        // (B,H,HD,T)  u = mix1*v + mix2*y1
    float* __restrict__ Mb,                  // (B,H,T)  (exp2 domain)
    float* __restrict__ Lb,
    const float* __restrict__ mix1p,
    const float* __restrict__ mix2p) {
  __shared__ __align__(16) __hip_bfloat16 Ks[2][64 * 128];
  __shared__ __align__(16) __hip_bfloat16 Vs[2][128 * 64];
  __shared__ __align__(16) char Ps[4][32 * 128];
  const int tid = threadIdx.x, lane = tid & 63, wid = tid >> 6;   // wid 0..3
  const int bi = blockIdx.x;
  const int u = bi & 255, half = bi >> 8;
  const int g = u & 7;
  const int pslot = (u >> 3) & 7;
  const int bh = g * 4 + (u >> 6);
  const int j = half ? (15 - pslot) : pslot;
  const int q0 = j * 128;
  const int nt = 2 * j + 2;
  const int sd = 2 * j + (wid >> 1);         // wave's diagonal k-tile (rows wid*32..+31)
  const __hip_bfloat16* Kp = kT + (size_t)g * 2048 * 128;
  const __hip_bfloat16* Vp = vt + (size_t)g * 128 * 2048;
  const int fr = lane & 15, hi = lane >> 4;

  bf16x8 qf[2][4];
  {
    const __hip_bfloat16* Qp = qT + ((size_t)bh * 2048 + q0 + wid * 32) * 128;
#pragma unroll
    for (int rr = 0; rr < 2; ++rr)
#pragma unroll
      for (int dc = 0; dc < 4; ++dc)
        qf[rr][dc] = *(const bf16x8*)(Qp + (rr * 16 + fr) * 128 + dc * 32 + hi * 8);
  }

  f32x4 accO[2][8] = {};                     // accO[rr][f][r]: q=rr*16+hi*4+r, d=f*16+fr
  float m[2], l[2];                          // per q-row rr*16+fr (uniform across hi)
  m[0] = m[1] = -1e30f; l[0] = l[1] = 0.f;

  char* Pb = Ps[wid];

  auto STAGE = [&](int buf, int kt) {        // 8 global_load_lds (4 K + 4 V)
    const int k0 = kt * 64;
#pragma unroll
    for (int i = 0; i < 4; ++i) {
      int f = i * 256 + tid;
      int r = f >> 4, s = f & 15, sx = s ^ (r & 7);
      gload_lds16(Kp + (size_t)(k0 + r) * 128 + sx * 8,
                  (char*)Ks[buf] + (i * 256 + wid * 64) * 16);
    }
#pragma unroll
    for (int i = 0; i < 4; ++i) {
      int f = i * 256 + tid;
      int r = f >> 3, s = f & 7, sx = s ^ (r & 7);
      gload_lds16(Vp + (size_t)r * 2048 + k0 + sx * 8,
                  (char*)Vs[buf] + (i * 256 + wid * 64) * 16);
    }
  };

  STAGE(0, 0);
  int cur = 0;
  for (int s = 0; s < nt; ++s) {
    if (s > 0) __builtin_amdgcn_s_barrier();   // WAR: compute(s-1) closed
    __builtin_amdgcn_sched_barrier(0);
    if (s + 1 < nt) STAGE(cur ^ 1, s + 1);
    __builtin_amdgcn_sched_barrier(0);
    if (s + 1 < nt) asm volatile("s_waitcnt vmcnt(8)" ::: "memory");
    else            asm volatile("s_waitcnt vmcnt(0)" ::: "memory");
    __builtin_amdgcn_s_barrier();              // K(s),V(s) landed for all waves
    __builtin_amdgcn_sched_barrier(0);

    const bool active = (s <= sd);
    if (active) {
      // ---- QK (swapped): sf[rr][c][r] = S[q=rr*16+fr][k=c*16+hi*4+r] ----
      const char* Kc = (const char*)Ks[cur];
      f32x4 sf[2][4] = {};
      __builtin_amdgcn_s_setprio(1);
#pragma unroll
      for (int c = 0; c < 4; ++c) {
        const int krow = c * 16 + fr;
#pragma unroll
        for (int dc = 0; dc < 4; ++dc) {
          int slot = (dc * 4 + hi) ^ (krow & 7);
          bf16x8 kf = *(const bf16x8*)(Kc + krow * 256 + slot * 16);
          sf[0][c] = MFMA_BF16(kf, qf[0][dc], sf[0][c]);
          sf[1][c] = MFMA_BF16(kf, qf[1][dc], sf[1][c]);
        }
      }
      __builtin_amdgcn_s_setprio(0);
      // ---- mask (diagonal) + in-lane row max + cross-hi reduce ----
      float rmax[2];
#pragma unroll
      for (int rr = 0; rr < 2; ++rr) {
        if (s == sd) {
          const int qq = q0 + wid * 32 + rr * 16 + fr;
#pragma unroll
          for (int c = 0; c < 4; ++c) {
            const int kb = s * 64 + c * 16 + hi * 4;
#pragma unroll
            for (int r = 0; r < 4; ++r)
              if (kb + r > qq) sf[rr][c][r] = -1e30f;
          }
        }
        float v = -1e30f;
#pragma unroll
        for (int c = 0; c < 4; ++c)
#pragma unroll
          for (int r = 0; r < 4; ++r) v = fmaxf(v, sf[rr][c][r]);
        v = fmaxf(v, __shfl_xor(v, 16));
        v = fmaxf(v, __shfl_xor(v, 32));
        rmax[rr] = v;
      }
      // ---- T13 defer-max ----
      bool grow = (rmax[0] > m[0] + 8.f) | (rmax[1] > m[1] + 8.f);
      if (__any(grow)) {
        float a[2];
#pragma unroll
        for (int rr = 0; rr < 2; ++rr) {
          float mn = fmaxf(m[rr], rmax[rr]);
          a[rr] = __builtin_amdgcn_exp2f(m[rr] - mn);
          m[rr] = mn;
          l[rr] *= a[rr];
        }
#pragma unroll
        for (int rr = 0; rr < 2; ++rr)
#pragma unroll
          for (int r = 0; r < 4; ++r) {
            float aq = __shfl(a[rr], hi * 4 + r);   // a for q-row rr*16+hi*4+r
#pragma unroll
            for (int f = 0; f < 8; ++f) accO[rr][f][r] *= aq;
          }
      }
      // ---- exp2 + in-lane sum + cross-hi reduce ----
#pragma unroll
      for (int rr = 0; rr < 2; ++rr) {
        float rs = 0.f;
#pragma unroll
        for (int c = 0; c < 4; ++c)
#pragma unroll
          for (int r = 0; r < 4; ++r) {
            float p = __builtin_amdgcn_exp2f(sf[rr][c][r] - m[rr]);
            sf[rr][c][r] = p;
            rs += p;
          }
        rs += __shfl_xor(rs, 16);
        rs += __shfl_xor(rs, 32);
        l[rr] += rs;
      }
      // ---- P -> LDS: 8 packed b64 writes (swizzled 16B slots), read 4 b128 A-frags ----
#pragma unroll
      for (int rr = 0; rr < 2; ++rr) {
        const int row = rr * 16 + fr;
        char* Prow = Pb + row * 128;
#pragma unroll
        for (int c = 0; c < 4; ++c) {
          uint32_t w0 = pk2(sf[rr][c][0], sf[rr][c][1]);
          uint32_t w1 = pk2(sf[rr][c][2], sf[rr][c][3]);
          int sl = (c * 2 + (hi >> 1)) ^ (row & 7);
          *(uint2*)(Prow + sl * 16 + (hi & 1) * 8) = make_uint2(w0, w1);
        }
      }
      bf16x8 pf[2][2];
#pragma unroll
      for (int rr = 0; rr < 2; ++rr) {
        const int row = rr * 16 + fr;
#pragma unroll
        for (int kc = 0; kc < 2; ++kc) {
          int sl = (kc * 4 + hi) ^ (row & 7);
          pf[rr][kc] = *(const bf16x8*)(Pb + row * 128 + sl * 16);
        }
      }
      // ---- PV ----
      const __hip_bfloat16* Vc = Vs[cur];
      __builtin_amdgcn_s_setprio(1);
#pragma unroll
      for (int kc = 0; kc < 2; ++kc)
#pragma unroll
        for (int f = 0; f < 8; ++f) {
          int vrow = f * 16 + fr;
          int vslot = (kc * 4 + hi) ^ (fr & 7);
          bf16x8 vf = *(const bf16x8*)(Vc + vrow * 64 + vslot * 8);
          accO[0][f] = MFMA_BF16(pf[0][kc], vf, accO[0][f]);
          accO[1][f] = MFMA_BF16(pf[1][kc], vf, accO[1][f]);
        }
      __builtin_amdgcn_s_setprio(0);
    }
    cur ^= 1;
  }

  // ---- epilogue: u = mix1*v + mix2*(accO/l), d-major; store m,l ----
  const float m1v = mix1p[0], m2v = mix2p[0];
  float rlq[2][4];
#pragma unroll
  for (int rr = 0; rr < 2; ++rr) {
    float inv = 1.f / l[rr];
#pragma unroll
    for (int r = 0; r < 4; ++r) rlq[rr][r] = __shfl(inv, hi * 4 + r);
  }
  const int t0 = q0 + wid * 32;
#pragma unroll
  for (int rr = 0; rr < 2; ++rr) {
    const int tb = t0 + rr * 16 + hi * 4;
#pragma unroll
    for (int f = 0; f < 8; ++f) {
      const int d = f * 16 + fr;
      const ushort4 v4 = *(const ushort4*)(vt + ((size_t)g * 128 + d) * 2048 + tb);
      float u0 = m1v * b2f(v4.x) + m2v * (accO[rr][f][0] * rlq[rr][0]);
      float u1 = m1v * b2f(v4.y) + m2v * (accO[rr][f][1] * rlq[rr][1]);
      float u2 = m1v * b2f(v4.z) + m2v * (accO[rr][f][2] * rlq[rr][2]);
      float u3 = m1v * b2f(v4.w) + m2v * (accO[rr][f][3] * rlq[rr][3]);
      *(uint2*)(y1u + ((size_t)bh * 128 + d) * 2048 + tb) =
          make_uint2(pk2(u0, u1), pk2(u2, u3));
    }
  }
  if (hi == 0) {
#pragma unroll
    for (int rr = 0; rr < 2; ++rr) {
      Mb[(size_t)bh * 2048 + t0 + rr * 16 + fr] = m[rr];
      Lb[(size_t)bh * 2048 + t0 + rr * 16 + fr] = l[rr];
    }
  }
}

// ---------------- attention pass 2: ymix = att @ u  (direct final output) ----------------
__global__ __launch_bounds__(256, 2) void attn_pass2_kernel(
    const __hip_bfloat16* __restrict__ qT,
    const __hip_bfloat16* __restrict__ kT,
    const __hip_bfloat16* __restrict__ y1u,  // (B,H,HD,T)
    const float* __restrict__ Mb,
    const float* __restrict__ Lb,
    __hip_bfloat16* __restrict__ ymix) {     // (B,T,C)
  __shared__ __align__(16) __hip_bfloat16 Ks[2][64 * 128];
  __shared__ __align__(16) __hip_bfloat16 Vs[2][128 * 64];
  __shared__ __align__(16) char Ps[4][32 * 128];
  const int tid = threadIdx.x, lane = tid & 63, wid = tid >> 6;
  const int bi = blockIdx.x;
  const int u = bi & 255, half = bi >> 8;
  const int g = u & 7;
  const int pslot = (u >> 3) & 7;
  const int bh = g * 4 + (u >> 6);
  const int h = bh & 15, b = bh >> 4;
  const int j = half ? (15 - pslot) : pslot;
  const int q0 = j * 128;
  const int nt = 2 * j + 2;
  const int sd = 2 * j + (wid >> 1);
  const __hip_bfloat16* Kp = kT + (size_t)g * 2048 * 128;
  const __hip_bfloat16* Yp = y1u + (size_t)bh * 128 * 2048;
  const int fr = lane & 15, hi = lane >> 4;

  bf16x8 qf[2][4];
  float mr[2], rl[2];
  {
    const __hip_bfloat16* Qp = qT + ((size_t)bh * 2048 + q0 + wid * 32) * 128;
#pragma unroll
    for (int rr = 0; rr < 2; ++rr)
#pragma unroll
      for (int dc = 0; dc < 4; ++dc)
        qf[rr][dc] = *(const bf16x8*)(Qp + (rr * 16 + fr) * 128 + dc * 32 + hi * 8);
    const size_t qb = (size_t)bh * 2048 + q0 + wid * 32;
    mr[0] = Mb[qb + fr];        mr[1] = Mb[qb + 16 + fr];
    rl[0] = 1.f / Lb[qb + fr];  rl[1] = 1.f / Lb[qb + 16 + fr];
  }

  f32x4 accO[2][8] = {};
  char* Pb = Ps[wid];

  auto STAGE = [&](int buf, int kt) {
    const int k0 = kt * 64;
#pragma unroll
    for (int i = 0; i < 4; ++i) {
      int f = i * 256 + tid;
      int r = f >> 4, s = f & 15, sx = s ^ (r & 7);
      gload_lds16(Kp + (size_t)(k0 + r) * 128 + sx * 8,
                  (char*)Ks[buf] + (i * 256 + wid * 64) * 16);
    }
#pragma unroll
    for (int i = 0; i < 4; ++i) {
      int f = i * 256 + tid;
      int r = f >> 3, s = f & 7, sx = s ^ (r & 7);
      gload_lds16(Yp + (size_t)r * 2048 + k0 + sx * 8,
                  (char*)Vs[buf] + (i * 256 + wid * 64) * 16);
    }
  };

  STAGE(0, 0);
  int cur = 0;
  for (int s = 0; s < nt; ++s) {
    if (s > 0) __builtin_amdgcn_s_barrier();
    __builtin_amdgcn_sched_barrier(0);
    if (s + 1 < nt) STAGE(cur ^ 1, s + 1);
    __builtin_amdgcn_sched_barrier(0);
    if (s + 1 < nt) asm volatile("s_waitcnt vmcnt(8)" ::: "memory");
    else            asm volatile("s_waitcnt vmcnt(0)" ::: "memory");
    __builtin_amdgcn_s_barrier();
    __builtin_amdgcn_sched_barrier(0);

    const bool active = (s <= sd);
    if (active) {
      const char* Kc = (const char*)Ks[cur];
      f32x4 sf[2][4] = {};
      __builtin_amdgcn_s_setprio(1);
#pragma unroll
      for (int c = 0; c < 4; ++c) {
        const int krow = c * 16 + fr;
#pragma unroll
        for (int dc = 0; dc < 4; ++dc) {
          int slot = (dc * 4 + hi) ^ (krow & 7);
          bf16x8 kf = *(const bf16x8*)(Kc + krow * 256 + slot * 16);
          sf[0][c] = MFMA_BF16(kf, qf[0][dc], sf[0][c]);
          sf[1][c] = MFMA_BF16(kf, qf[1][dc], sf[1][c]);
        }
      }
      __builtin_amdgcn_s_setprio(0);
      // normalize P directly from stored stats (all fr-indexed, no shuffles)
#pragma unroll
      for (int rr = 0; rr < 2; ++rr) {
        if (s == sd) {
          const int qq = q0 + wid * 32 + rr * 16 + fr;
#pragma unroll
          for (int c = 0; c < 4; ++c) {
            const int kb = s * 64 + c * 16 + hi * 4;
#pragma unroll
            for (int r = 0; r < 4; ++r)
              if (kb + r > qq) sf[rr][c][r] = -1e30f;
          }
        }
#pragma unroll
        for (int c = 0; c < 4; ++c)
#pragma unroll
          for (int r = 0; r < 4; ++r)
            sf[rr][c][r] = __builtin_amdgcn_exp2f(sf[rr][c][r] - mr[rr]) * rl[rr];
      }
#pragma unroll
      for (int rr = 0; rr < 2; ++rr) {
        const int row = rr * 16 + fr;
        char* Prow = Pb + row * 128;
#pragma unroll
        for (int c = 0; c < 4; ++c) {
          uint32_t w0 = pk2(sf[rr][c][0], sf[rr][c][1]);
          uint32_t w1 = pk2(sf[rr][c][2], sf[rr][c][3]);
          int sl = (c * 2 + (hi >> 1)) ^ (row & 7);
          *(uint2*)(Prow + sl * 16 + (hi & 1) * 8) = make_uint2(w0, w1);
        }
      }
      bf16x8 pf[2][2];
#pragma unroll
      for (int rr = 0; rr < 2; ++rr) {
        const int row = rr * 16 + fr;
#pragma unroll
        for (int kc = 0; kc < 2; ++kc) {
          int sl = (kc * 4 + hi) ^ (row & 7);
          pf[rr][kc] = *(const bf16x8*)(Pb + row * 128 + sl * 16);
        }
      }
      const __hip_bfloat16* Vc = Vs[cur];
      __builtin_amdgcn_s_setprio(1);
#pragma unroll
      for (int kc = 0; kc < 2; ++kc)
#pragma unroll
        for (int f = 0; f < 8; ++f) {
          int vrow = f * 16 + fr;
          int vslot = (kc * 4 + hi) ^ (fr & 7);
          bf16x8 vf = *(const bf16x8*)(Vc + vrow * 64 + vslot * 8);
          accO[0][f] = MFMA_BF16(pf[0][kc], vf, accO[0][f]);
          accO[1][f] = MFMA_BF16(pf[1][kc], vf, accO[1][f]);
        }
      __builtin_amdgcn_s_setprio(0);
    }
    cur ^= 1;
  }

  // accO already IS the final mixed output (P pre-normalized, u pre-mixed)
#pragma unroll
  for (int rr = 0; rr < 2; ++rr) {
#pragma unroll
    for (int f = 0; f < 8; ++f) {
      const int d = f * 16 + fr;
#pragma unroll
      for (int r = 0; r < 4; ++r) {
        int q = q0 + wid * 32 + rr * 16 + hi * 4 + r;
        ymix[((size_t)b * 2048 + q) * 2048 + h * 128 + d] = __float2bfloat16(accO[rr][f][r]);
      }
    }
  }
}

// ---------------- launch ----------------
extern "C" void kernel_launch(void* const* d_in, const int* in_sizes, int n_in,
                              void* d_out, int out_size, void* d_ws, size_t ws_size,
                              hipStream_t stream) {
  const float* x    = (const float*)d_in[0];
  const float* cosb = (const float*)d_in[1];
  const float* sinb = (const float*)d_in[2];
  const float* Wq   = (const float*)d_in[3];
  const float* Wk   = (const float*)d_in[4];
  const float* Wv   = (const float*)d_in[5];
  const float* Wp   = (const float*)d_in[6];
  const float* mix1 = (const float*)d_in[7];
  const float* mix2 = (const float*)d_in[8];
  float* out = (float*)d_out;
  char* ws = (char*)d_ws;

  // workspace layout (bytes), peak ~80.2 MB
  __hip_bfloat16* xb   = (__hip_bfloat16*)(ws + 0);            // 16.78 MB; reused as ymix
  __hip_bfloat16* WTa  = (__hip_bfloat16*)(ws + 16777216);     // 12.58 MB
  __hip_bfloat16* WpT  = (__hip_bfloat16*)(ws + 29360128);     // 8.39 MB
  __hip_bfloat16* y1u  = (__hip_bfloat16*)(ws + 37748736);     // 16.78 MB
  float*          Mb   = (float*)(ws + 54525952);              // 0.26 MB
  float*          Lb   = (float*)(ws + 54788096);              // 0.26 MB
  __hip_bfloat16* qTb  = (__hip_bfloat16*)(ws + 55050240);     // 16.78 MB
  __hip_bfloat16* kTb  = (__hip_bfloat16*)(ws + 71827456);     // 4.19 MB
  __hip_bfloat16* vtb  = (__hip_bfloat16*)(ws + 76021760);     // 4.19 MB
  __hip_bfloat16* ymix = (__hip_bfloat16*)(ws + 0);

  dim3 tb(32, 8);
  cast_bf16_kernel<<<8192, 256, 0, stream>>>(x, xb, 2097152);
  wtrans_kernel<<<10240, tb, 0, stream>>>(Wq, Wk, Wv, Wp, WTa, WpT);

  // fused QKV projection + RoPE + RMS + V-transpose
  gemm_qkv_rope_kernel<<<768, 256, 0, stream>>>(xb, WTa, cosb, sinb, qTb, kTb, vtb);

  attn_pass1_kernel<<<512, 256, 0, stream>>>(qTb, kTb, vtb, y1u, Mb, Lb, mix1, mix2);
  attn_pass2_kernel<<<512, 256, 0, stream>>>(qTb, kTb, y1u, Mb, Lb, ymix);

  gemm_bf16_kernel<<<512, 256, 0, stream>>>(ymix, WpT, out, 4096, 2048, 2048);
}

// Round 10
// 262.021 us; speedup vs baseline: 1.1716x; 1.1323x over previous
//
#include <hip/hip_runtime.h>
#include <hip/hip_bf16.h>
#include <cstdint>
#include <cstddef>

#define AS1 __attribute__((address_space(1)))
#define AS3 __attribute__((address_space(3)))

typedef __attribute__((ext_vector_type(8))) short bf16x8;
typedef __attribute__((ext_vector_type(4))) float f32x4;

__device__ __forceinline__ void gload_lds16(const void* g, void* l) {
  __builtin_amdgcn_global_load_lds((const AS1 void*)g, (AS3 void*)l, 16, 0, 0);
}

#define MFMA_BF16(A, B, C) __builtin_amdgcn_mfma_f32_16x16x32_bf16((A), (B), (C), 0, 0, 0)

// (1/sqrt(128)) * log2(e) — folded into q at rope time; softmax runs in exp2 domain.
#define QSCALE 0.12751744f

__device__ __forceinline__ uint32_t pk2(float a, float b) {
  uint32_t ua = (uint32_t)__builtin_bit_cast(unsigned short, __float2bfloat16(a));
  uint32_t ub = (uint32_t)__builtin_bit_cast(unsigned short, __float2bfloat16(b));
  return ua | (ub << 16);
}
__device__ __forceinline__ float b2f(unsigned short u) {
  return __builtin_bit_cast(float, (uint32_t)u << 16);
}

// sum over 8 consecutive lanes (group-aligned): DPP xor1, xor2, half-mirror
__device__ __forceinline__ float red8_sum(float v) {
  int x;
  x = __builtin_amdgcn_update_dpp(0, __builtin_bit_cast(int, v), 0xB1, 0xF, 0xF, true);
  v += __builtin_bit_cast(float, x);
  x = __builtin_amdgcn_update_dpp(0, __builtin_bit_cast(int, v), 0x4E, 0xF, 0xF, true);
  v += __builtin_bit_cast(float, x);
  x = __builtin_amdgcn_update_dpp(0, __builtin_bit_cast(int, v), 0x141, 0xF, 0xF, true);
  v += __builtin_bit_cast(float, x);
  return v;
}

// ---------------- cast f32 -> bf16 ----------------
__global__ __launch_bounds__(256) void cast_bf16_kernel(const float* __restrict__ in,
                                                        __hip_bfloat16* __restrict__ out,
                                                        int n4) {
  int i = blockIdx.x * 256 + threadIdx.x;
  if (i < n4) {
    float4 v = ((const float4*)in)[i];
    __hip_bfloat16* o = out + (size_t)i * 4;
    o[0] = __float2bfloat16(v.x);
    o[1] = __float2bfloat16(v.y);
    o[2] = __float2bfloat16(v.z);
    o[3] = __float2bfloat16(v.w);
  }
}

// ---------------- merged weight transpose+cast (Wq,Wk,Wv,Wp in one launch) ----------------
__global__ __launch_bounds__(256) void wtrans_kernel(const float* __restrict__ Wq,
                                                     const float* __restrict__ Wk,
                                                     const float* __restrict__ Wv,
                                                     const float* __restrict__ Wp,
                                                     __hip_bfloat16* __restrict__ WTa,
                                                     __hip_bfloat16* __restrict__ WpT) {
  __shared__ float tile[32][33];
  int id = blockIdx.x;
  const float* in; __hip_bfloat16* out; int is, os, bx, by;
  if (id < 4096)      { in = Wq; out = WTa;                          is = 2048; os = 2048; bx = id & 63; by = id >> 6; }
  else if (id < 5120) { int t = id - 4096; in = Wk; out = WTa + (size_t)2048 * 2048; is = 512; os = 2048; bx = t & 15; by = t >> 4; }
  else if (id < 6144) { int t = id - 5120; in = Wv; out = WTa + (size_t)2560 * 2048; is = 512; os = 2048; bx = t & 15; by = t >> 4; }
  else                { int t = id - 6144; in = Wp; out = WpT;       is = 2048; os = 2048; bx = t & 63; by = t >> 6; }
  int c0 = bx * 32, r0 = by * 32;
  int tx = threadIdx.x, ty = threadIdx.y;
#pragma unroll
  for (int i = 0; i < 32; i += 8)
    tile[ty + i][tx] = in[(size_t)(r0 + ty + i) * is + c0 + tx];
  __syncthreads();
#pragma unroll
  for (int i = 0; i < 32; i += 8)
    out[(size_t)(c0 + ty + i) * os + r0 + tx] = __float2bfloat16(tile[tx][ty + i]);
}

// ---------------- qkv GEMM (2-phase counted-vmcnt dbuf) + fused RoPE+RMS epilogue ----------------
// C(4096x3072) = xb @ WTa^T, tile 128x128; col tile == one head.
// K-loop: dbuf A/B (32KB), STAGE(next) issued before compute, vmcnt(4) keeps the
// next tile's 4 loads in flight across the barrier (same schedule as attn passes).
// Epilogue: acc -> CL4 packed layout -> rope+rms (q/k) or transposed V store.
__global__ __launch_bounds__(256) void gemm_qkv_rope_kernel(
    const __hip_bfloat16* __restrict__ A,
    const __hip_bfloat16* __restrict__ Bt,
    const float* __restrict__ cosb,
    const float* __restrict__ sinb,
    __hip_bfloat16* __restrict__ qT,
    __hip_bfloat16* __restrict__ kT,
    __hip_bfloat16* __restrict__ vt) {
  __shared__ __align__(16) char smem[34048];          // A0|A1|B0|B1 during loop; CL4 after
  __hip_bfloat16* CL4 = (__hip_bfloat16*)smem;        // (quad*133+col)*4 + rr
  const int K = 2048;
  const int tid = threadIdx.x;
  const int lane = tid & 63;
  const int wid = tid >> 6;
  const int wm = wid >> 1, wn = wid & 1;
  const int nwg = gridDim.x;
  const int bid = blockIdx.x;
  const int swz = (bid & 7) * (nwg >> 3) + (bid >> 3);
  const int tm = swz / 24, tn = swz % 24;
  const int row0 = tm << 7, col0 = tn << 7;
  const int fr = lane & 15;
  const int hi = lane >> 4;
  const int kg = hi * 8;

  auto STAGE = [&](int buf, int k0) {                 // 4 loads/thread (2 A + 2 B)
#pragma unroll
    for (int i = 0; i < 2; ++i) {
      int f = i * 256 + tid;
      int r = f >> 2, s = f & 3;
      gload_lds16(A + (size_t)(row0 + r) * K + k0 + s * 8,
                  smem + buf * 8192 + (i * 256 + wid * 64) * 16);
      gload_lds16(Bt + (size_t)(col0 + r) * K + k0 + s * 8,
                  smem + 16384 + buf * 8192 + (i * 256 + wid * 64) * 16);
    }
  };

  f32x4 acc[4][4] = {};
  STAGE(0, 0);
  int cur = 0;
  for (int kk = 0; kk < 64; ++kk) {
    if (kk > 0) __builtin_amdgcn_s_barrier();         // WAR: compute(kk-1) closed
    __builtin_amdgcn_sched_barrier(0);
    if (kk + 1 < 64) STAGE(cur ^ 1, (kk + 1) * 32);
    __builtin_amdgcn_sched_barrier(0);
    if (kk + 1 < 64) asm volatile("s_waitcnt vmcnt(4)" ::: "memory");
    else             asm volatile("s_waitcnt vmcnt(0)" ::: "memory");
    __builtin_amdgcn_s_barrier();                     // tile(kk) landed for all waves
    __builtin_amdgcn_sched_barrier(0);
    const __hip_bfloat16* Ac = (const __hip_bfloat16*)(smem + cur * 8192);
    const __hip_bfloat16* Bc = (const __hip_bfloat16*)(smem + 16384 + cur * 8192);
    bf16x8 af[4], bfr[4];
#pragma unroll
    for (int m = 0; m < 4; ++m)
      af[m] = *(const bf16x8*)(Ac + (wm * 64 + m * 16 + fr) * 32 + kg);
#pragma unroll
    for (int n = 0; n < 4; ++n)
      bfr[n] = *(const bf16x8*)(Bc + (wn * 64 + n * 16 + fr) * 32 + kg);
#pragma unroll
    for (int m = 0; m < 4; ++m)
#pragma unroll
      for (int n = 0; n < 4; ++n)
        acc[m][n] = MFMA_BF16(af[m], bfr[n], acc[m][n]);
    cur ^= 1;
  }
  __syncthreads();                                    // staging reads done; reuse as CL4

  // ---- pack acc -> CL4: one b64 per fragment (4 consecutive rows, same col) ----
#pragma unroll
  for (int m = 0; m < 4; ++m)
#pragma unroll
    for (int n = 0; n < 4; ++n) {
      int q4 = wm * 16 + m * 4 + hi;                  // (row>>2)
      int col = wn * 64 + n * 16 + fr;
      *(uint2*)(CL4 + ((q4 * 133 + col) << 2)) =
          make_uint2(pk2(acc[m][n][0], acc[m][n][1]), pk2(acc[m][n][2], acc[m][n][3]));
    }
  __syncthreads();

  const int b = row0 >> 11;
  const int t0 = row0 & 2047;

  if (col0 >= 2560) {
    // ---- V: column gather from CL4, 128B-contiguous stores to (B,HK,HD,T) ----
    const int hv = (col0 - 2560) >> 7;
    __hip_bfloat16* vb = vt + (size_t)(b * 4 + hv) * 128 * 2048;
    const int col = tid >> 1, th = tid & 1;
    uint2 w[16];
#pragma unroll
    for (int qq = 0; qq < 16; ++qq)
      w[qq] = *(const uint2*)(CL4 + (((th * 16 + qq) * 133 + col) << 2));
    __hip_bfloat16* dstv = vb + (size_t)col * 2048 + t0 + th * 64;
#pragma unroll
    for (int e = 0; e < 8; ++e)
      *(uint4*)(dstv + e * 8) = make_uint4(w[2 * e].x, w[2 * e].y, w[2 * e + 1].x, w[2 * e + 1].y);
    return;
  }

  // ---- q/k: rope + rms. thread = (row-quad, 8-col-slice) ----
  const int quad = tid >> 3, cp = tid & 7;
  const int tb = t0 + quad * 4;
  bf16x8 lov[4], hiv[4];
#pragma unroll
  for (int e = 0; e < 4; ++e) {
    lov[e] = *(const bf16x8*)(CL4 + ((quad * 133 + cp * 8 + e * 2) << 2));
    hiv[e] = *(const bf16x8*)(CL4 + ((quad * 133 + 64 + cp * 8 + e * 2) << 2));
  }
  const float oscale = (col0 < 2048) ? QSCALE : 1.0f;
  __hip_bfloat16* dstq = (col0 < 2048)
      ? qT + (size_t)(b * 16 + (col0 >> 7)) * 2048 * 128
      : kT + (size_t)(b * 4 + ((col0 - 2048) >> 7)) * 2048 * 128;

  float o1v[4][8], o2v[4][8], ssum[4];
#pragma unroll
  for (int rr = 0; rr < 4; ++rr) {
    const float* cb = cosb + (size_t)(tb + rr) * 64 + cp * 8;
    const float* sb = sinb + (size_t)(tb + rr) * 64 + cp * 8;
    float4 c0 = *(const float4*)cb, c1 = *(const float4*)(cb + 4);
    float4 s0 = *(const float4*)sb, s1 = *(const float4*)(sb + 4);
    float cc[8] = {c0.x, c0.y, c0.z, c0.w, c1.x, c1.y, c1.z, c1.w};
    float sn[8] = {s0.x, s0.y, s0.z, s0.w, s1.x, s1.y, s1.z, s1.w};
    float ss = 0.f;
#pragma unroll
    for (int e = 0; e < 4; ++e)
#pragma unroll
      for (int w2 = 0; w2 < 2; ++w2) {
        int pd = e * 2 + w2;
        float x1 = b2f((unsigned short)lov[e][w2 * 4 + rr]);
        float x2 = b2f((unsigned short)hiv[e][w2 * 4 + rr]);
        float a = x1 * cc[pd] - x2 * sn[pd];
        float bb = x1 * sn[pd] + x2 * cc[pd];
        o1v[rr][pd] = a;
        o2v[rr][pd] = bb;
        ss += a * a + bb * bb;
      }
    ssum[rr] = ss;
  }
#pragma unroll
  for (int rr = 0; rr < 4; ++rr) {
    float rn = rsqrtf(red8_sum(ssum[rr]) * (1.f / 128.f) + 1e-6f) * oscale;
    __hip_bfloat16* dr = dstq + (size_t)(tb + rr) * 128 + cp * 8;
    *(uint4*)dr = make_uint4(pk2(o1v[rr][0] * rn, o1v[rr][1] * rn),
                             pk2(o1v[rr][2] * rn, o1v[rr][3] * rn),
                             pk2(o1v[rr][4] * rn, o1v[rr][5] * rn),
                             pk2(o1v[rr][6] * rn, o1v[rr][7] * rn));
    *(uint4*)(dr + 64) = make_uint4(pk2(o2v[rr][0] * rn, o2v[rr][1] * rn),
                                    pk2(o2v[rr][2] * rn, o2v[rr][3] * rn),
                                    pk2(o2v[rr][4] * rn, o2v[rr][5] * rn),
                                    pk2(o2v[rr][6] * rn, o2v[rr][7] * rn));
  }
}

// ---------------- generic bf16 GEMM (2-phase counted-vmcnt dbuf, f32 out) ----------------
__global__ __launch_bounds__(256) void gemm_bf16_kernel(const __hip_bfloat16* __restrict__ A,
                                                        const __hip_bfloat16* __restrict__ Bt,
                                                        float* __restrict__ C,
                                                        int M, int N, int K) {
  __shared__ __align__(16) char smem[32768];          // A0|A1|B0|B1
  const int tid = threadIdx.x;
  const int lane = tid & 63;
  const int wid = tid >> 6;
  const int wm = wid >> 1, wn = wid & 1;
  const int nwg = gridDim.x;
  const int bid = blockIdx.x;
  const int swz = (bid & 7) * (nwg >> 3) + (bid >> 3);
  const int ntile = N >> 7;
  const int tm = swz / ntile, tn = swz % ntile;
  const int row0 = tm << 7, col0 = tn << 7;

  const int fr = lane & 15;
  const int kg = (lane >> 4) * 8;

  auto STAGE = [&](int buf, int k0) {
#pragma unroll
    for (int i = 0; i < 2; ++i) {
      int f = i * 256 + tid;
      int r = f >> 2, s = f & 3;
      gload_lds16(A + (size_t)(row0 + r) * K + k0 + s * 8,
                  smem + buf * 8192 + (i * 256 + wid * 64) * 16);
      gload_lds16(Bt + (size_t)(col0 + r) * K + k0 + s * 8,
                  smem + 16384 + buf * 8192 + (i * 256 + wid * 64) * 16);
    }
  };

  f32x4 acc[4][4] = {};
  const int nk = K >> 5;
  STAGE(0, 0);
  int cur = 0;
  for (int kk = 0; kk < nk; ++kk) {
    if (kk > 0) __builtin_amdgcn_s_barrier();
    __builtin_amdgcn_sched_barrier(0);
    if (kk + 1 < nk) STAGE(cur ^ 1, (kk + 1) * 32);
    __builtin_amdgcn_sched_barrier(0);
    if (kk + 1 < nk) asm volatile("s_waitcnt vmcnt(4)" ::: "memory");
    else             asm volatile("s_waitcnt vmcnt(0)" ::: "memory");
    __builtin_amdgcn_s_barrier();
    __builtin_amdgcn_sched_barrier(0);
    const __hip_bfloat16* Ac = (const __hip_bfloat16*)(smem + cur * 8192);
    const __hip_bfloat16* Bc = (const __hip_bfloat16*)(smem + 16384 + cur * 8192);
    bf16x8 af[4], bfr[4];
#pragma unroll
    for (int m = 0; m < 4; ++m)
      af[m] = *(const bf16x8*)(Ac + (wm * 64 + m * 16 + fr) * 32 + kg);
#pragma unroll
    for (int n = 0; n < 4; ++n)
      bfr[n] = *(const bf16x8*)(Bc + (wn * 64 + n * 16 + fr) * 32 + kg);
#pragma unroll
    for (int m = 0; m < 4; ++m)
#pragma unroll
      for (int n = 0; n < 4; ++n)
        acc[m][n] = MFMA_BF16(af[m], bfr[n], acc[m][n]);
    cur ^= 1;
  }

  const int cr = (lane >> 4) * 4;
#pragma unroll
  for (int m = 0; m < 4; ++m)
#pragma unroll
    for (int n = 0; n < 4; ++n) {
      int col = col0 + wn * 64 + n * 16 + fr;
#pragma unroll
      for (int r = 0; r < 4; ++r) {
        int row = row0 + wm * 64 + m * 16 + cr + r;
        C[(size_t)row * N + col] = acc[m][n][r];
      }
    }
}

// block decode (both passes): bi in [0,512): u=bi&255, half=bi>>8. g=u&7 = (b*4+kvh).
// bi and bi+256 (two halves of a balanced 34-step pair) land on the same CU under rr
// dispatch: per-CU balance at 2 blocks/CU.

// ---------------- attention pass 1: y1 = softmax(qk^T) v ; writes u = mix1*v + mix2*y1 ----------------
__global__ __launch_bounds__(256, 2) void attn_pass1_kernel(
    const __hip_bfloat16* __restrict__ qT,   // (B,H,T,HD), q pre-scaled
    const __hip_bfloat16* __restrict__ kT,   // (B,HK,T,HD)
    const __hip_bfloat16* __restrict__ vt,   // (B,HK,HD,T)
    __hip_bfloat16* __restrict__ y1u,        // (B,H,HD,T)  u = mix1*v + mix2*y1
    float* __restrict__ Mb,                  // (B,H,T)  (exp2 domain)
    float* __restrict__ Lb,
    const float* __restrict__ mix1p,
    const float* __restrict__ mix2p) {
  __shared__ __align__(16) __hip_bfloat16 Ks[2][64 * 128];
  __shared__ __align__(16) __hip_bfloat16 Vs[2][128 * 64];
  __shared__ __align__(16) char Ps[4][32 * 128];
  const int tid = threadIdx.x, lane = tid & 63, wid = tid >> 6;   // wid 0..3
  const int bi = blockIdx.x;
  const int u = bi & 255, half = bi >> 8;
  const int g = u & 7;
  const int pslot = (u >> 3) & 7;
  const int bh = g * 4 + (u >> 6);
  const int j = half ? (15 - pslot) : pslot;
  const int q0 = j * 128;
  const int nt = 2 * j + 2;
  const int sd = 2 * j + (wid >> 1);         // wave's diagonal k-tile (rows wid*32..+31)
  const __hip_bfloat16* Kp = kT + (size_t)g * 2048 * 128;
  const __hip_bfloat16* Vp = vt + (size_t)g * 128 * 2048;
  const int fr = lane & 15, hi = lane >> 4;

  bf16x8 qf[2][4];
  {
    const __hip_bfloat16* Qp = qT + ((size_t)bh * 2048 + q0 + wid * 32) * 128;
#pragma unroll
    for (int rr = 0; rr < 2; ++rr)
#pragma unroll
      for (int dc = 0; dc < 4; ++dc)
        qf[rr][dc] = *(const bf16x8*)(Qp + (rr * 16 + fr) * 128 + dc * 32 + hi * 8);
  }

  f32x4 accO[2][8] = {};                     // accO[rr][f][r]: q=rr*16+hi*4+r, d=f*16+fr
  float m[2], l[2];                          // per q-row rr*16+fr (uniform across hi)
  m[0] = m[1] = -1e30f; l[0] = l[1] = 0.f;

  char* Pb = Ps[wid];

  auto STAGE = [&](int buf, int kt) {        // 8 global_load_lds (4 K + 4 V)
    const int k0 = kt * 64;
#pragma unroll
    for (int i = 0; i < 4; ++i) {
      int f = i * 256 + tid;
      int r = f >> 4, s = f & 15, sx = s ^ (r & 7);
      gload_lds16(Kp + (size_t)(k0 + r) * 128 + sx * 8,
                  (char*)Ks[buf] + (i * 256 + wid * 64) * 16);
    }
#pragma unroll
    for (int i = 0; i < 4; ++i) {
      int f = i * 256 + tid;
      int r = f >> 3, s = f & 7, sx = s ^ (r & 7);
      gload_lds16(Vp + (size_t)r * 2048 + k0 + sx * 8,
                  (char*)Vs[buf] + (i * 256 + wid * 64) * 16);
    }
  };

  STAGE(0, 0);
  int cur = 0;
  for (int s = 0; s < nt; ++s) {
    if (s > 0) __builtin_amdgcn_s_barrier();   // WAR: compute(s-1) closed
    __builtin_amdgcn_sched_barrier(0);
    if (s + 1 < nt) STAGE(cur ^ 1, s + 1);
    __builtin_amdgcn_sched_barrier(0);
    if (s + 1 < nt) asm volatile("s_waitcnt vmcnt(8)" ::: "memory");
    else            asm volatile("s_waitcnt vmcnt(0)" ::: "memory");
    __builtin_amdgcn_s_barrier();              // K(s),V(s) landed for all waves
    __builtin_amdgcn_sched_barrier(0);

    const bool active = (s <= sd);
    if (active) {
      // ---- QK (swapped): sf[rr][c][r] = S[q=rr*16+fr][k=c*16+hi*4+r] ----
      const char* Kc = (const char*)Ks[cur];
      f32x4 sf[2][4] = {};
      __builtin_amdgcn_s_setprio(1);
#pragma unroll
      for (int c = 0; c < 4; ++c) {
        const int krow = c * 16 + fr;
#pragma unroll
        for (int dc = 0; dc < 4; ++dc) {
          int slot = (dc * 4 + hi) ^ (krow & 7);
          bf16x8 kf = *(const bf16x8*)(Kc + krow * 256 + slot * 16);
          sf[0][c] = MFMA_BF16(kf, qf[0][dc], sf[0][c]);
          sf[1][c] = MFMA_BF16(kf, qf[1][dc], sf[1][c]);
        }
      }
      __builtin_amdgcn_s_setprio(0);
      // ---- mask (diagonal) + in-lane row max + cross-hi reduce ----
      float rmax[2];
#pragma unroll
      for (int rr = 0; rr < 2; ++rr) {
        if (s == sd) {
          const int qq = q0 + wid * 32 + rr * 16 + fr;
#pragma unroll
          for (int c = 0; c < 4; ++c) {
            const int kb = s * 64 + c * 16 + hi * 4;
#pragma unroll
            for (int r = 0; r < 4; ++r)
              if (kb + r > qq) sf[rr][c][r] = -1e30f;
          }
        }
        float v = -1e30f;
#pragma unroll
        for (int c = 0; c < 4; ++c)
#pragma unroll
          for (int r = 0; r < 4; ++r) v = fmaxf(v, sf[rr][c][r]);
        v = fmaxf(v, __shfl_xor(v, 16));
        v = fmaxf(v, __shfl_xor(v, 32));
        rmax[rr] = v;
      }
      // ---- T13 defer-max ----
      bool grow = (rmax[0] > m[0] + 8.f) | (rmax[1] > m[1] + 8.f);
      if (__any(grow)) {
        float a[2];
#pragma unroll
        for (int rr = 0; rr < 2; ++rr) {
          float mn = fmaxf(m[rr], rmax[rr]);
          a[rr] = __builtin_amdgcn_exp2f(m[rr] - mn);
          m[rr] = mn;
          l[rr] *= a[rr];
        }
#pragma unroll
        for (int rr = 0; rr < 2; ++rr)
#pragma unroll
          for (int r = 0; r < 4; ++r) {
            float aq = __shfl(a[rr], hi * 4 + r);   // a for q-row rr*16+hi*4+r
#pragma unroll
            for (int f = 0; f < 8; ++f) accO[rr][f][r] *= aq;
          }
      }
      // ---- exp2 + in-lane sum + cross-hi reduce ----
#pragma unroll
      for (int rr = 0; rr < 2; ++rr) {
        float rs = 0.f;
#pragma unroll
        for (int c = 0; c < 4; ++c)
#pragma unroll
          for (int r = 0; r < 4; ++r) {
            float p = __builtin_amdgcn_exp2f(sf[rr][c][r] - m[rr]);
            sf[rr][c][r] = p;
            rs += p;
          }
        rs += __shfl_xor(rs, 16);
        rs += __shfl_xor(rs, 32);
        l[rr] += rs;
      }
      // ---- P -> LDS: 8 packed b64 writes (swizzled 16B slots), read 4 b128 A-frags ----
#pragma unroll
      for (int rr = 0; rr < 2; ++rr) {
        const int row = rr * 16 + fr;
        char* Prow = Pb + row * 128;
#pragma unroll
        for (int c = 0; c < 4; ++c) {
          uint32_t w0 = pk2(sf[rr][c][0], sf[rr][c][1]);
          uint32_t w1 = pk2(sf[rr][c][2], sf[rr][c][3]);
          int sl = (c * 2 + (hi >> 1)) ^ (row & 7);
          *(uint2*)(Prow + sl * 16 + (hi & 1) * 8) = make_uint2(w0, w1);
        }
      }
      bf16x8 pf[2][2];
#pragma unroll
      for (int rr = 0; rr < 2; ++rr) {
        const int row = rr * 16 + fr;
#pragma unroll
        for (int kc = 0; kc < 2; ++kc) {
          int sl = (kc * 4 + hi) ^ (row & 7);
          pf[rr][kc] = *(const bf16x8*)(Pb + row * 128 + sl * 16);
        }
      }
      // ---- PV ----
      const __hip_bfloat16* Vc = Vs[cur];
      __builtin_amdgcn_s_setprio(1);
#pragma unroll
      for (int kc = 0; kc < 2; ++kc)
#pragma unroll
        for (int f = 0; f < 8; ++f) {
          int vrow = f * 16 + fr;
          int vslot = (kc * 4 + hi) ^ (fr & 7);
          bf16x8 vf = *(const bf16x8*)(Vc + vrow * 64 + vslot * 8);
          accO[0][f] = MFMA_BF16(pf[0][kc], vf, accO[0][f]);
          accO[1][f] = MFMA_BF16(pf[1][kc], vf, accO[1][f]);
        }
      __builtin_amdgcn_s_setprio(0);
    }
    cur ^= 1;
  }

  // ---- epilogue: u = mix1*v + mix2*(accO/l), d-major; store m,l ----
  const float m1v = mix1p[0], m2v = mix2p[0];
  float rlq[2][4];
#pragma unroll
  for (int rr = 0; rr < 2; ++rr) {
    float inv = 1.f / l[rr];
#pragma unroll
    for (int r = 0; r < 4; ++r) rlq[rr][r] = __shfl(inv, hi * 4 + r);
  }
  const int t0 = q0 + wid * 32;
#pragma unroll
  for (int rr = 0; rr < 2; ++rr) {
    const int tb = t0 + rr * 16 + hi * 4;
#pragma unroll
    for (int f = 0; f < 8; ++f) {
      const int d = f * 16 + fr;
      const ushort4 v4 = *(const ushort4*)(vt + ((size_t)g * 128 + d) * 2048 + tb);
      float u0 = m1v * b2f(v4.x) + m2v * (accO[rr][f][0] * rlq[rr][0]);
      float u1 = m1v * b2f(v4.y) + m2v * (accO[rr][f][1] * rlq[rr][1]);
      float u2 = m1v * b2f(v4.z) + m2v * (accO[rr][f][2] * rlq[rr][2]);
      float u3 = m1v * b2f(v4.w) + m2v * (accO[rr][f][3] * rlq[rr][3]);
      *(uint2*)(y1u + ((size_t)bh * 128 + d) * 2048 + tb) =
          make_uint2(pk2(u0, u1), pk2(u2, u3));
    }
  }
  if (hi == 0) {
#pragma unroll
    for (int rr = 0; rr < 2; ++rr) {
      Mb[(size_t)bh * 2048 + t0 + rr * 16 + fr] = m[rr];
      Lb[(size_t)bh * 2048 + t0 + rr * 16 + fr] = l[rr];
    }
  }
}

// ---------------- attention pass 2: ymix = att @ u  (direct final output) ----------------
__global__ __launch_bounds__(256, 2) void attn_pass2_kernel(
    const __hip_bfloat16* __restrict__ qT,
    const __hip_bfloat16* __restrict__ kT,
    const __hip_bfloat16* __restrict__ y1u,  // (B,H,HD,T)
    const float* __restrict__ Mb,
    const float* __restrict__ Lb,
    __hip_bfloat16* __restrict__ ymix) {     // (B,T,C)
  __shared__ __align__(16) __hip_bfloat16 Ks[2][64 * 128];
  __shared__ __align__(16) __hip_bfloat16 Vs[2][128 * 64];
  __shared__ __align__(16) char Ps[4][32 * 128];
  const int tid = threadIdx.x, lane = tid & 63, wid = tid >> 6;
  const int bi = blockIdx.x;
  const int u = bi & 255, half = bi >> 8;
  const int g = u & 7;
  const int pslot = (u >> 3) & 7;
  const int bh = g * 4 + (u >> 6);
  const int h = bh & 15, b = bh >> 4;
  const int j = half ? (15 - pslot) : pslot;
  const int q0 = j * 128;
  const int nt = 2 * j + 2;
  const int sd = 2 * j + (wid >> 1);
  const __hip_bfloat16* Kp = kT + (size_t)g * 2048 * 128;
  const __hip_bfloat16* Yp = y1u + (size_t)bh * 128 * 2048;
  const int fr = lane & 15, hi = lane >> 4;

  bf16x8 qf[2][4];
  float mr[2], rl[2];
  {
    const __hip_bfloat16* Qp = qT + ((size_t)bh * 2048 + q0 + wid * 32) * 128;
#pragma unroll
    for (int rr = 0; rr < 2; ++rr)
#pragma unroll
      for (int dc = 0; dc < 4; ++dc)
        qf[rr][dc] = *(const bf16x8*)(Qp + (rr * 16 + fr) * 128 + dc * 32 + hi * 8);
    const size_t qb = (size_t)bh * 2048 + q0 + wid * 32;
    mr[0] = Mb[qb + fr];        mr[1] = Mb[qb + 16 + fr];
    rl[0] = 1.f / Lb[qb + fr];  rl[1] = 1.f / Lb[qb + 16 + fr];
  }

  f32x4 accO[2][8] = {};
  char* Pb = Ps[wid];

  auto STAGE = [&](int buf, int kt) {
    const int k0 = kt * 64;
#pragma unroll
    for (int i = 0; i < 4; ++i) {
      int f = i * 256 + tid;
      int r = f >> 4, s = f & 15, sx = s ^ (r & 7);
      gload_lds16(Kp + (size_t)(k0 + r) * 128 + sx * 8,
                  (char*)Ks[buf] + (i * 256 + wid * 64) * 16);
    }
#pragma unroll
    for (int i = 0; i < 4; ++i) {
      int f = i * 256 + tid;
      int r = f >> 3, s = f & 7, sx = s ^ (r & 7);
      gload_lds16(Yp + (size_t)r * 2048 + k0 + sx * 8,
                  (char*)Vs[buf] + (i * 256 + wid * 64) * 16);
    }
  };

  STAGE(0, 0);
  int cur = 0;
  for (int s = 0; s < nt; ++s) {
    if (s > 0) __builtin_amdgcn_s_barrier();
    __builtin_amdgcn_sched_barrier(0);
    if (s + 1 < nt) STAGE(cur ^ 1, s + 1);
    __builtin_amdgcn_sched_barrier(0);
    if (s + 1 < nt) asm volatile("s_waitcnt vmcnt(8)" ::: "memory");
    else            asm volatile("s_waitcnt vmcnt(0)" ::: "memory");
    __builtin_amdgcn_s_barrier();
    __builtin_amdgcn_sched_barrier(0);

    const bool active = (s <= sd);
    if (active) {
      const char* Kc = (const char*)Ks[cur];
      f32x4 sf[2][4] = {};
      __builtin_amdgcn_s_setprio(1);
#pragma unroll
      for (int c = 0; c < 4; ++c) {
        const int krow = c * 16 + fr;
#pragma unroll
        for (int dc = 0; dc < 4; ++dc) {
          int slot = (dc * 4 + hi) ^ (krow & 7);
          bf16x8 kf = *(const bf16x8*)(Kc + krow * 256 + slot * 16);
          sf[0][c] = MFMA_BF16(kf, qf[0][dc], sf[0][c]);
          sf[1][c] = MFMA_BF16(kf, qf[1][dc], sf[1][c]);
        }
      }
      __builtin_amdgcn_s_setprio(0);
      // normalize P directly from stored stats (all fr-indexed, no shuffles)
#pragma unroll
      for (int rr = 0; rr < 2; ++rr) {
        if (s == sd) {
          const int qq = q0 + wid * 32 + rr * 16 + fr;
#pragma unroll
          for (int c = 0; c < 4; ++c) {
            const int kb = s * 64 + c * 16 + hi * 4;
#pragma unroll
            for (int r = 0; r < 4; ++r)
              if (kb + r > qq) sf[rr][c][r] = -1e30f;
          }
        }
#pragma unroll
        for (int c = 0; c < 4; ++c)
#pragma unroll
          for (int r = 0; r < 4; ++r)
            sf[rr][c][r] = __builtin_amdgcn_exp2f(sf[rr][c][r] - mr[rr]) * rl[rr];
      }
#pragma unroll
      for (int rr = 0; rr < 2; ++rr) {
        const int row = rr * 16 + fr;
        char* Prow = Pb + row * 128;
#pragma unroll
        for (int c = 0; c < 4; ++c) {
          uint32_t w0 = pk2(sf[rr][c][0], sf[rr][c][1]);
          uint32_t w1 = pk2(sf[rr][c][2], sf[rr][c][3]);
          int sl = (c * 2 + (hi >> 1)) ^ (row & 7);
          *(uint2*)(Prow + sl * 16 + (hi & 1) * 8) = make_uint2(w0, w1);
        }
      }
      bf16x8 pf[2][2];
#pragma unroll
      for (int rr = 0; rr < 2; ++rr) {
        const int row = rr * 16 + fr;
#pragma unroll
        for (int kc = 0; kc < 2; ++kc) {
          int sl = (kc * 4 + hi) ^ (row & 7);
          pf[rr][kc] = *(const bf16x8*)(Pb + row * 128 + sl * 16);
        }
      }
      const __hip_bfloat16* Vc = Vs[cur];
      __builtin_amdgcn_s_setprio(1);
#pragma unroll
      for (int kc = 0; kc < 2; ++kc)
#pragma unroll
        for (int f = 0; f < 8; ++f) {
          int vrow = f * 16 + fr;
          int vslot = (kc * 4 + hi) ^ (fr & 7);
          bf16x8 vf = *(const bf16x8*)(Vc + vrow * 64 + vslot * 8);
          accO[0][f] = MFMA_BF16(pf[0][kc], vf, accO[0][f]);
          accO[1][f] = MFMA_BF16(pf[1][kc], vf, accO[1][f]);
        }
      __builtin_amdgcn_s_setprio(0);
    }
    cur ^= 1;
  }

  // accO already IS the final mixed output (P pre-normalized, u pre-mixed)
#pragma unroll
  for (int rr = 0; rr < 2; ++rr) {
#pragma unroll
    for (int f = 0; f < 8; ++f) {
      const int d = f * 16 + fr;
#pragma unroll
      for (int r = 0; r < 4; ++r) {
        int q = q0 + wid * 32 + rr * 16 + hi * 4 + r;
        ymix[((size_t)b * 2048 + q) * 2048 + h * 128 + d] = __float2bfloat16(accO[rr][f][r]);
      }
    }
  }
}

// ---------------- launch ----------------
extern "C" void kernel_launch(void* const* d_in, const int* in_sizes, int n_in,
                              void* d_out, int out_size, void* d_ws, size_t ws_size,
                              hipStream_t stream) {
  const float* x    = (const float*)d_in[0];
  const float* cosb = (const float*)d_in[1];
  const float* sinb = (const float*)d_in[2];
  const float* Wq   = (const float*)d_in[3];
  const float* Wk   = (const float*)d_in[4];
  const float* Wv   = (const float*)d_in[5];
  const float* Wp   = (const float*)d_in[6];
  const float* mix1 = (const float*)d_in[7];
  const float* mix2 = (const float*)d_in[8];
  float* out = (float*)d_out;
  char* ws = (char*)d_ws;

  // workspace layout (bytes), peak ~80.2 MB
  __hip_bfloat16* xb   = (__hip_bfloat16*)(ws + 0);            // 16.78 MB; reused as ymix
  __hip_bfloat16* WTa  = (__hip_bfloat16*)(ws + 16777216);     // 12.58 MB
  __hip_bfloat16* WpT  = (__hip_bfloat16*)(ws + 29360128);     // 8.39 MB
  __hip_bfloat16* y1u  = (__hip_bfloat16*)(ws + 37748736);     // 16.78 MB
  float*          Mb   = (float*)(ws + 54525952);              // 0.26 MB
  float*          Lb   = (float*)(ws + 54788096);              // 0.26 MB
  __hip_bfloat16* qTb  = (__hip_bfloat16*)(ws + 55050240);     // 16.78 MB
  __hip_bfloat16* kTb  = (__hip_bfloat16*)(ws + 71827456);     // 4.19 MB
  __hip_bfloat16* vtb  = (__hip_bfloat16*)(ws + 76021760);     // 4.19 MB
  __hip_bfloat16* ymix = (__hip_bfloat16*)(ws + 0);

  dim3 tb(32, 8);
  cast_bf16_kernel<<<8192, 256, 0, stream>>>(x, xb, 2097152);
  wtrans_kernel<<<10240, tb, 0, stream>>>(Wq, Wk, Wv, Wp, WTa, WpT);

  // fused QKV projection + RoPE + RMS + V-transpose
  gemm_qkv_rope_kernel<<<768, 256, 0, stream>>>(xb, WTa, cosb, sinb, qTb, kTb, vtb);

  attn_pass1_kernel<<<512, 256, 0, stream>>>(qTb, kTb, vtb, y1u, Mb, Lb, mix1, mix2);
  attn_pass2_kernel<<<512, 256, 0, stream>>>(qTb, kTb, y1u, Mb, Lb, ymix);

  gemm_bf16_kernel<<<512, 256, 0, stream>>>(ymix, WpT, out, 4096, 2048, 2048);
}

// Round 11
// 259.092 us; speedup vs baseline: 1.1849x; 1.0113x over previous
//
#include <hip/hip_runtime.h>
#include <hip/hip_bf16.h>
#include <cstdint>
#include <cstddef>

#define AS1 __attribute__((address_space(1)))
#define AS3 __attribute__((address_space(3)))

typedef __attribute__((ext_vector_type(8))) short bf16x8;
typedef __attribute__((ext_vector_type(4))) float f32x4;

__device__ __forceinline__ void gload_lds16(const void* g, void* l) {
  __builtin_amdgcn_global_load_lds((const AS1 void*)g, (AS3 void*)l, 16, 0, 0);
}

#define MFMA_BF16(A, B, C) __builtin_amdgcn_mfma_f32_16x16x32_bf16((A), (B), (C), 0, 0, 0)

// (1/sqrt(128)) * log2(e) — folded into q at rope time; softmax runs in exp2 domain.
#define QSCALE 0.12751744f

__device__ __forceinline__ uint32_t pk2(float a, float b) {
  uint32_t ua = (uint32_t)__builtin_bit_cast(unsigned short, __float2bfloat16(a));
  uint32_t ub = (uint32_t)__builtin_bit_cast(unsigned short, __float2bfloat16(b));
  return ua | (ub << 16);
}
__device__ __forceinline__ float b2f(unsigned short u) {
  return __builtin_bit_cast(float, (uint32_t)u << 16);
}
// extract bf16 element rr (0..3) from a packed uint2 (4 row-values)
__device__ __forceinline__ float elem4(uint2 w, int rr) {
  uint32_t v = (rr & 2) ? w.y : w.x;
  uint32_t u = (rr & 1) ? (v >> 16) : (v & 0xffffu);
  return __builtin_bit_cast(float, u << 16);
}

// sum over aligned 4-lane groups: DPP quad_perm xor1, xor2
__device__ __forceinline__ float red4_sum(float v) {
  int x;
  x = __builtin_amdgcn_update_dpp(0, __builtin_bit_cast(int, v), 0xB1, 0xF, 0xF, true);
  v += __builtin_bit_cast(float, x);
  x = __builtin_amdgcn_update_dpp(0, __builtin_bit_cast(int, v), 0x4E, 0xF, 0xF, true);
  v += __builtin_bit_cast(float, x);
  return v;
}

// ---------------- cast f32 -> bf16 ----------------
__global__ __launch_bounds__(256) void cast_bf16_kernel(const float* __restrict__ in,
                                                        __hip_bfloat16* __restrict__ out,
                                                        int n4) {
  int i = blockIdx.x * 256 + threadIdx.x;
  if (i < n4) {
    float4 v = ((const float4*)in)[i];
    __hip_bfloat16* o = out + (size_t)i * 4;
    o[0] = __float2bfloat16(v.x);
    o[1] = __float2bfloat16(v.y);
    o[2] = __float2bfloat16(v.z);
    o[3] = __float2bfloat16(v.w);
  }
}

// ---------------- merged weight transpose+cast (Wq,Wk,Wv,Wp in one launch) ----------------
__global__ __launch_bounds__(256) void wtrans_kernel(const float* __restrict__ Wq,
                                                     const float* __restrict__ Wk,
                                                     const float* __restrict__ Wv,
                                                     const float* __restrict__ Wp,
                                                     __hip_bfloat16* __restrict__ WTa,
                                                     __hip_bfloat16* __restrict__ WpT) {
  __shared__ float tile[32][33];
  int id = blockIdx.x;
  const float* in; __hip_bfloat16* out; int is, os, bx, by;
  if (id < 4096)      { in = Wq; out = WTa;                          is = 2048; os = 2048; bx = id & 63; by = id >> 6; }
  else if (id < 5120) { int t = id - 4096; in = Wk; out = WTa + (size_t)2048 * 2048; is = 512; os = 2048; bx = t & 15; by = t >> 4; }
  else if (id < 6144) { int t = id - 5120; in = Wv; out = WTa + (size_t)2560 * 2048; is = 512; os = 2048; bx = t & 15; by = t >> 4; }
  else                { int t = id - 6144; in = Wp; out = WpT;       is = 2048; os = 2048; bx = t & 63; by = t >> 6; }
  int c0 = bx * 32, r0 = by * 32;
  int tx = threadIdx.x, ty = threadIdx.y;
#pragma unroll
  for (int i = 0; i < 32; i += 8)
    tile[ty + i][tx] = in[(size_t)(r0 + ty + i) * is + c0 + tx];
  __syncthreads();
#pragma unroll
  for (int i = 0; i < 32; i += 8)
    out[(size_t)(c0 + ty + i) * os + r0 + tx] = __float2bfloat16(tile[tx][ty + i]);
}

// ---------------- qkv GEMM: 256x256 tile, BK=64, 8 waves, 2-phase counted-vmcnt ----------------
// C(4096x3072) = xb @ WTa^T. Wave tile 128x64 (2M x 4N wave grid).
// A/B staged with 16B-slot XOR swizzle (source-swizzled, linear LDS dest, swizzled read)
// to kill the 16-way conflict of 128B row stride. Grid 16x12=192, 1 block/CU.
// Epilogue: acc -> CL4 ([64 quads][257] packed) -> rope+rms (q/k, 2 heads/tile) or V store.
__global__ __launch_bounds__(512, 2) void gemm_qkv_rope_kernel(
    const __hip_bfloat16* __restrict__ A,
    const __hip_bfloat16* __restrict__ Bt,
    const float* __restrict__ cosb,
    const float* __restrict__ sinb,
    __hip_bfloat16* __restrict__ qT,
    __hip_bfloat16* __restrict__ kT,
    __hip_bfloat16* __restrict__ vt) {
  // stage: A0 @0, A1 @32768, B0 @65536, B1 @98304 (128KB). epilogue: CL4 (128.5KB).
  __shared__ __align__(16) char smem[131584];
  __hip_bfloat16* CL4 = (__hip_bfloat16*)smem;    // elem idx = (q4*257+col)*4 + rr
  const int K = 2048;
  const int tid = threadIdx.x;
  const int lane = tid & 63;
  const int wid = tid >> 6;                       // 0..7
  const int wm = wid >> 2, wn = wid & 3;
  const int bid = blockIdx.x;
  const int swz = (bid & 7) * 24 + (bid >> 3);    // nwg=192, XCD-contiguous
  const int tm = swz / 12, tn = swz % 12;
  const int row0 = tm << 8, col0 = tn << 8;
  const int fr = lane & 15, hi = lane >> 4;

  auto STAGE = [&](int buf, int k0) {             // 8 gload_lds / thread
#pragma unroll
    for (int i = 0; i < 4; ++i) {
      int f = i * 512 + tid;
      int r = f >> 3, s = f & 7, sx = s ^ (r & 7);
      gload_lds16(A + (size_t)(row0 + r) * K + k0 + sx * 8,
                  smem + buf * 32768 + f * 16);
    }
#pragma unroll
    for (int i = 0; i < 4; ++i) {
      int f = i * 512 + tid;
      int r = f >> 3, s = f & 7, sx = s ^ (r & 7);
      gload_lds16(Bt + (size_t)(col0 + r) * K + k0 + sx * 8,
                  smem + 65536 + buf * 32768 + f * 16);
    }
  };

  f32x4 acc[8][4] = {};
  STAGE(0, 0);
  int cur = 0;
  for (int kk = 0; kk < 32; ++kk) {
    if (kk > 0) __builtin_amdgcn_s_barrier();     // WAR: compute(kk-1) closed
    __builtin_amdgcn_sched_barrier(0);
    if (kk + 1 < 32) STAGE(cur ^ 1, (kk + 1) * 64);
    __builtin_amdgcn_sched_barrier(0);
    if (kk + 1 < 32) asm volatile("s_waitcnt vmcnt(8)" ::: "memory");
    else             asm volatile("s_waitcnt vmcnt(0)" ::: "memory");
    __builtin_amdgcn_s_barrier();                 // tile(kk) landed for all waves
    __builtin_amdgcn_sched_barrier(0);
    const char* Ac = smem + cur * 32768;
    const char* Bc = smem + 65536 + cur * 32768;
#pragma unroll
    for (int kh = 0; kh < 2; ++kh) {              // K=64 in two 32-halves
      bf16x8 bfr[4];
#pragma unroll
      for (int n = 0; n < 4; ++n) {
        int rowb = wn * 64 + n * 16 + fr;
        int sl = (kh * 4 + hi) ^ (rowb & 7);
        bfr[n] = *(const bf16x8*)(Bc + rowb * 128 + sl * 16);
      }
      __builtin_amdgcn_s_setprio(1);
#pragma unroll
      for (int m = 0; m < 8; ++m) {
        int rowa = wm * 128 + m * 16 + fr;
        int sl = (kh * 4 + hi) ^ (rowa & 7);
        bf16x8 af = *(const bf16x8*)(Ac + rowa * 128 + sl * 16);
#pragma unroll
        for (int n = 0; n < 4; ++n)
          acc[m][n] = MFMA_BF16(af, bfr[n], acc[m][n]);
      }
      __builtin_amdgcn_s_setprio(0);
    }
    cur ^= 1;
  }
  __syncthreads();                                // staging reads done; reuse as CL4

  // ---- pack acc -> CL4: one b64 per fragment (4 consecutive rows, same col) ----
#pragma unroll
  for (int m = 0; m < 8; ++m)
#pragma unroll
    for (int n = 0; n < 4; ++n) {
      int q4 = wm * 32 + m * 4 + hi;              // (row>>2), row = wm*128+m*16+hi*4+r
      int col = wn * 64 + n * 16 + fr;
      *(uint2*)(CL4 + ((q4 * 257 + col) << 2)) =
          make_uint2(pk2(acc[m][n][0], acc[m][n][1]), pk2(acc[m][n][2], acc[m][n][3]));
    }
  __syncthreads();

  const int b = row0 >> 11;
  const int t0 = row0 & 2047;

  if (tn >= 10) {
    // ---- V (2 heads): column gather, 256B-contiguous stores to (B,HK,HD,T) ----
    const int col = tid >> 1, th = tid & 1;       // th: row strip 128
    const int hv = ((col0 - 2560) >> 7) + (col >> 7);
    const int d = col & 127;
    __hip_bfloat16* dstv = vt + ((size_t)(b * 4 + hv) * 128 + d) * 2048 + t0 + th * 128;
    uint2 w[32];
#pragma unroll
    for (int qq = 0; qq < 32; ++qq)
      w[qq] = *(const uint2*)(CL4 + (((th * 32 + qq) * 257 + col) << 2));
#pragma unroll
    for (int e = 0; e < 16; ++e)
      *(uint4*)(dstv + e * 8) =
          make_uint4(w[2 * e].x, w[2 * e].y, w[2 * e + 1].x, w[2 * e + 1].y);
    return;
  }

  // ---- q/k (2 heads): rope + rms. thread = (row-quad, head, 16-pair-slice) ----
  const int quad = tid >> 3, cp = tid & 7;        // 64 quads x 8
  const int hh = cp >> 2, sub = cp & 3;           // head half, pair-slice
  const float oscale = (tn < 8) ? QSCALE : 1.0f;
  __hip_bfloat16* headbuf;
  if (tn < 8) headbuf = qT + (size_t)(b * 16 + 2 * tn + hh) * 2048 * 128;
  else        headbuf = kT + (size_t)(b * 4 + ((col0 - 2048) >> 7) + hh) * 2048 * 128;

  uint2 lo[16], hi2[16];
#pragma unroll
  for (int jj = 0; jj < 16; ++jj) {
    int colL = hh * 128 + sub * 16 + jj;
    lo[jj]  = *(const uint2*)(CL4 + ((quad * 257 + colL) << 2));
    hi2[jj] = *(const uint2*)(CL4 + ((quad * 257 + colL + 64) << 2));
  }
  const int tb = t0 + quad * 4;
#pragma unroll
  for (int rr = 0; rr < 4; ++rr) {
    const float* cb = cosb + (size_t)(tb + rr) * 64 + sub * 16;
    const float* sb = sinb + (size_t)(tb + rr) * 64 + sub * 16;
    float cc[16], sn[16];
#pragma unroll
    for (int e = 0; e < 4; ++e) {
      float4 c4 = *(const float4*)(cb + e * 4);
      float4 s4 = *(const float4*)(sb + e * 4);
      cc[e * 4 + 0] = c4.x; cc[e * 4 + 1] = c4.y; cc[e * 4 + 2] = c4.z; cc[e * 4 + 3] = c4.w;
      sn[e * 4 + 0] = s4.x; sn[e * 4 + 1] = s4.y; sn[e * 4 + 2] = s4.z; sn[e * 4 + 3] = s4.w;
    }
    float o1[16], o2[16];
    float ss = 0.f;
#pragma unroll
    for (int jj = 0; jj < 16; ++jj) {
      float x1 = elem4(lo[jj], rr);
      float x2 = elem4(hi2[jj], rr);
      float a = x1 * cc[jj] - x2 * sn[jj];
      float bb = x1 * sn[jj] + x2 * cc[jj];
      o1[jj] = a; o2[jj] = bb;
      ss += a * a + bb * bb;
    }
    ss = red4_sum(ss);                            // across the 4 sub-lanes of this head
    float rn = rsqrtf(ss * (1.f / 128.f) + 1e-6f) * oscale;
    __hip_bfloat16* dr = headbuf + (size_t)(tb + rr) * 128 + sub * 16;
    *(uint4*)dr = make_uint4(pk2(o1[0] * rn, o1[1] * rn), pk2(o1[2] * rn, o1[3] * rn),
                             pk2(o1[4] * rn, o1[5] * rn), pk2(o1[6] * rn, o1[7] * rn));
    *(uint4*)(dr + 8) = make_uint4(pk2(o1[8] * rn, o1[9] * rn), pk2(o1[10] * rn, o1[11] * rn),
                                   pk2(o1[12] * rn, o1[13] * rn), pk2(o1[14] * rn, o1[15] * rn));
    *(uint4*)(dr + 64) = make_uint4(pk2(o2[0] * rn, o2[1] * rn), pk2(o2[2] * rn, o2[3] * rn),
                                    pk2(o2[4] * rn, o2[5] * rn), pk2(o2[6] * rn, o2[7] * rn));
    *(uint4*)(dr + 72) = make_uint4(pk2(o2[8] * rn, o2[9] * rn), pk2(o2[10] * rn, o2[11] * rn),
                                    pk2(o2[12] * rn, o2[13] * rn), pk2(o2[14] * rn, o2[15] * rn));
  }
}

// ---------------- generic bf16 GEMM (2-phase counted-vmcnt dbuf, f32 out) ----------------
__global__ __launch_bounds__(256) void gemm_bf16_kernel(const __hip_bfloat16* __restrict__ A,
                                                        const __hip_bfloat16* __restrict__ Bt,
                                                        float* __restrict__ C,
                                                        int M, int N, int K) {
  __shared__ __align__(16) char smem[32768];          // A0|A1|B0|B1
  const int tid = threadIdx.x;
  const int lane = tid & 63;
  const int wid = tid >> 6;
  const int wm = wid >> 1, wn = wid & 1;
  const int nwg = gridDim.x;
  const int bid = blockIdx.x;
  const int swz = (bid & 7) * (nwg >> 3) + (bid >> 3);
  const int ntile = N >> 7;
  const int tm = swz / ntile, tn = swz % ntile;
  const int row0 = tm << 7, col0 = tn << 7;

  const int fr = lane & 15;
  const int kg = (lane >> 4) * 8;

  auto STAGE = [&](int buf, int k0) {
#pragma unroll
    for (int i = 0; i < 2; ++i) {
      int f = i * 256 + tid;
      int r = f >> 2, s = f & 3;
      gload_lds16(A + (size_t)(row0 + r) * K + k0 + s * 8,
                  smem + buf * 8192 + (i * 256 + wid * 64) * 16);
      gload_lds16(Bt + (size_t)(col0 + r) * K + k0 + s * 8,
                  smem + 16384 + buf * 8192 + (i * 256 + wid * 64) * 16);
    }
  };

  f32x4 acc[4][4] = {};
  const int nk = K >> 5;
  STAGE(0, 0);
  int cur = 0;
  for (int kk = 0; kk < nk; ++kk) {
    if (kk > 0) __builtin_amdgcn_s_barrier();
    __builtin_amdgcn_sched_barrier(0);
    if (kk + 1 < nk) STAGE(cur ^ 1, (kk + 1) * 32);
    __builtin_amdgcn_sched_barrier(0);
    if (kk + 1 < nk) asm volatile("s_waitcnt vmcnt(4)" ::: "memory");
    else             asm volatile("s_waitcnt vmcnt(0)" ::: "memory");
    __builtin_amdgcn_s_barrier();
    __builtin_amdgcn_sched_barrier(0);
    const __hip_bfloat16* Ac = (const __hip_bfloat16*)(smem + cur * 8192);
    const __hip_bfloat16* Bc = (const __hip_bfloat16*)(smem + 16384 + cur * 8192);
    bf16x8 af[4], bfr[4];
#pragma unroll
    for (int m = 0; m < 4; ++m)
      af[m] = *(const bf16x8*)(Ac + (wm * 64 + m * 16 + fr) * 32 + kg);
#pragma unroll
    for (int n = 0; n < 4; ++n)
      bfr[n] = *(const bf16x8*)(Bc + (wn * 64 + n * 16 + fr) * 32 + kg);
#pragma unroll
    for (int m = 0; m < 4; ++m)
#pragma unroll
      for (int n = 0; n < 4; ++n)
        acc[m][n] = MFMA_BF16(af[m], bfr[n], acc[m][n]);
    cur ^= 1;
  }

  const int cr = (lane >> 4) * 4;
#pragma unroll
  for (int m = 0; m < 4; ++m)
#pragma unroll
    for (int n = 0; n < 4; ++n) {
      int col = col0 + wn * 64 + n * 16 + fr;
#pragma unroll
      for (int r = 0; r < 4; ++r) {
        int row = row0 + wm * 64 + m * 16 + cr + r;
        C[(size_t)row * N + col] = acc[m][n][r];
      }
    }
}

// block decode (both passes): bi in [0,512): u=bi&255, half=bi>>8. g=u&7 = (b*4+kvh).
// bi and bi+256 (two halves of a balanced 34-step pair) land on the same CU under rr
// dispatch: per-CU balance at 2 blocks/CU.

// ---------------- attention pass 1: y1 = softmax(qk^T) v ; writes u = mix1*v + mix2*y1 ----------------
__global__ __launch_bounds__(256, 2) void attn_pass1_kernel(
    const __hip_bfloat16* __restrict__ qT,   // (B,H,T,HD), q pre-scaled
    const __hip_bfloat16* __restrict__ kT,   // (B,HK,T,HD)
    const __hip_bfloat16* __restrict__ vt,   // (B,HK,HD,T)
    __hip_bfloat16* __restrict__ y1u,        // (B,H,HD,T)  u = mix1*v + mix2*y1
    float* __restrict__ Mb,                  // (B,H,T)  (exp2 domain)
    float* __restrict__ Lb,
    const float* __restrict__ mix1p,
    const float* __restrict__ mix2p) {
  __shared__ __align__(16) __hip_bfloat16 Ks[2][64 * 128];
  __shared__ __align__(16) __hip_bfloat16 Vs[2][128 * 64];
  __shared__ __align__(16) char Ps[4][32 * 128];
  const int tid = threadIdx.x, lane = tid & 63, wid = tid >> 6;   // wid 0..3
  const int bi = blockIdx.x;
  const int u = bi & 255, half = bi >> 8;
  const int g = u & 7;
  const int pslot = (u >> 3) & 7;
  const int bh = g * 4 + (u >> 6);
  const int j = half ? (15 - pslot) : pslot;
  const int q0 = j * 128;
  const int nt = 2 * j + 2;
  const int sd = 2 * j + (wid >> 1);         // wave's diagonal k-tile (rows wid*32..+31)
  const __hip_bfloat16* Kp = kT + (size_t)g * 2048 * 128;
  const __hip_bfloat16* Vp = vt + (size_t)g * 128 * 2048;
  const int fr = lane & 15, hi = lane >> 4;

  bf16x8 qf[2][4];
  {
    const __hip_bfloat16* Qp = qT + ((size_t)bh * 2048 + q0 + wid * 32) * 128;
#pragma unroll
    for (int rr = 0; rr < 2; ++rr)
#pragma unroll
      for (int dc = 0; dc < 4; ++dc)
        qf[rr][dc] = *(const bf16x8*)(Qp + (rr * 16 + fr) * 128 + dc * 32 + hi * 8);
  }

  f32x4 accO[2][8] = {};                     // accO[rr][f][r]: q=rr*16+hi*4+r, d=f*16+fr
  float m[2], l[2];                          // per q-row rr*16+fr (uniform across hi)
  m[0] = m[1] = -1e30f; l[0] = l[1] = 0.f;

  char* Pb = Ps[wid];

  auto STAGE = [&](int buf, int kt) {        // 8 global_load_lds (4 K + 4 V)
    const int k0 = kt * 64;
#pragma unroll
    for (int i = 0; i < 4; ++i) {
      int f = i * 256 + tid;
      int r = f >> 4, s = f & 15, sx = s ^ (r & 7);
      gload_lds16(Kp + (size_t)(k0 + r) * 128 + sx * 8,
                  (char*)Ks[buf] + (i * 256 + wid * 64) * 16);
    }
#pragma unroll
    for (int i = 0; i < 4; ++i) {
      int f = i * 256 + tid;
      int r = f >> 3, s = f & 7, sx = s ^ (r & 7);
      gload_lds16(Vp + (size_t)r * 2048 + k0 + sx * 8,
                  (char*)Vs[buf] + (i * 256 + wid * 64) * 16);
    }
  };

  STAGE(0, 0);
  int cur = 0;
  for (int s = 0; s < nt; ++s) {
    if (s > 0) __builtin_amdgcn_s_barrier();   // WAR: compute(s-1) closed
    __builtin_amdgcn_sched_barrier(0);
    if (s + 1 < nt) STAGE(cur ^ 1, s + 1);
    __builtin_amdgcn_sched_barrier(0);
    if (s + 1 < nt) asm volatile("s_waitcnt vmcnt(8)" ::: "memory");
    else            asm volatile("s_waitcnt vmcnt(0)" ::: "memory");
    __builtin_amdgcn_s_barrier();              // K(s),V(s) landed for all waves
    __builtin_amdgcn_sched_barrier(0);

    const bool active = (s <= sd);
    if (active) {
      // ---- QK (swapped): sf[rr][c][r] = S[q=rr*16+fr][k=c*16+hi*4+r] ----
      const char* Kc = (const char*)Ks[cur];
      f32x4 sf[2][4] = {};
      __builtin_amdgcn_s_setprio(1);
#pragma unroll
      for (int c = 0; c < 4; ++c) {
        const int krow = c * 16 + fr;
#pragma unroll
        for (int dc = 0; dc < 4; ++dc) {
          int slot = (dc * 4 + hi) ^ (krow & 7);
          bf16x8 kf = *(const bf16x8*)(Kc + krow * 256 + slot * 16);
          sf[0][c] = MFMA_BF16(kf, qf[0][dc], sf[0][c]);
          sf[1][c] = MFMA_BF16(kf, qf[1][dc], sf[1][c]);
        }
      }
      __builtin_amdgcn_s_setprio(0);
      // ---- mask (diagonal) + in-lane row max + cross-hi reduce ----
      float rmax[2];
#pragma unroll
      for (int rr = 0; rr < 2; ++rr) {
        if (s == sd) {
          const int qq = q0 + wid * 32 + rr * 16 + fr;
#pragma unroll
          for (int c = 0; c < 4; ++c) {
            const int kb = s * 64 + c * 16 + hi * 4;
#pragma unroll
            for (int r = 0; r < 4; ++r)
              if (kb + r > qq) sf[rr][c][r] = -1e30f;
          }
        }
        float v = -1e30f;
#pragma unroll
        for (int c = 0; c < 4; ++c)
#pragma unroll
          for (int r = 0; r < 4; ++r) v = fmaxf(v, sf[rr][c][r]);
        v = fmaxf(v, __shfl_xor(v, 16));
        v = fmaxf(v, __shfl_xor(v, 32));
        rmax[rr] = v;
      }
      // ---- T13 defer-max ----
      bool grow = (rmax[0] > m[0] + 8.f) | (rmax[1] > m[1] + 8.f);
      if (__any(grow)) {
        float a[2];
#pragma unroll
        for (int rr = 0; rr < 2; ++rr) {
          float mn = fmaxf(m[rr], rmax[rr]);
          a[rr] = __builtin_amdgcn_exp2f(m[rr] - mn);
          m[rr] = mn;
          l[rr] *= a[rr];
        }
#pragma unroll
        for (int rr = 0; rr < 2; ++rr)
#pragma unroll
          for (int r = 0; r < 4; ++r) {
            float aq = __shfl(a[rr], hi * 4 + r);   // a for q-row rr*16+hi*4+r
#pragma unroll
            for (int f = 0; f < 8; ++f) accO[rr][f][r] *= aq;
          }
      }
      // ---- exp2 + in-lane sum + cross-hi reduce ----
#pragma unroll
      for (int rr = 0; rr < 2; ++rr) {
        float rs = 0.f;
#pragma unroll
        for (int c = 0; c < 4; ++c)
#pragma unroll
          for (int r = 0; r < 4; ++r) {
            float p = __builtin_amdgcn_exp2f(sf[rr][c][r] - m[rr]);
            sf[rr][c][r] = p;
            rs += p;
          }
        rs += __shfl_xor(rs, 16);
        rs += __shfl_xor(rs, 32);
        l[rr] += rs;
      }
      // ---- P -> LDS: 8 packed b64 writes (swizzled 16B slots), read 4 b128 A-frags ----
#pragma unroll
      for (int rr = 0; rr < 2; ++rr) {
        const int row = rr * 16 + fr;
        char* Prow = Pb + row * 128;
#pragma unroll
        for (int c = 0; c < 4; ++c) {
          uint32_t w0 = pk2(sf[rr][c][0], sf[rr][c][1]);
          uint32_t w1 = pk2(sf[rr][c][2], sf[rr][c][3]);
          int sl = (c * 2 + (hi >> 1)) ^ (row & 7);
          *(uint2*)(Prow + sl * 16 + (hi & 1) * 8) = make_uint2(w0, w1);
        }
      }
      bf16x8 pf[2][2];
#pragma unroll
      for (int rr = 0; rr < 2; ++rr) {
        const int row = rr * 16 + fr;
#pragma unroll
        for (int kc = 0; kc < 2; ++kc) {
          int sl = (kc * 4 + hi) ^ (row & 7);
          pf[rr][kc] = *(const bf16x8*)(Pb + row * 128 + sl * 16);
        }
      }
      // ---- PV ----
      const __hip_bfloat16* Vc = Vs[cur];
      __builtin_amdgcn_s_setprio(1);
#pragma unroll
      for (int kc = 0; kc < 2; ++kc)
#pragma unroll
        for (int f = 0; f < 8; ++f) {
          int vrow = f * 16 + fr;
          int vslot = (kc * 4 + hi) ^ (fr & 7);
          bf16x8 vf = *(const bf16x8*)(Vc + vrow * 64 + vslot * 8);
          accO[0][f] = MFMA_BF16(pf[0][kc], vf, accO[0][f]);
          accO[1][f] = MFMA_BF16(pf[1][kc], vf, accO[1][f]);
        }
      __builtin_amdgcn_s_setprio(0);
    }
    cur ^= 1;
  }

  // ---- epilogue: u = mix1*v + mix2*(accO/l), d-major; store m,l ----
  const float m1v = mix1p[0], m2v = mix2p[0];
  float rlq[2][4];
#pragma unroll
  for (int rr = 0; rr < 2; ++rr) {
    float inv = 1.f / l[rr];
#pragma unroll
    for (int r = 0; r < 4; ++r) rlq[rr][r] = __shfl(inv, hi * 4 + r);
  }
  const int t0 = q0 + wid * 32;
#pragma unroll
  for (int rr = 0; rr < 2; ++rr) {
    const int tb = t0 + rr * 16 + hi * 4;
#pragma unroll
    for (int f = 0; f < 8; ++f) {
      const int d = f * 16 + fr;
      const ushort4 v4 = *(const ushort4*)(vt + ((size_t)g * 128 + d) * 2048 + tb);
      float u0 = m1v * b2f(v4.x) + m2v * (accO[rr][f][0] * rlq[rr][0]);
      float u1 = m1v * b2f(v4.y) + m2v * (accO[rr][f][1] * rlq[rr][1]);
      float u2 = m1v * b2f(v4.z) + m2v * (accO[rr][f][2] * rlq[rr][2]);
      float u3 = m1v * b2f(v4.w) + m2v * (accO[rr][f][3] * rlq[rr][3]);
      *(uint2*)(y1u + ((size_t)bh * 128 + d) * 2048 + tb) =
          make_uint2(pk2(u0, u1), pk2(u2, u3));
    }
  }
  if (hi == 0) {
#pragma unroll
    for (int rr = 0; rr < 2; ++rr) {
      Mb[(size_t)bh * 2048 + t0 + rr * 16 + fr] = m[rr];
      Lb[(size_t)bh * 2048 + t0 + rr * 16 + fr] = l[rr];
    }
  }
}

// ---------------- attention pass 2: ymix = att @ u  (direct final output) ----------------
__global__ __launch_bounds__(256, 2) void attn_pass2_kernel(
    const __hip_bfloat16* __restrict__ qT,
    const __hip_bfloat16* __restrict__ kT,
    const __hip_bfloat16* __restrict__ y1u,  // (B,H,HD,T)
    const float* __restrict__ Mb,
    const float* __restrict__ Lb,
    __hip_bfloat16* __restrict__ ymix) {     // (B,T,C)
  __shared__ __align__(16) __hip_bfloat16 Ks[2][64 * 128];
  __shared__ __align__(16) __hip_bfloat16 Vs[2][128 * 64];
  __shared__ __align__(16) char Ps[4][32 * 128];
  const int tid = threadIdx.x, lane = tid & 63, wid = tid >> 6;
  const int bi = blockIdx.x;
  const int u = bi & 255, half = bi >> 8;
  const int g = u & 7;
  const int pslot = (u >> 3) & 7;
  const int bh = g * 4 + (u >> 6);
  const int h = bh & 15, b = bh >> 4;
  const int j = half ? (15 - pslot) : pslot;
  const int q0 = j * 128;
  const int nt = 2 * j + 2;
  const int sd = 2 * j + (wid >> 1);
  const __hip_bfloat16* Kp = kT + (size_t)g * 2048 * 128;
  const __hip_bfloat16* Yp = y1u + (size_t)bh * 128 * 2048;
  const int fr = lane & 15, hi = lane >> 4;

  bf16x8 qf[2][4];
  float mr[2], rl[2];
  {
    const __hip_bfloat16* Qp = qT + ((size_t)bh * 2048 + q0 + wid * 32) * 128;
#pragma unroll
    for (int rr = 0; rr < 2; ++rr)
#pragma unroll
      for (int dc = 0; dc < 4; ++dc)
        qf[rr][dc] = *(const bf16x8*)(Qp + (rr * 16 + fr) * 128 + dc * 32 + hi * 8);
    const size_t qb = (size_t)bh * 2048 + q0 + wid * 32;
    mr[0] = Mb[qb + fr];        mr[1] = Mb[qb + 16 + fr];
    rl[0] = 1.f / Lb[qb + fr];  rl[1] = 1.f / Lb[qb + 16 + fr];
  }

  f32x4 accO[2][8] = {};
  char* Pb = Ps[wid];

  auto STAGE = [&](int buf, int kt) {
    const int k0 = kt * 64;
#pragma unroll
    for (int i = 0; i < 4; ++i) {
      int f = i * 256 + tid;
      int r = f >> 4, s = f & 15, sx = s ^ (r & 7);
      gload_lds16(Kp + (size_t)(k0 + r) * 128 + sx * 8,
                  (char*)Ks[buf] + (i * 256 + wid * 64) * 16);
    }
#pragma unroll
    for (int i = 0; i < 4; ++i) {
      int f = i * 256 + tid;
      int r = f >> 3, s = f & 7, sx = s ^ (r & 7);
      gload_lds16(Yp + (size_t)r * 2048 + k0 + sx * 8,
                  (char*)Vs[buf] + (i * 256 + wid * 64) * 16);
    }
  };

  STAGE(0, 0);
  int cur = 0;
  for (int s = 0; s < nt; ++s) {
    if (s > 0) __builtin_amdgcn_s_barrier();
    __builtin_amdgcn_sched_barrier(0);
    if (s + 1 < nt) STAGE(cur ^ 1, s + 1);
    __builtin_amdgcn_sched_barrier(0);
    if (s + 1 < nt) asm volatile("s_waitcnt vmcnt(8)" ::: "memory");
    else            asm volatile("s_waitcnt vmcnt(0)" ::: "memory");
    __builtin_amdgcn_s_barrier();
    __builtin_amdgcn_sched_barrier(0);

    const bool active = (s <= sd);
    if (active) {
      const char* Kc = (const char*)Ks[cur];
      f32x4 sf[2][4] = {};
      __builtin_amdgcn_s_setprio(1);
#pragma unroll
      for (int c = 0; c < 4; ++c) {
        const int krow = c * 16 + fr;
#pragma unroll
        for (int dc = 0; dc < 4; ++dc) {
          int slot = (dc * 4 + hi) ^ (krow & 7);
          bf16x8 kf = *(const bf16x8*)(Kc + krow * 256 + slot * 16);
          sf[0][c] = MFMA_BF16(kf, qf[0][dc], sf[0][c]);
          sf[1][c] = MFMA_BF16(kf, qf[1][dc], sf[1][c]);
        }
      }
      __builtin_amdgcn_s_setprio(0);
      // normalize P directly from stored stats (all fr-indexed, no shuffles)
#pragma unroll
      for (int rr = 0; rr < 2; ++rr) {
        if (s == sd) {
          const int qq = q0 + wid * 32 + rr * 16 + fr;
#pragma unroll
          for (int c = 0; c < 4; ++c) {
            const int kb = s * 64 + c * 16 + hi * 4;
#pragma unroll
            for (int r = 0; r < 4; ++r)
              if (kb + r > qq) sf[rr][c][r] = -1e30f;
          }
        }
#pragma unroll
        for (int c = 0; c < 4; ++c)
#pragma unroll
          for (int r = 0; r < 4; ++r)
            sf[rr][c][r] = __builtin_amdgcn_exp2f(sf[rr][c][r] - mr[rr]) * rl[rr];
      }
#pragma unroll
      for (int rr = 0; rr < 2; ++rr) {
        const int row = rr * 16 + fr;
        char* Prow = Pb + row * 128;
#pragma unroll
        for (int c = 0; c < 4; ++c) {
          uint32_t w0 = pk2(sf[rr][c][0], sf[rr][c][1]);
          uint32_t w1 = pk2(sf[rr][c][2], sf[rr][c][3]);
          int sl = (c * 2 + (hi >> 1)) ^ (row & 7);
          *(uint2*)(Prow + sl * 16 + (hi & 1) * 8) = make_uint2(w0, w1);
        }
      }
      bf16x8 pf[2][2];
#pragma unroll
      for (int rr = 0; rr < 2; ++rr) {
        const int row = rr * 16 + fr;
#pragma unroll
        for (int kc = 0; kc < 2; ++kc) {
          int sl = (kc * 4 + hi) ^ (row & 7);
          pf[rr][kc] = *(const bf16x8*)(Pb + row * 128 + sl * 16);
        }
      }
      const __hip_bfloat16* Vc = Vs[cur];
      __builtin_amdgcn_s_setprio(1);
#pragma unroll
      for (int kc = 0; kc < 2; ++kc)
#pragma unroll
        for (int f = 0; f < 8; ++f) {
          int vrow = f * 16 + fr;
          int vslot = (kc * 4 + hi) ^ (fr & 7);
          bf16x8 vf = *(const bf16x8*)(Vc + vrow * 64 + vslot * 8);
          accO[0][f] = MFMA_BF16(pf[0][kc], vf, accO[0][f]);
          accO[1][f] = MFMA_BF16(pf[1][kc], vf, accO[1][f]);
        }
      __builtin_amdgcn_s_setprio(0);
    }
    cur ^= 1;
  }

  // accO already IS the final mixed output (P pre-normalized, u pre-mixed)
#pragma unroll
  for (int rr = 0; rr < 2; ++rr) {
#pragma unroll
    for (int f = 0; f < 8; ++f) {
      const int d = f * 16 + fr;
#pragma unroll
      for (int r = 0; r < 4; ++r) {
        int q = q0 + wid * 32 + rr * 16 + hi * 4 + r;
        ymix[((size_t)b * 2048 + q) * 2048 + h * 128 + d] = __float2bfloat16(accO[rr][f][r]);
      }
    }
  }
}

// ---------------- launch ----------------
extern "C" void kernel_launch(void* const* d_in, const int* in_sizes, int n_in,
                              void* d_out, int out_size, void* d_ws, size_t ws_size,
                              hipStream_t stream) {
  const float* x    = (const float*)d_in[0];
  const float* cosb = (const float*)d_in[1];
  const float* sinb = (const float*)d_in[2];
  const float* Wq   = (const float*)d_in[3];
  const float* Wk   = (const float*)d_in[4];
  const float* Wv   = (const float*)d_in[5];
  const float* Wp   = (const float*)d_in[6];
  const float* mix1 = (const float*)d_in[7];
  const float* mix2 = (const float*)d_in[8];
  float* out = (float*)d_out;
  char* ws = (char*)d_ws;

  // workspace layout (bytes), peak ~80.2 MB
  __hip_bfloat16* xb   = (__hip_bfloat16*)(ws + 0);            // 16.78 MB; reused as ymix
  __hip_bfloat16* WTa  = (__hip_bfloat16*)(ws + 16777216);     // 12.58 MB
  __hip_bfloat16* WpT  = (__hip_bfloat16*)(ws + 29360128);     // 8.39 MB
  __hip_bfloat16* y1u  = (__hip_bfloat16*)(ws + 37748736);     // 16.78 MB
  float*          Mb   = (float*)(ws + 54525952);              // 0.26 MB
  float*          Lb   = (float*)(ws + 54788096);              // 0.26 MB
  __hip_bfloat16* qTb  = (__hip_bfloat16*)(ws + 55050240);     // 16.78 MB
  __hip_bfloat16* kTb  = (__hip_bfloat16*)(ws + 71827456);     // 4.19 MB
  __hip_bfloat16* vtb  = (__hip_bfloat16*)(ws + 76021760);     // 4.19 MB
  __hip_bfloat16* ymix = (__hip_bfloat16*)(ws + 0);

  dim3 tb(32, 8);
  cast_bf16_kernel<<<8192, 256, 0, stream>>>(x, xb, 2097152);
  wtrans_kernel<<<10240, tb, 0, stream>>>(Wq, Wk, Wv, Wp, WTa, WpT);

  // fused QKV projection + RoPE + RMS + V-transpose (256x256 tiles, 192 blocks)
  gemm_qkv_rope_kernel<<<192, 512, 0, stream>>>(xb, WTa, cosb, sinb, qTb, kTb, vtb);

  attn_pass1_kernel<<<512, 256, 0, stream>>>(qTb, kTb, vtb, y1u, Mb, Lb, mix1, mix2);
  attn_pass2_kernel<<<512, 256, 0, stream>>>(qTb, kTb, y1u, Mb, Lb, ymix);

  gemm_bf16_kernel<<<512, 256, 0, stream>>>(ymix, WpT, out, 4096, 2048, 2048);
}

// Round 12
// 252.671 us; speedup vs baseline: 1.2150x; 1.0254x over previous
//
#include <hip/hip_runtime.h>
#include <hip/hip_bf16.h>
#include <cstdint>
#include <cstddef>

#define AS1 __attribute__((address_space(1)))
#define AS3 __attribute__((address_space(3)))

typedef __attribute__((ext_vector_type(8))) short bf16x8;
typedef __attribute__((ext_vector_type(4))) float f32x4;

__device__ __forceinline__ void gload_lds16(const void* g, void* l) {
  __builtin_amdgcn_global_load_lds((const AS1 void*)g, (AS3 void*)l, 16, 0, 0);
}

#define MFMA_BF16(A, B, C) __builtin_amdgcn_mfma_f32_16x16x32_bf16((A), (B), (C), 0, 0, 0)

// (1/sqrt(128)) * log2(e) — folded into q at rope time; softmax runs in exp2 domain.
#define QSCALE 0.12751744f

__device__ __forceinline__ uint32_t pk2(float a, float b) {
  uint32_t ua = (uint32_t)__builtin_bit_cast(unsigned short, __float2bfloat16(a));
  uint32_t ub = (uint32_t)__builtin_bit_cast(unsigned short, __float2bfloat16(b));
  return ua | (ub << 16);
}
__device__ __forceinline__ float b2f(unsigned short u) {
  return __builtin_bit_cast(float, (uint32_t)u << 16);
}
// extract bf16 element rr (0..3) from a packed uint2 (4 row-values)
__device__ __forceinline__ float elem4(uint2 w, int rr) {
  uint32_t v = (rr & 2) ? w.y : w.x;
  uint32_t u = (rr & 1) ? (v >> 16) : (v & 0xffffu);
  return __builtin_bit_cast(float, u << 16);
}

// sum over aligned 4-lane groups: DPP quad_perm xor1, xor2
__device__ __forceinline__ float red4_sum(float v) {
  int x;
  x = __builtin_amdgcn_update_dpp(0, __builtin_bit_cast(int, v), 0xB1, 0xF, 0xF, true);
  v += __builtin_bit_cast(float, x);
  x = __builtin_amdgcn_update_dpp(0, __builtin_bit_cast(int, v), 0x4E, 0xF, 0xF, true);
  v += __builtin_bit_cast(float, x);
  return v;
}

// ---------------- merged prep: x cast + weight transposes in one launch ----------------
__global__ __launch_bounds__(256) void prep_kernel(const float* __restrict__ x,
                                                   __hip_bfloat16* __restrict__ xb,
                                                   const float* __restrict__ Wq,
                                                   const float* __restrict__ Wk,
                                                   const float* __restrict__ Wv,
                                                   const float* __restrict__ Wp,
                                                   __hip_bfloat16* __restrict__ WTa,
                                                   __hip_bfloat16* __restrict__ WpT) {
  __shared__ float tile[32][33];
  int id = blockIdx.x;
  int tx = threadIdx.x, ty = threadIdx.y;
  if (id < 8192) {             // cast: 8192 blocks x 256 f32x4
    int i = id * 256 + ty * 32 + tx;
    float4 v = ((const float4*)x)[i];
    __hip_bfloat16* o = xb + (size_t)i * 4;
    o[0] = __float2bfloat16(v.x);
    o[1] = __float2bfloat16(v.y);
    o[2] = __float2bfloat16(v.z);
    o[3] = __float2bfloat16(v.w);
    return;
  }
  id -= 8192;
  const float* in; __hip_bfloat16* out; int is, os, bx, by;
  if (id < 4096)      { in = Wq; out = WTa;                          is = 2048; os = 2048; bx = id & 63; by = id >> 6; }
  else if (id < 5120) { int t = id - 4096; in = Wk; out = WTa + (size_t)2048 * 2048; is = 512; os = 2048; bx = t & 15; by = t >> 4; }
  else if (id < 6144) { int t = id - 5120; in = Wv; out = WTa + (size_t)2560 * 2048; is = 512; os = 2048; bx = t & 15; by = t >> 4; }
  else                { int t = id - 6144; in = Wp; out = WpT;       is = 2048; os = 2048; bx = t & 63; by = t >> 6; }
  int c0 = bx * 32, r0 = by * 32;
#pragma unroll
  for (int i = 0; i < 32; i += 8)
    tile[ty + i][tx] = in[(size_t)(r0 + ty + i) * is + c0 + tx];
  __syncthreads();
#pragma unroll
  for (int i = 0; i < 32; i += 8)
    out[(size_t)(c0 + ty + i) * os + r0 + tx] = __float2bfloat16(tile[tx][ty + i]);
}

// ---------------- qkv GEMM: 256x256 tile, BK=64, 8 waves, 2-phase counted-vmcnt ----------------
__global__ __launch_bounds__(512, 2) void gemm_qkv_rope_kernel(
    const __hip_bfloat16* __restrict__ A,
    const __hip_bfloat16* __restrict__ Bt,
    const float* __restrict__ cosb,
    const float* __restrict__ sinb,
    __hip_bfloat16* __restrict__ qT,
    __hip_bfloat16* __restrict__ kT,
    __hip_bfloat16* __restrict__ vt) {
  __shared__ __align__(16) char smem[131584];
  __hip_bfloat16* CL4 = (__hip_bfloat16*)smem;    // elem idx = (q4*257+col)*4 + rr
  const int K = 2048;
  const int tid = threadIdx.x;
  const int lane = tid & 63;
  const int wid = tid >> 6;                       // 0..7
  const int wm = wid >> 2, wn = wid & 3;
  const int bid = blockIdx.x;
  const int swz = (bid & 7) * 24 + (bid >> 3);    // nwg=192, XCD-contiguous
  const int tm = swz / 12, tn = swz % 12;
  const int row0 = tm << 8, col0 = tn << 8;
  const int fr = lane & 15, hi = lane >> 4;

  auto STAGE = [&](int buf, int k0) {             // 8 gload_lds / thread
#pragma unroll
    for (int i = 0; i < 4; ++i) {
      int f = i * 512 + tid;
      int r = f >> 3, s = f & 7, sx = s ^ (r & 7);
      gload_lds16(A + (size_t)(row0 + r) * K + k0 + sx * 8,
                  smem + buf * 32768 + f * 16);
    }
#pragma unroll
    for (int i = 0; i < 4; ++i) {
      int f = i * 512 + tid;
      int r = f >> 3, s = f & 7, sx = s ^ (r & 7);
      gload_lds16(Bt + (size_t)(col0 + r) * K + k0 + sx * 8,
                  smem + 65536 + buf * 32768 + f * 16);
    }
  };

  f32x4 acc[8][4] = {};
  STAGE(0, 0);
  int cur = 0;
  for (int kk = 0; kk < 32; ++kk) {
    if (kk > 0) __builtin_amdgcn_s_barrier();     // WAR: compute(kk-1) closed
    __builtin_amdgcn_sched_barrier(0);
    if (kk + 1 < 32) STAGE(cur ^ 1, (kk + 1) * 64);
    __builtin_amdgcn_sched_barrier(0);
    if (kk + 1 < 32) asm volatile("s_waitcnt vmcnt(8)" ::: "memory");
    else             asm volatile("s_waitcnt vmcnt(0)" ::: "memory");
    __builtin_amdgcn_s_barrier();                 // tile(kk) landed for all waves
    __builtin_amdgcn_sched_barrier(0);
    const char* Ac = smem + cur * 32768;
    const char* Bc = smem + 65536 + cur * 32768;
#pragma unroll
    for (int kh = 0; kh < 2; ++kh) {              // K=64 in two 32-halves
      bf16x8 bfr[4];
#pragma unroll
      for (int n = 0; n < 4; ++n) {
        int rowb = wn * 64 + n * 16 + fr;
        int sl = (kh * 4 + hi) ^ (rowb & 7);
        bfr[n] = *(const bf16x8*)(Bc + rowb * 128 + sl * 16);
      }
      __builtin_amdgcn_s_setprio(1);
#pragma unroll
      for (int m = 0; m < 8; ++m) {
        int rowa = wm * 128 + m * 16 + fr;
        int sl = (kh * 4 + hi) ^ (rowa & 7);
        bf16x8 af = *(const bf16x8*)(Ac + rowa * 128 + sl * 16);
#pragma unroll
        for (int n = 0; n < 4; ++n)
          acc[m][n] = MFMA_BF16(af, bfr[n], acc[m][n]);
      }
      __builtin_amdgcn_s_setprio(0);
    }
    cur ^= 1;
  }
  __syncthreads();                                // staging reads done; reuse as CL4

  // ---- pack acc -> CL4 ----
#pragma unroll
  for (int m = 0; m < 8; ++m)
#pragma unroll
    for (int n = 0; n < 4; ++n) {
      int q4 = wm * 32 + m * 4 + hi;
      int col = wn * 64 + n * 16 + fr;
      *(uint2*)(CL4 + ((q4 * 257 + col) << 2)) =
          make_uint2(pk2(acc[m][n][0], acc[m][n][1]), pk2(acc[m][n][2], acc[m][n][3]));
    }
  __syncthreads();

  const int b = row0 >> 11;
  const int t0 = row0 & 2047;

  if (tn >= 10) {
    // ---- V (2 heads): column gather, 256B-contiguous stores ----
    const int col = tid >> 1, th = tid & 1;
    const int hv = ((col0 - 2560) >> 7) + (col >> 7);
    const int d = col & 127;
    __hip_bfloat16* dstv = vt + ((size_t)(b * 4 + hv) * 128 + d) * 2048 + t0 + th * 128;
    uint2 w[32];
#pragma unroll
    for (int qq = 0; qq < 32; ++qq)
      w[qq] = *(const uint2*)(CL4 + (((th * 32 + qq) * 257 + col) << 2));
#pragma unroll
    for (int e = 0; e < 16; ++e)
      *(uint4*)(dstv + e * 8) =
          make_uint4(w[2 * e].x, w[2 * e].y, w[2 * e + 1].x, w[2 * e + 1].y);
    return;
  }

  // ---- q/k (2 heads): rope + rms ----
  const int quad = tid >> 3, cp = tid & 7;
  const int hh = cp >> 2, sub = cp & 3;
  const float oscale = (tn < 8) ? QSCALE : 1.0f;
  __hip_bfloat16* headbuf;
  if (tn < 8) headbuf = qT + (size_t)(b * 16 + 2 * tn + hh) * 2048 * 128;
  else        headbuf = kT + (size_t)(b * 4 + ((col0 - 2048) >> 7) + hh) * 2048 * 128;

  uint2 lo[16], hi2[16];
#pragma unroll
  for (int jj = 0; jj < 16; ++jj) {
    int colL = hh * 128 + sub * 16 + jj;
    lo[jj]  = *(const uint2*)(CL4 + ((quad * 257 + colL) << 2));
    hi2[jj] = *(const uint2*)(CL4 + ((quad * 257 + colL + 64) << 2));
  }
  const int tb = t0 + quad * 4;
#pragma unroll
  for (int rr = 0; rr < 4; ++rr) {
    const float* cb = cosb + (size_t)(tb + rr) * 64 + sub * 16;
    const float* sb = sinb + (size_t)(tb + rr) * 64 + sub * 16;
    float cc[16], sn[16];
#pragma unroll
    for (int e = 0; e < 4; ++e) {
      float4 c4 = *(const float4*)(cb + e * 4);
      float4 s4 = *(const float4*)(sb + e * 4);
      cc[e * 4 + 0] = c4.x; cc[e * 4 + 1] = c4.y; cc[e * 4 + 2] = c4.z; cc[e * 4 + 3] = c4.w;
      sn[e * 4 + 0] = s4.x; sn[e * 4 + 1] = s4.y; sn[e * 4 + 2] = s4.z; sn[e * 4 + 3] = s4.w;
    }
    float o1[16], o2[16];
    float ss = 0.f;
#pragma unroll
    for (int jj = 0; jj < 16; ++jj) {
      float x1 = elem4(lo[jj], rr);
      float x2 = elem4(hi2[jj], rr);
      float a = x1 * cc[jj] - x2 * sn[jj];
      float bb = x1 * sn[jj] + x2 * cc[jj];
      o1[jj] = a; o2[jj] = bb;
      ss += a * a + bb * bb;
    }
    ss = red4_sum(ss);
    float rn = rsqrtf(ss * (1.f / 128.f) + 1e-6f) * oscale;
    __hip_bfloat16* dr = headbuf + (size_t)(tb + rr) * 128 + sub * 16;
    *(uint4*)dr = make_uint4(pk2(o1[0] * rn, o1[1] * rn), pk2(o1[2] * rn, o1[3] * rn),
                             pk2(o1[4] * rn, o1[5] * rn), pk2(o1[6] * rn, o1[7] * rn));
    *(uint4*)(dr + 8) = make_uint4(pk2(o1[8] * rn, o1[9] * rn), pk2(o1[10] * rn, o1[11] * rn),
                                   pk2(o1[12] * rn, o1[13] * rn), pk2(o1[14] * rn, o1[15] * rn));
    *(uint4*)(dr + 64) = make_uint4(pk2(o2[0] * rn, o2[1] * rn), pk2(o2[2] * rn, o2[3] * rn),
                                    pk2(o2[4] * rn, o2[5] * rn), pk2(o2[6] * rn, o2[7] * rn));
    *(uint4*)(dr + 72) = make_uint4(pk2(o2[8] * rn, o2[9] * rn), pk2(o2[10] * rn, o2[11] * rn),
                                    pk2(o2[12] * rn, o2[13] * rn), pk2(o2[14] * rn, o2[15] * rn));
  }
}

// ---------------- generic bf16 GEMM (2-phase counted-vmcnt dbuf, f32 out) ----------------
__global__ __launch_bounds__(256) void gemm_bf16_kernel(const __hip_bfloat16* __restrict__ A,
                                                        const __hip_bfloat16* __restrict__ Bt,
                                                        float* __restrict__ C,
                                                        int M, int N, int K) {
  __shared__ __align__(16) char smem[32768];          // A0|A1|B0|B1
  const int tid = threadIdx.x;
  const int lane = tid & 63;
  const int wid = tid >> 6;
  const int wm = wid >> 1, wn = wid & 1;
  const int nwg = gridDim.x;
  const int bid = blockIdx.x;
  const int swz = (bid & 7) * (nwg >> 3) + (bid >> 3);
  const int ntile = N >> 7;
  const int tm = swz / ntile, tn = swz % ntile;
  const int row0 = tm << 7, col0 = tn << 7;

  const int fr = lane & 15;
  const int kg = (lane >> 4) * 8;

  auto STAGE = [&](int buf, int k0) {
#pragma unroll
    for (int i = 0; i < 2; ++i) {
      int f = i * 256 + tid;
      int r = f >> 2, s = f & 3;
      gload_lds16(A + (size_t)(row0 + r) * K + k0 + s * 8,
                  smem + buf * 8192 + (i * 256 + wid * 64) * 16);
      gload_lds16(Bt + (size_t)(col0 + r) * K + k0 + s * 8,
                  smem + 16384 + buf * 8192 + (i * 256 + wid * 64) * 16);
    }
  };

  f32x4 acc[4][4] = {};
  const int nk = K >> 5;
  STAGE(0, 0);
  int cur = 0;
  for (int kk = 0; kk < nk; ++kk) {
    if (kk > 0) __builtin_amdgcn_s_barrier();
    __builtin_amdgcn_sched_barrier(0);
    if (kk + 1 < nk) STAGE(cur ^ 1, (kk + 1) * 32);
    __builtin_amdgcn_sched_barrier(0);
    if (kk + 1 < nk) asm volatile("s_waitcnt vmcnt(4)" ::: "memory");
    else             asm volatile("s_waitcnt vmcnt(0)" ::: "memory");
    __builtin_amdgcn_s_barrier();
    __builtin_amdgcn_sched_barrier(0);
    const __hip_bfloat16* Ac = (const __hip_bfloat16*)(smem + cur * 8192);
    const __hip_bfloat16* Bc = (const __hip_bfloat16*)(smem + 16384 + cur * 8192);
    bf16x8 af[4], bfr[4];
#pragma unroll
    for (int m = 0; m < 4; ++m)
      af[m] = *(const bf16x8*)(Ac + (wm * 64 + m * 16 + fr) * 32 + kg);
#pragma unroll
    for (int n = 0; n < 4; ++n)
      bfr[n] = *(const bf16x8*)(Bc + (wn * 64 + n * 16 + fr) * 32 + kg);
#pragma unroll
    for (int m = 0; m < 4; ++m)
#pragma unroll
      for (int n = 0; n < 4; ++n)
        acc[m][n] = MFMA_BF16(af[m], bfr[n], acc[m][n]);
    cur ^= 1;
  }

  const int cr = (lane >> 4) * 4;
#pragma unroll
  for (int m = 0; m < 4; ++m)
#pragma unroll
    for (int n = 0; n < 4; ++n) {
      int col = col0 + wn * 64 + n * 16 + fr;
#pragma unroll
      for (int r = 0; r < 4; ++r) {
        int row = row0 + wm * 64 + m * 16 + cr + r;
        C[(size_t)row * N + col] = acc[m][n][r];
      }
    }
}

// block decode (both passes): bi in [0,512): u=bi&255, half=bi>>8. g=u&7 = (b*4+kvh).
// bi and bi+256 (two halves of a balanced 34-step pair) land on the same CU under rr
// dispatch: per-CU balance at 2 blocks/CU.

// ---------------- attention pass 1: y1 = softmax(qk^T) v ; writes u = mix1*v + mix2*y1 ----------------
// Lazy softmax: common path has ZERO cross-lane ops (in-lane max + __any ballot;
// l kept as per-lane partial, reduced once in the epilogue). Cross-lane reduction
// only on max-growth (rare, T13 threshold 8) — exact algorithm.
__global__ __launch_bounds__(256, 2) void attn_pass1_kernel(
    const __hip_bfloat16* __restrict__ qT,   // (B,H,T,HD), q pre-scaled
    const __hip_bfloat16* __restrict__ kT,   // (B,HK,T,HD)
    const __hip_bfloat16* __restrict__ vt,   // (B,HK,HD,T)
    __hip_bfloat16* __restrict__ y1u,        // (B,H,HD,T)  u = mix1*v + mix2*y1
    float* __restrict__ Mb,                  // (B,H,T)  (exp2 domain)
    float* __restrict__ Lb,
    const float* __restrict__ mix1p,
    const float* __restrict__ mix2p) {
  __shared__ __align__(16) __hip_bfloat16 Ks[2][64 * 128];
  __shared__ __align__(16) __hip_bfloat16 Vs[2][128 * 64];
  __shared__ __align__(16) char Ps[4][32 * 128];
  const int tid = threadIdx.x, lane = tid & 63, wid = tid >> 6;   // wid 0..3
  const int bi = blockIdx.x;
  const int u = bi & 255, half = bi >> 8;
  const int g = u & 7;
  const int pslot = (u >> 3) & 7;
  const int bh = g * 4 + (u >> 6);
  const int j = half ? (15 - pslot) : pslot;
  const int q0 = j * 128;
  const int nt = 2 * j + 2;
  const int sd = 2 * j + (wid >> 1);
  const __hip_bfloat16* Kp = kT + (size_t)g * 2048 * 128;
  const __hip_bfloat16* Vp = vt + (size_t)g * 128 * 2048;
  const int fr = lane & 15, hi = lane >> 4;

  bf16x8 qf[2][4];
  {
    const __hip_bfloat16* Qp = qT + ((size_t)bh * 2048 + q0 + wid * 32) * 128;
#pragma unroll
    for (int rr = 0; rr < 2; ++rr)
#pragma unroll
      for (int dc = 0; dc < 4; ++dc)
        qf[rr][dc] = *(const bf16x8*)(Qp + (rr * 16 + fr) * 128 + dc * 32 + hi * 8);
  }

  f32x4 accO[2][8] = {};                     // accO[rr][f][r]: q=rr*16+hi*4+r, d=f*16+fr
  float m[2], l[2];                          // m row-uniform; l PER-LANE partial
  m[0] = m[1] = -1e30f; l[0] = l[1] = 0.f;

  char* Pb = Ps[wid];

  auto STAGE = [&](int buf, int kt) {        // 8 global_load_lds (4 K + 4 V)
    const int k0 = kt * 64;
#pragma unroll
    for (int i = 0; i < 4; ++i) {
      int f = i * 256 + tid;
      int r = f >> 4, s = f & 15, sx = s ^ (r & 7);
      gload_lds16(Kp + (size_t)(k0 + r) * 128 + sx * 8,
                  (char*)Ks[buf] + (i * 256 + wid * 64) * 16);
    }
#pragma unroll
    for (int i = 0; i < 4; ++i) {
      int f = i * 256 + tid;
      int r = f >> 3, s = f & 7, sx = s ^ (r & 7);
      gload_lds16(Vp + (size_t)r * 2048 + k0 + sx * 8,
                  (char*)Vs[buf] + (i * 256 + wid * 64) * 16);
    }
  };

  STAGE(0, 0);
  int cur = 0;
  for (int s = 0; s < nt; ++s) {
    if (s > 0) __builtin_amdgcn_s_barrier();   // WAR: compute(s-1) closed
    __builtin_amdgcn_sched_barrier(0);
    if (s + 1 < nt) STAGE(cur ^ 1, s + 1);
    __builtin_amdgcn_sched_barrier(0);
    if (s + 1 < nt) asm volatile("s_waitcnt vmcnt(8)" ::: "memory");
    else            asm volatile("s_waitcnt vmcnt(0)" ::: "memory");
    __builtin_amdgcn_s_barrier();              // K(s),V(s) landed for all waves
    __builtin_amdgcn_sched_barrier(0);

    const bool active = (s <= sd);
    if (active) {
      // ---- QK (swapped): sf[rr][c][r] = S[q=rr*16+fr][k=c*16+hi*4+r] ----
      const char* Kc = (const char*)Ks[cur];
      f32x4 sf[2][4] = {};
      __builtin_amdgcn_s_setprio(1);
#pragma unroll
      for (int c = 0; c < 4; ++c) {
        const int krow = c * 16 + fr;
#pragma unroll
        for (int dc = 0; dc < 4; ++dc) {
          int slot = (dc * 4 + hi) ^ (krow & 7);
          bf16x8 kf = *(const bf16x8*)(Kc + krow * 256 + slot * 16);
          sf[0][c] = MFMA_BF16(kf, qf[0][dc], sf[0][c]);
          sf[1][c] = MFMA_BF16(kf, qf[1][dc], sf[1][c]);
        }
      }
      __builtin_amdgcn_s_setprio(0);
      // ---- mask (diagonal) + in-lane max (NO cross-lane in common path) ----
      float lmax[2];
#pragma unroll
      for (int rr = 0; rr < 2; ++rr) {
        if (s == sd) {
          const int qq = q0 + wid * 32 + rr * 16 + fr;
#pragma unroll
          for (int c = 0; c < 4; ++c) {
            const int kb = s * 64 + c * 16 + hi * 4;
#pragma unroll
            for (int r = 0; r < 4; ++r)
              if (kb + r > qq) sf[rr][c][r] = -1e30f;
          }
        }
        float v = -1e30f;
#pragma unroll
        for (int c = 0; c < 4; ++c)
#pragma unroll
          for (int r = 0; r < 4; ++r) v = fmaxf(v, sf[rr][c][r]);
        lmax[rr] = v;
      }
      // ---- T13 defer-max + lazy reduction: reduce only on growth ----
      bool grow = (lmax[0] > m[0] + 8.f) | (lmax[1] > m[1] + 8.f);
      if (__any(grow)) {
        float a[2];
#pragma unroll
        for (int rr = 0; rr < 2; ++rr) {
          float v = lmax[rr];
          v = fmaxf(v, __shfl_xor(v, 16));
          v = fmaxf(v, __shfl_xor(v, 32));
          float mn = fmaxf(m[rr], v);
          a[rr] = __builtin_amdgcn_exp2f(m[rr] - mn);
          m[rr] = mn;
          l[rr] *= a[rr];
        }
#pragma unroll
        for (int rr = 0; rr < 2; ++rr)
#pragma unroll
          for (int r = 0; r < 4; ++r) {
            float aq = __shfl(a[rr], hi * 4 + r);   // a for q-row rr*16+hi*4+r
#pragma unroll
            for (int f = 0; f < 8; ++f) accO[rr][f][r] *= aq;
          }
      }
      // ---- exp2 + PER-LANE partial sum (row-sum deferred to epilogue) ----
#pragma unroll
      for (int rr = 0; rr < 2; ++rr) {
        float rs = 0.f;
#pragma unroll
        for (int c = 0; c < 4; ++c)
#pragma unroll
          for (int r = 0; r < 4; ++r) {
            float p = __builtin_amdgcn_exp2f(sf[rr][c][r] - m[rr]);
            sf[rr][c][r] = p;
            rs += p;
          }
        l[rr] += rs;
      }
      // ---- P -> LDS: 8 packed b64 writes (swizzled 16B slots), read 4 b128 A-frags ----
#pragma unroll
      for (int rr = 0; rr < 2; ++rr) {
        const int row = rr * 16 + fr;
        char* Prow = Pb + row * 128;
#pragma unroll
        for (int c = 0; c < 4; ++c) {
          uint32_t w0 = pk2(sf[rr][c][0], sf[rr][c][1]);
          uint32_t w1 = pk2(sf[rr][c][2], sf[rr][c][3]);
          int sl = (c * 2 + (hi >> 1)) ^ (row & 7);
          *(uint2*)(Prow + sl * 16 + (hi & 1) * 8) = make_uint2(w0, w1);
        }
      }
      bf16x8 pf[2][2];
#pragma unroll
      for (int rr = 0; rr < 2; ++rr) {
        const int row = rr * 16 + fr;
#pragma unroll
        for (int kc = 0; kc < 2; ++kc) {
          int sl = (kc * 4 + hi) ^ (row & 7);
          pf[rr][kc] = *(const bf16x8*)(Pb + row * 128 + sl * 16);
        }
      }
      // ---- PV ----
      const __hip_bfloat16* Vc = Vs[cur];
      __builtin_amdgcn_s_setprio(1);
#pragma unroll
      for (int kc = 0; kc < 2; ++kc)
#pragma unroll
        for (int f = 0; f < 8; ++f) {
          int vrow = f * 16 + fr;
          int vslot = (kc * 4 + hi) ^ (fr & 7);
          bf16x8 vf = *(const bf16x8*)(Vc + vrow * 64 + vslot * 8);
          accO[0][f] = MFMA_BF16(pf[0][kc], vf, accO[0][f]);
          accO[1][f] = MFMA_BF16(pf[1][kc], vf, accO[1][f]);
        }
      __builtin_amdgcn_s_setprio(0);
    }
    cur ^= 1;
  }

  // ---- epilogue: reduce per-lane l once; u = mix1*v + mix2*(accO/l); store m,l ----
  float lsum[2];
#pragma unroll
  for (int rr = 0; rr < 2; ++rr) {
    float v = l[rr];
    v += __shfl_xor(v, 16);
    v += __shfl_xor(v, 32);
    lsum[rr] = v;
  }
  const float m1v = mix1p[0], m2v = mix2p[0];
  float rlq[2][4];
#pragma unroll
  for (int rr = 0; rr < 2; ++rr) {
    float inv = 1.f / lsum[rr];
#pragma unroll
    for (int r = 0; r < 4; ++r) rlq[rr][r] = __shfl(inv, hi * 4 + r);
  }
  const int t0 = q0 + wid * 32;
#pragma unroll
  for (int rr = 0; rr < 2; ++rr) {
    const int tb = t0 + rr * 16 + hi * 4;
#pragma unroll
    for (int f = 0; f < 8; ++f) {
      const int d = f * 16 + fr;
      const ushort4 v4 = *(const ushort4*)(vt + ((size_t)g * 128 + d) * 2048 + tb);
      float u0 = m1v * b2f(v4.x) + m2v * (accO[rr][f][0] * rlq[rr][0]);
      float u1 = m1v * b2f(v4.y) + m2v * (accO[rr][f][1] * rlq[rr][1]);
      float u2 = m1v * b2f(v4.z) + m2v * (accO[rr][f][2] * rlq[rr][2]);
      float u3 = m1v * b2f(v4.w) + m2v * (accO[rr][f][3] * rlq[rr][3]);
      *(uint2*)(y1u + ((size_t)bh * 128 + d) * 2048 + tb) =
          make_uint2(pk2(u0, u1), pk2(u2, u3));
    }
  }
  if (hi == 0) {
#pragma unroll
    for (int rr = 0; rr < 2; ++rr) {
      Mb[(size_t)bh * 2048 + t0 + rr * 16 + fr] = m[rr];
      Lb[(size_t)bh * 2048 + t0 + rr * 16 + fr] = lsum[rr];
    }
  }
}

// ---------------- attention pass 2: ymix = att @ u  (direct final output) ----------------
__global__ __launch_bounds__(256, 2) void attn_pass2_kernel(
    const __hip_bfloat16* __restrict__ qT,
    const __hip_bfloat16* __restrict__ kT,
    const __hip_bfloat16* __restrict__ y1u,  // (B,H,HD,T)
    const float* __restrict__ Mb,
    const float* __restrict__ Lb,
    __hip_bfloat16* __restrict__ ymix) {     // (B,T,C)
  __shared__ __align__(16) __hip_bfloat16 Ks[2][64 * 128];
  __shared__ __align__(16) __hip_bfloat16 Vs[2][128 * 64];
  __shared__ __align__(16) char Ps[4][32 * 128];
  const int tid = threadIdx.x, lane = tid & 63, wid = tid >> 6;
  const int bi = blockIdx.x;
  const int u = bi & 255, half = bi >> 8;
  const int g = u & 7;
  const int pslot = (u >> 3) & 7;
  const int bh = g * 4 + (u >> 6);
  const int h = bh & 15, b = bh >> 4;
  const int j = half ? (15 - pslot) : pslot;
  const int q0 = j * 128;
  const int nt = 2 * j + 2;
  const int sd = 2 * j + (wid >> 1);
  const __hip_bfloat16* Kp = kT + (size_t)g * 2048 * 128;
  const __hip_bfloat16* Yp = y1u + (size_t)bh * 128 * 2048;
  const int fr = lane & 15, hi = lane >> 4;

  bf16x8 qf[2][4];
  float mr[2], rl[2];
  {
    const __hip_bfloat16* Qp = qT + ((size_t)bh * 2048 + q0 + wid * 32) * 128;
#pragma unroll
    for (int rr = 0; rr < 2; ++rr)
#pragma unroll
      for (int dc = 0; dc < 4; ++dc)
        qf[rr][dc] = *(const bf16x8*)(Qp + (rr * 16 + fr) * 128 + dc * 32 + hi * 8);
    const size_t qb = (size_t)bh * 2048 + q0 + wid * 32;
    mr[0] = Mb[qb + fr];        mr[1] = Mb[qb + 16 + fr];
    rl[0] = 1.f / Lb[qb + fr];  rl[1] = 1.f / Lb[qb + 16 + fr];
  }

  f32x4 accO[2][8] = {};
  char* Pb = Ps[wid];

  auto STAGE = [&](int buf, int kt) {
    const int k0 = kt * 64;
#pragma unroll
    for (int i = 0; i < 4; ++i) {
      int f = i * 256 + tid;
      int r = f >> 4, s = f & 15, sx = s ^ (r & 7);
      gload_lds16(Kp + (size_t)(k0 + r) * 128 + sx * 8,
                  (char*)Ks[buf] + (i * 256 + wid * 64) * 16);
    }
#pragma unroll
    for (int i = 0; i < 4; ++i) {
      int f = i * 256 + tid;
      int r = f >> 3, s = f & 7, sx = s ^ (r & 7);
      gload_lds16(Yp + (size_t)r * 2048 + k0 + sx * 8,
                  (char*)Vs[buf] + (i * 256 + wid * 64) * 16);
    }
  };

  STAGE(0, 0);
  int cur = 0;
  for (int s = 0; s < nt; ++s) {
    if (s > 0) __builtin_amdgcn_s_barrier();
    __builtin_amdgcn_sched_barrier(0);
    if (s + 1 < nt) STAGE(cur ^ 1, s + 1);
    __builtin_amdgcn_sched_barrier(0);
    if (s + 1 < nt) asm volatile("s_waitcnt vmcnt(8)" ::: "memory");
    else            asm volatile("s_waitcnt vmcnt(0)" ::: "memory");
    __builtin_amdgcn_s_barrier();
    __builtin_amdgcn_sched_barrier(0);

    const bool active = (s <= sd);
    if (active) {
      const char* Kc = (const char*)Ks[cur];
      f32x4 sf[2][4] = {};
      __builtin_amdgcn_s_setprio(1);
#pragma unroll
      for (int c = 0; c < 4; ++c) {
        const int krow = c * 16 + fr;
#pragma unroll
        for (int dc = 0; dc < 4; ++dc) {
          int slot = (dc * 4 + hi) ^ (krow & 7);
          bf16x8 kf = *(const bf16x8*)(Kc + krow * 256 + slot * 16);
          sf[0][c] = MFMA_BF16(kf, qf[0][dc], sf[0][c]);
          sf[1][c] = MFMA_BF16(kf, qf[1][dc], sf[1][c]);
        }
      }
      __builtin_amdgcn_s_setprio(0);
      // normalize P directly from stored stats (all fr-indexed, no shuffles)
#pragma unroll
      for (int rr = 0; rr < 2; ++rr) {
        if (s == sd) {
          const int qq = q0 + wid * 32 + rr * 16 + fr;
#pragma unroll
          for (int c = 0; c < 4; ++c) {
            const int kb = s * 64 + c * 16 + hi * 4;
#pragma unroll
            for (int r = 0; r < 4; ++r)
              if (kb + r > qq) sf[rr][c][r] = -1e30f;
          }
        }
#pragma unroll
        for (int c = 0; c < 4; ++c)
#pragma unroll
          for (int r = 0; r < 4; ++r)
            sf[rr][c][r] = __builtin_amdgcn_exp2f(sf[rr][c][r] - mr[rr]) * rl[rr];
      }
#pragma unroll
      for (int rr = 0; rr < 2; ++rr) {
        const int row = rr * 16 + fr;
        char* Prow = Pb + row * 128;
#pragma unroll
        for (int c = 0; c < 4; ++c) {
          uint32_t w0 = pk2(sf[rr][c][0], sf[rr][c][1]);
          uint32_t w1 = pk2(sf[rr][c][2], sf[rr][c][3]);
          int sl = (c * 2 + (hi >> 1)) ^ (row & 7);
          *(uint2*)(Prow + sl * 16 + (hi & 1) * 8) = make_uint2(w0, w1);
        }
      }
      bf16x8 pf[2][2];
#pragma unroll
      for (int rr = 0; rr < 2; ++rr) {
        const int row = rr * 16 + fr;
#pragma unroll
        for (int kc = 0; kc < 2; ++kc) {
          int sl = (kc * 4 + hi) ^ (row & 7);
          pf[rr][kc] = *(const bf16x8*)(Pb + row * 128 + sl * 16);
        }
      }
      const __hip_bfloat16* Vc = Vs[cur];
      __builtin_amdgcn_s_setprio(1);
#pragma unroll
      for (int kc = 0; kc < 2; ++kc)
#pragma unroll
        for (int f = 0; f < 8; ++f) {
          int vrow = f * 16 + fr;
          int vslot = (kc * 4 + hi) ^ (fr & 7);
          bf16x8 vf = *(const bf16x8*)(Vc + vrow * 64 + vslot * 8);
          accO[0][f] = MFMA_BF16(pf[0][kc], vf, accO[0][f]);
          accO[1][f] = MFMA_BF16(pf[1][kc], vf, accO[1][f]);
        }
      __builtin_amdgcn_s_setprio(0);
    }
    cur ^= 1;
  }

  // accO already IS the final mixed output (P pre-normalized, u pre-mixed)
#pragma unroll
  for (int rr = 0; rr < 2; ++rr) {
#pragma unroll
    for (int f = 0; f < 8; ++f) {
      const int d = f * 16 + fr;
#pragma unroll
      for (int r = 0; r < 4; ++r) {
        int q = q0 + wid * 32 + rr * 16 + hi * 4 + r;
        ymix[((size_t)b * 2048 + q) * 2048 + h * 128 + d] = __float2bfloat16(accO[rr][f][r]);
      }
    }
  }
}

// ---------------- launch ----------------
extern "C" void kernel_launch(void* const* d_in, const int* in_sizes, int n_in,
                              void* d_out, int out_size, void* d_ws, size_t ws_size,
                              hipStream_t stream) {
  const float* x    = (const float*)d_in[0];
  const float* cosb = (const float*)d_in[1];
  const float* sinb = (const float*)d_in[2];
  const float* Wq   = (const float*)d_in[3];
  const float* Wk   = (const float*)d_in[4];
  const float* Wv   = (const float*)d_in[5];
  const float* Wp   = (const float*)d_in[6];
  const float* mix1 = (const float*)d_in[7];
  const float* mix2 = (const float*)d_in[8];
  float* out = (float*)d_out;
  char* ws = (char*)d_ws;

  // workspace layout (bytes), peak ~80.2 MB
  __hip_bfloat16* xb   = (__hip_bfloat16*)(ws + 0);            // 16.78 MB; reused as ymix
  __hip_bfloat16* WTa  = (__hip_bfloat16*)(ws + 16777216);     // 12.58 MB
  __hip_bfloat16* WpT  = (__hip_bfloat16*)(ws + 29360128);     // 8.39 MB
  __hip_bfloat16* y1u  = (__hip_bfloat16*)(ws + 37748736);     // 16.78 MB
  float*          Mb   = (float*)(ws + 54525952);              // 0.26 MB
  float*          Lb   = (float*)(ws + 54788096);              // 0.26 MB
  __hip_bfloat16* qTb  = (__hip_bfloat16*)(ws + 55050240);     // 16.78 MB
  __hip_bfloat16* kTb  = (__hip_bfloat16*)(ws + 71827456);     // 4.19 MB
  __hip_bfloat16* vtb  = (__hip_bfloat16*)(ws + 76021760);     // 4.19 MB
  __hip_bfloat16* ymix = (__hip_bfloat16*)(ws + 0);

  dim3 tb(32, 8);
  prep_kernel<<<18432, tb, 0, stream>>>(x, xb, Wq, Wk, Wv, Wp, WTa, WpT);

  // fused QKV projection + RoPE + RMS + V-transpose (256x256 tiles, 192 blocks)
  gemm_qkv_rope_kernel<<<192, 512, 0, stream>>>(xb, WTa, cosb, sinb, qTb, kTb, vtb);

  attn_pass1_kernel<<<512, 256, 0, stream>>>(qTb, kTb, vtb, y1u, Mb, Lb, mix1, mix2);
  attn_pass2_kernel<<<512, 256, 0, stream>>>(qTb, kTb, y1u, Mb, Lb, ymix);

  gemm_bf16_kernel<<<512, 256, 0, stream>>>(ymix, WpT, out, 4096, 2048, 2048);
}

// Round 13
// 243.860 us; speedup vs baseline: 1.2589x; 1.0361x over previous
//
#include <hip/hip_runtime.h>
#include <hip/hip_bf16.h>
#include <cstdint>
#include <cstddef>

#define AS1 __attribute__((address_space(1)))
#define AS3 __attribute__((address_space(3)))

typedef __attribute__((ext_vector_type(8))) short bf16x8;
typedef __attribute__((ext_vector_type(4))) float f32x4;

__device__ __forceinline__ void gload_lds16(const void* g, void* l) {
  __builtin_amdgcn_global_load_lds((const AS1 void*)g, (AS3 void*)l, 16, 0, 0);
}

#define MFMA_BF16(A, B, C) __builtin_amdgcn_mfma_f32_16x16x32_bf16((A), (B), (C), 0, 0, 0)

// (1/sqrt(128)) * log2(e) — folded into q at rope time; softmax runs in exp2 domain.
#define QSCALE 0.12751744f

__device__ __forceinline__ uint32_t pk2(float a, float b) {
  uint32_t ua = (uint32_t)__builtin_bit_cast(unsigned short, __float2bfloat16(a));
  uint32_t ub = (uint32_t)__builtin_bit_cast(unsigned short, __float2bfloat16(b));
  return ua | (ub << 16);
}
__device__ __forceinline__ float b2f(unsigned short u) {
  return __builtin_bit_cast(float, (uint32_t)u << 16);
}

// sum over 8 consecutive lanes (group-aligned): DPP xor1, xor2, half-mirror
__device__ __forceinline__ float red8_sum(float v) {
  int x;
  x = __builtin_amdgcn_update_dpp(0, __builtin_bit_cast(int, v), 0xB1, 0xF, 0xF, true);
  v += __builtin_bit_cast(float, x);
  x = __builtin_amdgcn_update_dpp(0, __builtin_bit_cast(int, v), 0x4E, 0xF, 0xF, true);
  v += __builtin_bit_cast(float, x);
  x = __builtin_amdgcn_update_dpp(0, __builtin_bit_cast(int, v), 0x141, 0xF, 0xF, true);
  v += __builtin_bit_cast(float, x);
  return v;
}

// ---------------- merged prep: x cast + weight transposes in one launch ----------------
__global__ __launch_bounds__(256) void prep_kernel(const float* __restrict__ x,
                                                   __hip_bfloat16* __restrict__ xb,
                                                   const float* __restrict__ Wq,
                                                   const float* __restrict__ Wk,
                                                   const float* __restrict__ Wv,
                                                   const float* __restrict__ Wp,
                                                   __hip_bfloat16* __restrict__ WTa,
                                                   __hip_bfloat16* __restrict__ WpT) {
  __shared__ float tile[32][33];
  int id = blockIdx.x;
  int tx = threadIdx.x, ty = threadIdx.y;
  if (id < 8192) {             // cast: 8192 blocks x 256 f32x4
    int i = id * 256 + ty * 32 + tx;
    float4 v = ((const float4*)x)[i];
    __hip_bfloat16* o = xb + (size_t)i * 4;
    o[0] = __float2bfloat16(v.x);
    o[1] = __float2bfloat16(v.y);
    o[2] = __float2bfloat16(v.z);
    o[3] = __float2bfloat16(v.w);
    return;
  }
  id -= 8192;
  const float* in; __hip_bfloat16* out; int is, os, bx, by;
  if (id < 4096)      { in = Wq; out = WTa;                          is = 2048; os = 2048; bx = id & 63; by = id >> 6; }
  else if (id < 5120) { int t = id - 4096; in = Wk; out = WTa + (size_t)2048 * 2048; is = 512; os = 2048; bx = t & 15; by = t >> 4; }
  else if (id < 6144) { int t = id - 5120; in = Wv; out = WTa + (size_t)2560 * 2048; is = 512; os = 2048; bx = t & 15; by = t >> 4; }
  else                { int t = id - 6144; in = Wp; out = WpT;       is = 2048; os = 2048; bx = t & 63; by = t >> 6; }
  int c0 = bx * 32, r0 = by * 32;
#pragma unroll
  for (int i = 0; i < 32; i += 8)
    tile[ty + i][tx] = in[(size_t)(r0 + ty + i) * is + c0 + tx];
  __syncthreads();
#pragma unroll
  for (int i = 0; i < 32; i += 8)
    out[(size_t)(c0 + ty + i) * os + r0 + tx] = __float2bfloat16(tile[tx][ty + i]);
}

// ---------------- qkv GEMM: 128x128 tile, BK=64, 4 waves, 2-phase counted-vmcnt ----------------
// 2 blocks/CU (64 KB staging), 768 blocks (full grid coverage). A/B staged with the
// 16B-slot XOR swizzle (source-swizzled, linear LDS dest, swizzled read) — kills the
// 16-way conflict of 128B row stride. Epilogue: acc -> CL4 packed -> rope+rms / V store.
__global__ __launch_bounds__(256, 2) void gemm_qkv_rope_kernel(
    const __hip_bfloat16* __restrict__ A,
    const __hip_bfloat16* __restrict__ Bt,
    const float* __restrict__ cosb,
    const float* __restrict__ sinb,
    __hip_bfloat16* __restrict__ qT,
    __hip_bfloat16* __restrict__ kT,
    __hip_bfloat16* __restrict__ vt) {
  // stage: A0 @0, A1 @16384, B0 @32768, B1 @49152 (64 KB). epilogue: CL4 (34 KB).
  __shared__ __align__(16) char smem[65536];
  __hip_bfloat16* CL4 = (__hip_bfloat16*)smem;    // elem idx = (q4*133+col)*4 + rr
  const int K = 2048;
  const int tid = threadIdx.x;
  const int lane = tid & 63;
  const int wid = tid >> 6;                       // 0..3
  const int wm = wid >> 1, wn = wid & 1;
  const int bid = blockIdx.x;
  const int swz = (bid & 7) * 96 + (bid >> 3);    // nwg=768, XCD-contiguous
  const int tm = swz / 24, tn = swz % 24;
  const int row0 = tm << 7, col0 = tn << 7;
  const int fr = lane & 15, hi = lane >> 4;

  auto STAGE = [&](int buf, int k0) {             // 8 gload_lds / thread (4 A + 4 B)
#pragma unroll
    for (int i = 0; i < 4; ++i) {
      int f = i * 256 + tid;
      int r = f >> 3, s = f & 7, sx = s ^ (r & 7);
      gload_lds16(A + (size_t)(row0 + r) * K + k0 + sx * 8,
                  smem + buf * 16384 + f * 16);
    }
#pragma unroll
    for (int i = 0; i < 4; ++i) {
      int f = i * 256 + tid;
      int r = f >> 3, s = f & 7, sx = s ^ (r & 7);
      gload_lds16(Bt + (size_t)(col0 + r) * K + k0 + sx * 8,
                  smem + 32768 + buf * 16384 + f * 16);
    }
  };

  f32x4 acc[4][4] = {};
  STAGE(0, 0);
  int cur = 0;
  for (int kk = 0; kk < 32; ++kk) {
    if (kk > 0) __builtin_amdgcn_s_barrier();     // WAR: compute(kk-1) closed
    __builtin_amdgcn_sched_barrier(0);
    if (kk + 1 < 32) STAGE(cur ^ 1, (kk + 1) * 64);
    __builtin_amdgcn_sched_barrier(0);
    if (kk + 1 < 32) asm volatile("s_waitcnt vmcnt(8)" ::: "memory");
    else             asm volatile("s_waitcnt vmcnt(0)" ::: "memory");
    __builtin_amdgcn_s_barrier();                 // tile(kk) landed for all waves
    __builtin_amdgcn_sched_barrier(0);
    const char* Ac = smem + cur * 16384;
    const char* Bc = smem + 32768 + cur * 16384;
#pragma unroll
    for (int kh = 0; kh < 2; ++kh) {              // K=64 in two 32-halves
      bf16x8 af[4], bfr[4];
#pragma unroll
      for (int n = 0; n < 4; ++n) {
        int rowb = wn * 64 + n * 16 + fr;
        int sl = (kh * 4 + hi) ^ (rowb & 7);
        bfr[n] = *(const bf16x8*)(Bc + rowb * 128 + sl * 16);
      }
#pragma unroll
      for (int m = 0; m < 4; ++m) {
        int rowa = wm * 64 + m * 16 + fr;
        int sl = (kh * 4 + hi) ^ (rowa & 7);
        af[m] = *(const bf16x8*)(Ac + rowa * 128 + sl * 16);
      }
      __builtin_amdgcn_s_setprio(1);
#pragma unroll
      for (int m = 0; m < 4; ++m)
#pragma unroll
        for (int n = 0; n < 4; ++n)
          acc[m][n] = MFMA_BF16(af[m], bfr[n], acc[m][n]);
      __builtin_amdgcn_s_setprio(0);
    }
    cur ^= 1;
  }
  __syncthreads();                                // staging reads done; reuse as CL4

  // ---- pack acc -> CL4: one b64 per fragment (4 consecutive rows, same col) ----
#pragma unroll
  for (int m = 0; m < 4; ++m)
#pragma unroll
    for (int n = 0; n < 4; ++n) {
      int q4 = wm * 16 + m * 4 + hi;              // (row>>2)
      int col = wn * 64 + n * 16 + fr;
      *(uint2*)(CL4 + ((q4 * 133 + col) << 2)) =
          make_uint2(pk2(acc[m][n][0], acc[m][n][1]), pk2(acc[m][n][2], acc[m][n][3]));
    }
  __syncthreads();

  const int b = row0 >> 11;
  const int t0 = row0 & 2047;

  if (col0 >= 2560) {
    // ---- V: column gather from CL4, 128B-contiguous stores to (B,HK,HD,T) ----
    const int hv = (col0 - 2560) >> 7;
    __hip_bfloat16* vb = vt + (size_t)(b * 4 + hv) * 128 * 2048;
    const int col = tid >> 1, th = tid & 1;
    uint2 w[16];
#pragma unroll
    for (int qq = 0; qq < 16; ++qq)
      w[qq] = *(const uint2*)(CL4 + (((th * 16 + qq) * 133 + col) << 2));
    __hip_bfloat16* dstv = vb + (size_t)col * 2048 + t0 + th * 64;
#pragma unroll
    for (int e = 0; e < 8; ++e)
      *(uint4*)(dstv + e * 8) = make_uint4(w[2 * e].x, w[2 * e].y, w[2 * e + 1].x, w[2 * e + 1].y);
    return;
  }

  // ---- q/k: rope + rms. thread = (row-quad, 8-col-slice) ----
  const int quad = tid >> 3, cp = tid & 7;
  const int tb = t0 + quad * 4;
  bf16x8 lov[4], hiv[4];
#pragma unroll
  for (int e = 0; e < 4; ++e) {
    lov[e] = *(const bf16x8*)(CL4 + ((quad * 133 + cp * 8 + e * 2) << 2));
    hiv[e] = *(const bf16x8*)(CL4 + ((quad * 133 + 64 + cp * 8 + e * 2) << 2));
  }
  const float oscale = (col0 < 2048) ? QSCALE : 1.0f;
  __hip_bfloat16* dstq = (col0 < 2048)
      ? qT + (size_t)(b * 16 + (col0 >> 7)) * 2048 * 128
      : kT + (size_t)(b * 4 + ((col0 - 2048) >> 7)) * 2048 * 128;

  float o1v[4][8], o2v[4][8], ssum[4];
#pragma unroll
  for (int rr = 0; rr < 4; ++rr) {
    const float* cb = cosb + (size_t)(tb + rr) * 64 + cp * 8;
    const float* sb = sinb + (size_t)(tb + rr) * 64 + cp * 8;
    float4 c0 = *(const float4*)cb, c1 = *(const float4*)(cb + 4);
    float4 s0 = *(const float4*)sb, s1 = *(const float4*)(sb + 4);
    float cc[8] = {c0.x, c0.y, c0.z, c0.w, c1.x, c1.y, c1.z, c1.w};
    float sn[8] = {s0.x, s0.y, s0.z, s0.w, s1.x, s1.y, s1.z, s1.w};
    float ss = 0.f;
#pragma unroll
    for (int e = 0; e < 4; ++e)
#pragma unroll
      for (int w2 = 0; w2 < 2; ++w2) {
        int pd = e * 2 + w2;
        float x1 = b2f((unsigned short)lov[e][w2 * 4 + rr]);
        float x2 = b2f((unsigned short)hiv[e][w2 * 4 + rr]);
        float a = x1 * cc[pd] - x2 * sn[pd];
        float bb = x1 * sn[pd] + x2 * cc[pd];
        o1v[rr][pd] = a;
        o2v[rr][pd] = bb;
        ss += a * a + bb * bb;
      }
    ssum[rr] = ss;
  }
#pragma unroll
  for (int rr = 0; rr < 4; ++rr) {
    float rn = rsqrtf(red8_sum(ssum[rr]) * (1.f / 128.f) + 1e-6f) * oscale;
    __hip_bfloat16* dr = dstq + (size_t)(tb + rr) * 128 + cp * 8;
    *(uint4*)dr = make_uint4(pk2(o1v[rr][0] * rn, o1v[rr][1] * rn),
                             pk2(o1v[rr][2] * rn, o1v[rr][3] * rn),
                             pk2(o1v[rr][4] * rn, o1v[rr][5] * rn),
                             pk2(o1v[rr][6] * rn, o1v[rr][7] * rn));
    *(uint4*)(dr + 64) = make_uint4(pk2(o2v[rr][0] * rn, o2v[rr][1] * rn),
                                    pk2(o2v[rr][2] * rn, o2v[rr][3] * rn),
                                    pk2(o2v[rr][4] * rn, o2v[rr][5] * rn),
                                    pk2(o2v[rr][6] * rn, o2v[rr][7] * rn));
  }
}

// ---------------- generic bf16 GEMM (2-phase counted-vmcnt dbuf, f32 out) ----------------
__global__ __launch_bounds__(256) void gemm_bf16_kernel(const __hip_bfloat16* __restrict__ A,
                                                        const __hip_bfloat16* __restrict__ Bt,
                                                        float* __restrict__ C,
                                                        int M, int N, int K) {
  __shared__ __align__(16) char smem[32768];          // A0|A1|B0|B1
  const int tid = threadIdx.x;
  const int lane = tid & 63;
  const int wid = tid >> 6;
  const int wm = wid >> 1, wn = wid & 1;
  const int nwg = gridDim.x;
  const int bid = blockIdx.x;
  const int swz = (bid & 7) * (nwg >> 3) + (bid >> 3);
  const int ntile = N >> 7;
  const int tm = swz / ntile, tn = swz % ntile;
  const int row0 = tm << 7, col0 = tn << 7;

  const int fr = lane & 15;
  const int kg = (lane >> 4) * 8;

  auto STAGE = [&](int buf, int k0) {
#pragma unroll
    for (int i = 0; i < 2; ++i) {
      int f = i * 256 + tid;
      int r = f >> 2, s = f & 3;
      gload_lds16(A + (size_t)(row0 + r) * K + k0 + s * 8,
                  smem + buf * 8192 + (i * 256 + wid * 64) * 16);
      gload_lds16(Bt + (size_t)(col0 + r) * K + k0 + s * 8,
                  smem + 16384 + buf * 8192 + (i * 256 + wid * 64) * 16);
    }
  };

  f32x4 acc[4][4] = {};
  const int nk = K >> 5;
  STAGE(0, 0);
  int cur = 0;
  for (int kk = 0; kk < nk; ++kk) {
    if (kk > 0) __builtin_amdgcn_s_barrier();
    __builtin_amdgcn_sched_barrier(0);
    if (kk + 1 < nk) STAGE(cur ^ 1, (kk + 1) * 32);
    __builtin_amdgcn_sched_barrier(0);
    if (kk + 1 < nk) asm volatile("s_waitcnt vmcnt(4)" ::: "memory");
    else             asm volatile("s_waitcnt vmcnt(0)" ::: "memory");
    __builtin_amdgcn_s_barrier();
    __builtin_amdgcn_sched_barrier(0);
    const __hip_bfloat16* Ac = (const __hip_bfloat16*)(smem + cur * 8192);
    const __hip_bfloat16* Bc = (const __hip_bfloat16*)(smem + 16384 + cur * 8192);
    bf16x8 af[4], bfr[4];
#pragma unroll
    for (int m = 0; m < 4; ++m)
      af[m] = *(const bf16x8*)(Ac + (wm * 64 + m * 16 + fr) * 32 + kg);
#pragma unroll
    for (int n = 0; n < 4; ++n)
      bfr[n] = *(const bf16x8*)(Bc + (wn * 64 + n * 16 + fr) * 32 + kg);
#pragma unroll
    for (int m = 0; m < 4; ++m)
#pragma unroll
      for (int n = 0; n < 4; ++n)
        acc[m][n] = MFMA_BF16(af[m], bfr[n], acc[m][n]);
    cur ^= 1;
  }

  const int cr = (lane >> 4) * 4;
#pragma unroll
  for (int m = 0; m < 4; ++m)
#pragma unroll
    for (int n = 0; n < 4; ++n) {
      int col = col0 + wn * 64 + n * 16 + fr;
#pragma unroll
      for (int r = 0; r < 4; ++r) {
        int row = row0 + wm * 64 + m * 16 + cr + r;
        C[(size_t)row * N + col] = acc[m][n][r];
      }
    }
}

// block decode (both passes): bi in [0,512): u=bi&255, half=bi>>8. g=u&7 = (b*4+kvh).
// bi and bi+256 (two halves of a balanced 34-step pair) land on the same CU under rr
// dispatch: per-CU balance at 2 blocks/CU.

// ---------------- attention pass 1: y1 = softmax(qk^T) v ; writes u = mix1*v + mix2*y1 ----------------
// Lazy softmax: common path has ZERO cross-lane ops (in-lane max + __any ballot;
// l kept as per-lane partial, reduced once in the epilogue). Cross-lane reduction
// only on max-growth (rare, T13 threshold 8) — exact algorithm.
__global__ __launch_bounds__(256, 2) void attn_pass1_kernel(
    const __hip_bfloat16* __restrict__ qT,   // (B,H,T,HD), q pre-scaled
    const __hip_bfloat16* __restrict__ kT,   // (B,HK,T,HD)
    const __hip_bfloat16* __restrict__ vt,   // (B,HK,HD,T)
    __hip_bfloat16* __restrict__ y1u,        // (B,H,HD,T)  u = mix1*v + mix2*y1
    float* __restrict__ Mb,                  // (B,H,T)  (exp2 domain)
    float* __restrict__ Lb,
    const float* __restrict__ mix1p,
    const float* __restrict__ mix2p) {
  __shared__ __align__(16) __hip_bfloat16 Ks[2][64 * 128];
  __shared__ __align__(16) __hip_bfloat16 Vs[2][128 * 64];
  __shared__ __align__(16) char Ps[4][32 * 128];
  const int tid = threadIdx.x, lane = tid & 63, wid = tid >> 6;   // wid 0..3
  const int bi = blockIdx.x;
  const int u = bi & 255, half = bi >> 8;
  const int g = u & 7;
  const int pslot = (u >> 3) & 7;
  const int bh = g * 4 + (u >> 6);
  const int j = half ? (15 - pslot) : pslot;
  const int q0 = j * 128;
  const int nt = 2 * j + 2;
  const int sd = 2 * j + (wid >> 1);
  const __hip_bfloat16* Kp = kT + (size_t)g * 2048 * 128;
  const __hip_bfloat16* Vp = vt + (size_t)g * 128 * 2048;
  const int fr = lane & 15, hi = lane >> 4;

  bf16x8 qf[2][4];
  {
    const __hip_bfloat16* Qp = qT + ((size_t)bh * 2048 + q0 + wid * 32) * 128;
#pragma unroll
    for (int rr = 0; rr < 2; ++rr)
#pragma unroll
      for (int dc = 0; dc < 4; ++dc)
        qf[rr][dc] = *(const bf16x8*)(Qp + (rr * 16 + fr) * 128 + dc * 32 + hi * 8);
  }

  f32x4 accO[2][8] = {};                     // accO[rr][f][r]: q=rr*16+hi*4+r, d=f*16+fr
  float m[2], l[2];                          // m row-uniform; l PER-LANE partial
  m[0] = m[1] = -1e30f; l[0] = l[1] = 0.f;

  char* Pb = Ps[wid];

  auto STAGE = [&](int buf, int kt) {        // 8 global_load_lds (4 K + 4 V)
    const int k0 = kt * 64;
#pragma unroll
    for (int i = 0; i < 4; ++i) {
      int f = i * 256 + tid;
      int r = f >> 4, s = f & 15, sx = s ^ (r & 7);
      gload_lds16(Kp + (size_t)(k0 + r) * 128 + sx * 8,
                  (char*)Ks[buf] + (i * 256 + wid * 64) * 16);
    }
#pragma unroll
    for (int i = 0; i < 4; ++i) {
      int f = i * 256 + tid;
      int r = f >> 3, s = f & 7, sx = s ^ (r & 7);
      gload_lds16(Vp + (size_t)r * 2048 + k0 + sx * 8,
                  (char*)Vs[buf] + (i * 256 + wid * 64) * 16);
    }
  };

  STAGE(0, 0);
  int cur = 0;
  for (int s = 0; s < nt; ++s) {
    if (s > 0) __builtin_amdgcn_s_barrier();   // WAR: compute(s-1) closed
    __builtin_amdgcn_sched_barrier(0);
    if (s + 1 < nt) STAGE(cur ^ 1, s + 1);
    __builtin_amdgcn_sched_barrier(0);
    if (s + 1 < nt) asm volatile("s_waitcnt vmcnt(8)" ::: "memory");
    else            asm volatile("s_waitcnt vmcnt(0)" ::: "memory");
    __builtin_amdgcn_s_barrier();              // K(s),V(s) landed for all waves
    __builtin_amdgcn_sched_barrier(0);

    const bool active = (s <= sd);
    if (active) {
      // ---- QK (swapped): sf[rr][c][r] = S[q=rr*16+fr][k=c*16+hi*4+r] ----
      const char* Kc = (const char*)Ks[cur];
      f32x4 sf[2][4] = {};
      __builtin_amdgcn_s_setprio(1);
#pragma unroll
      for (int c = 0; c < 4; ++c) {
        const int krow = c * 16 + fr;
#pragma unroll
        for (int dc = 0; dc < 4; ++dc) {
          int slot = (dc * 4 + hi) ^ (krow & 7);
          bf16x8 kf = *(const bf16x8*)(Kc + krow * 256 + slot * 16);
          sf[0][c] = MFMA_BF16(kf, qf[0][dc], sf[0][c]);
          sf[1][c] = MFMA_BF16(kf, qf[1][dc], sf[1][c]);
        }
      }
      __builtin_amdgcn_s_setprio(0);
      // ---- mask (diagonal) + in-lane max (NO cross-lane in common path) ----
      float lmax[2];
#pragma unroll
      for (int rr = 0; rr < 2; ++rr) {
        if (s == sd) {
          const int qq = q0 + wid * 32 + rr * 16 + fr;
#pragma unroll
          for (int c = 0; c < 4; ++c) {
            const int kb = s * 64 + c * 16 + hi * 4;
#pragma unroll
            for (int r = 0; r < 4; ++r)
              if (kb + r > qq) sf[rr][c][r] = -1e30f;
          }
        }
        float v = -1e30f;
#pragma unroll
        for (int c = 0; c < 4; ++c)
#pragma unroll
          for (int r = 0; r < 4; ++r) v = fmaxf(v, sf[rr][c][r]);
        lmax[rr] = v;
      }
      // ---- T13 defer-max + lazy reduction: reduce only on growth ----
      bool grow = (lmax[0] > m[0] + 8.f) | (lmax[1] > m[1] + 8.f);
      if (__any(grow)) {
        float a[2];
#pragma unroll
        for (int rr = 0; rr < 2; ++rr) {
          float v = lmax[rr];
          v = fmaxf(v, __shfl_xor(v, 16));
          v = fmaxf(v, __shfl_xor(v, 32));
          float mn = fmaxf(m[rr], v);
          a[rr] = __builtin_amdgcn_exp2f(m[rr] - mn);
          m[rr] = mn;
          l[rr] *= a[rr];
        }
#pragma unroll
        for (int rr = 0; rr < 2; ++rr)
#pragma unroll
          for (int r = 0; r < 4; ++r) {
            float aq = __shfl(a[rr], hi * 4 + r);   // a for q-row rr*16+hi*4+r
#pragma unroll
            for (int f = 0; f < 8; ++f) accO[rr][f][r] *= aq;
          }
      }
      // ---- exp2 + PER-LANE partial sum (row-sum deferred to epilogue) ----
#pragma unroll
      for (int rr = 0; rr < 2; ++rr) {
        float rs = 0.f;
#pragma unroll
        for (int c = 0; c < 4; ++c)
#pragma unroll
          for (int r = 0; r < 4; ++r) {
            float p = __builtin_amdgcn_exp2f(sf[rr][c][r] - m[rr]);
            sf[rr][c][r] = p;
            rs += p;
          }
        l[rr] += rs;
      }
      // ---- P -> LDS: 8 packed b64 writes (swizzled 16B slots), read 4 b128 A-frags ----
#pragma unroll
      for (int rr = 0; rr < 2; ++rr) {
        const int row = rr * 16 + fr;
        char* Prow = Pb + row * 128;
#pragma unroll
        for (int c = 0; c < 4; ++c) {
          uint32_t w0 = pk2(sf[rr][c][0], sf[rr][c][1]);
          uint32_t w1 = pk2(sf[rr][c][2], sf[rr][c][3]);
          int sl = (c * 2 + (hi >> 1)) ^ (row & 7);
          *(uint2*)(Prow + sl * 16 + (hi & 1) * 8) = make_uint2(w0, w1);
        }
      }
      bf16x8 pf[2][2];
#pragma unroll
      for (int rr = 0; rr < 2; ++rr) {
        const int row = rr * 16 + fr;
#pragma unroll
        for (int kc = 0; kc < 2; ++kc) {
          int sl = (kc * 4 + hi) ^ (row & 7);
          pf[rr][kc] = *(const bf16x8*)(Pb + row * 128 + sl * 16);
        }
      }
      // ---- PV ----
      const __hip_bfloat16* Vc = Vs[cur];
      __builtin_amdgcn_s_setprio(1);
#pragma unroll
      for (int kc = 0; kc < 2; ++kc)
#pragma unroll
        for (int f = 0; f < 8; ++f) {
          int vrow = f * 16 + fr;
          int vslot = (kc * 4 + hi) ^ (fr & 7);
          bf16x8 vf = *(const bf16x8*)(Vc + vrow * 64 + vslot * 8);
          accO[0][f] = MFMA_BF16(pf[0][kc], vf, accO[0][f]);
          accO[1][f] = MFMA_BF16(pf[1][kc], vf, accO[1][f]);
        }
      __builtin_amdgcn_s_setprio(0);
    }
    cur ^= 1;
  }

  // ---- epilogue: reduce per-lane l once; u = mix1*v + mix2*(accO/l); store m,l ----
  float lsum[2];
#pragma unroll
  for (int rr = 0; rr < 2; ++rr) {
    float v = l[rr];
    v += __shfl_xor(v, 16);
    v += __shfl_xor(v, 32);
    lsum[rr] = v;
  }
  const float m1v = mix1p[0], m2v = mix2p[0];
  float rlq[2][4];
#pragma unroll
  for (int rr = 0; rr < 2; ++rr) {
    float inv = 1.f / lsum[rr];
#pragma unroll
    for (int r = 0; r < 4; ++r) rlq[rr][r] = __shfl(inv, hi * 4 + r);
  }
  const int t0 = q0 + wid * 32;
#pragma unroll
  for (int rr = 0; rr < 2; ++rr) {
    const int tb = t0 + rr * 16 + hi * 4;
#pragma unroll
    for (int f = 0; f < 8; ++f) {
      const int d = f * 16 + fr;
      const ushort4 v4 = *(const ushort4*)(vt + ((size_t)g * 128 + d) * 2048 + tb);
      float u0 = m1v * b2f(v4.x) + m2v * (accO[rr][f][0] * rlq[rr][0]);
      float u1 = m1v * b2f(v4.y) + m2v * (accO[rr][f][1] * rlq[rr][1]);
      float u2 = m1v * b2f(v4.z) + m2v * (accO[rr][f][2] * rlq[rr][2]);
      float u3 = m1v * b2f(v4.w) + m2v * (accO[rr][f][3] * rlq[rr][3]);
      *(uint2*)(y1u + ((size_t)bh * 128 + d) * 2048 + tb) =
          make_uint2(pk2(u0, u1), pk2(u2, u3));
    }
  }
  if (hi == 0) {
#pragma unroll
    for (int rr = 0; rr < 2; ++rr) {
      Mb[(size_t)bh * 2048 + t0 + rr * 16 + fr] = m[rr];
      Lb[(size_t)bh * 2048 + t0 + rr * 16 + fr] = lsum[rr];
    }
  }
}

// ---------------- attention pass 2: ymix = att @ u  (direct final output) ----------------
__global__ __launch_bounds__(256, 2) void attn_pass2_kernel(
    const __hip_bfloat16* __restrict__ qT,
    const __hip_bfloat16* __restrict__ kT,
    const __hip_bfloat16* __restrict__ y1u,  // (B,H,HD,T)
    const float* __restrict__ Mb,
    const float* __restrict__ Lb,
    __hip_bfloat16* __restrict__ ymix) {     // (B,T,C)
  __shared__ __align__(16) __hip_bfloat16 Ks[2][64 * 128];
  __shared__ __align__(16) __hip_bfloat16 Vs[2][128 * 64];
  __shared__ __align__(16) char Ps[4][32 * 128];
  const int tid = threadIdx.x, lane = tid & 63, wid = tid >> 6;
  const int bi = blockIdx.x;
  const int u = bi & 255, half = bi >> 8;
  const int g = u & 7;
  const int pslot = (u >> 3) & 7;
  const int bh = g * 4 + (u >> 6);
  const int h = bh & 15, b = bh >> 4;
  const int j = half ? (15 - pslot) : pslot;
  const int q0 = j * 128;
  const int nt = 2 * j + 2;
  const int sd = 2 * j + (wid >> 1);
  const __hip_bfloat16* Kp = kT + (size_t)g * 2048 * 128;
  const __hip_bfloat16* Yp = y1u + (size_t)bh * 128 * 2048;
  const int fr = lane & 15, hi = lane >> 4;

  bf16x8 qf[2][4];
  float mr[2], rl[2];
  {
    const __hip_bfloat16* Qp = qT + ((size_t)bh * 2048 + q0 + wid * 32) * 128;
#pragma unroll
    for (int rr = 0; rr < 2; ++rr)
#pragma unroll
      for (int dc = 0; dc < 4; ++dc)
        qf[rr][dc] = *(const bf16x8*)(Qp + (rr * 16 + fr) * 128 + dc * 32 + hi * 8);
    const size_t qb = (size_t)bh * 2048 + q0 + wid * 32;
    mr[0] = Mb[qb + fr];        mr[1] = Mb[qb + 16 + fr];
    rl[0] = 1.f / Lb[qb + fr];  rl[1] = 1.f / Lb[qb + 16 + fr];
  }

  f32x4 accO[2][8] = {};
  char* Pb = Ps[wid];

  auto STAGE = [&](int buf, int kt) {
    const int k0 = kt * 64;
#pragma unroll
    for (int i = 0; i < 4; ++i) {
      int f = i * 256 + tid;
      int r = f >> 4, s = f & 15, sx = s ^ (r & 7);
      gload_lds16(Kp + (size_t)(k0 + r) * 128 + sx * 8,
                  (char*)Ks[buf] + (i * 256 + wid * 64) * 16);
    }
#pragma unroll
    for (int i = 0; i < 4; ++i) {
      int f = i * 256 + tid;
      int r = f >> 3, s = f & 7, sx = s ^ (r & 7);
      gload_lds16(Yp + (size_t)r * 2048 + k0 + sx * 8,
                  (char*)Vs[buf] + (i * 256 + wid * 64) * 16);
    }
  };

  STAGE(0, 0);
  int cur = 0;
  for (int s = 0; s < nt; ++s) {
    if (s > 0) __builtin_amdgcn_s_barrier();
    __builtin_amdgcn_sched_barrier(0);
    if (s + 1 < nt) STAGE(cur ^ 1, s + 1);
    __builtin_amdgcn_sched_barrier(0);
    if (s + 1 < nt) asm volatile("s_waitcnt vmcnt(8)" ::: "memory");
    else            asm volatile("s_waitcnt vmcnt(0)" ::: "memory");
    __builtin_amdgcn_s_barrier();
    __builtin_amdgcn_sched_barrier(0);

    const bool active = (s <= sd);
    if (active) {
      const char* Kc = (const char*)Ks[cur];
      f32x4 sf[2][4] = {};
      __builtin_amdgcn_s_setprio(1);
#pragma unroll
      for (int c = 0; c < 4; ++c) {
        const int krow = c * 16 + fr;
#pragma unroll
        for (int dc = 0; dc < 4; ++dc) {
          int slot = (dc * 4 + hi) ^ (krow & 7);
          bf16x8 kf = *(const bf16x8*)(Kc + krow * 256 + slot * 16);
          sf[0][c] = MFMA_BF16(kf, qf[0][dc], sf[0][c]);
          sf[1][c] = MFMA_BF16(kf, qf[1][dc], sf[1][c]);
        }
      }
      __builtin_amdgcn_s_setprio(0);
      // normalize P directly from stored stats (all fr-indexed, no shuffles)
#pragma unroll
      for (int rr = 0; rr < 2; ++rr) {
        if (s == sd) {
          const int qq = q0 + wid * 32 + rr * 16 + fr;
#pragma unroll
          for (int c = 0; c < 4; ++c) {
            const int kb = s * 64 + c * 16 + hi * 4;
#pragma unroll
            for (int r = 0; r < 4; ++r)
              if (kb + r > qq) sf[rr][c][r] = -1e30f;
          }
        }
#pragma unroll
        for (int c = 0; c < 4; ++c)
#pragma unroll
          for (int r = 0; r < 4; ++r)
            sf[rr][c][r] = __builtin_amdgcn_exp2f(sf[rr][c][r] - mr[rr]) * rl[rr];
      }
#pragma unroll
      for (int rr = 0; rr < 2; ++rr) {
        const int row = rr * 16 + fr;
        char* Prow = Pb + row * 128;
#pragma unroll
        for (int c = 0; c < 4; ++c) {
          uint32_t w0 = pk2(sf[rr][c][0], sf[rr][c][1]);
          uint32_t w1 = pk2(sf[rr][c][2], sf[rr][c][3]);
          int sl = (c * 2 + (hi >> 1)) ^ (row & 7);
          *(uint2*)(Prow + sl * 16 + (hi & 1) * 8) = make_uint2(w0, w1);
        }
      }
      bf16x8 pf[2][2];
#pragma unroll
      for (int rr = 0; rr < 2; ++rr) {
        const int row = rr * 16 + fr;
#pragma unroll
        for (int kc = 0; kc < 2; ++kc) {
          int sl = (kc * 4 + hi) ^ (row & 7);
          pf[rr][kc] = *(const bf16x8*)(Pb + row * 128 + sl * 16);
        }
      }
      const __hip_bfloat16* Vc = Vs[cur];
      __builtin_amdgcn_s_setprio(1);
#pragma unroll
      for (int kc = 0; kc < 2; ++kc)
#pragma unroll
        for (int f = 0; f < 8; ++f) {
          int vrow = f * 16 + fr;
          int vslot = (kc * 4 + hi) ^ (fr & 7);
          bf16x8 vf = *(const bf16x8*)(Vc + vrow * 64 + vslot * 8);
          accO[0][f] = MFMA_BF16(pf[0][kc], vf, accO[0][f]);
          accO[1][f] = MFMA_BF16(pf[1][kc], vf, accO[1][f]);
        }
      __builtin_amdgcn_s_setprio(0);
    }
    cur ^= 1;
  }

  // accO already IS the final mixed output (P pre-normalized, u pre-mixed)
#pragma unroll
  for (int rr = 0; rr < 2; ++rr) {
#pragma unroll
    for (int f = 0; f < 8; ++f) {
      const int d = f * 16 + fr;
#pragma unroll
      for (int r = 0; r < 4; ++r) {
        int q = q0 + wid * 32 + rr * 16 + hi * 4 + r;
        ymix[((size_t)b * 2048 + q) * 2048 + h * 128 + d] = __float2bfloat16(accO[rr][f][r]);
      }
    }
  }
}

// ---------------- launch ----------------
extern "C" void kernel_launch(void* const* d_in, const int* in_sizes, int n_in,
                              void* d_out, int out_size, void* d_ws, size_t ws_size,
                              hipStream_t stream) {
  const float* x    = (const float*)d_in[0];
  const float* cosb = (const float*)d_in[1];
  const float* sinb = (const float*)d_in[2];
  const float* Wq   = (const float*)d_in[3];
  const float* Wk   = (const float*)d_in[4];
  const float* Wv   = (const float*)d_in[5];
  const float* Wp   = (const float*)d_in[6];
  const float* mix1 = (const float*)d_in[7];
  const float* mix2 = (const float*)d_in[8];
  float* out = (float*)d_out;
  char* ws = (char*)d_ws;

  // workspace layout (bytes), peak ~80.2 MB
  __hip_bfloat16* xb   = (__hip_bfloat16*)(ws + 0);            // 16.78 MB; reused as ymix
  __hip_bfloat16* WTa  = (__hip_bfloat16*)(ws + 16777216);     // 12.58 MB
  __hip_bfloat16* WpT  = (__hip_bfloat16*)(ws + 29360128);     // 8.39 MB
  __hip_bfloat16* y1u  = (__hip_bfloat16*)(ws + 37748736);     // 16.78 MB
  float*          Mb   = (float*)(ws + 54525952);              // 0.26 MB
  float*          Lb   = (float*)(ws + 54788096);              // 0.26 MB
  __hip_bfloat16* qTb  = (__hip_bfloat16*)(ws + 55050240);     // 16.78 MB
  __hip_bfloat16* kTb  = (__hip_bfloat16*)(ws + 71827456);     // 4.19 MB
  __hip_bfloat16* vtb  = (__hip_bfloat16*)(ws + 76021760);     // 4.19 MB
  __hip_bfloat16* ymix = (__hip_bfloat16*)(ws + 0);

  dim3 tb(32, 8);
  prep_kernel<<<18432, tb, 0, stream>>>(x, xb, Wq, Wk, Wv, Wp, WTa, WpT);

  // fused QKV projection + RoPE + RMS + V-transpose (128x128 tiles, BK=64, 768 blocks)
  gemm_qkv_rope_kernel<<<768, 256, 0, stream>>>(xb, WTa, cosb, sinb, qTb, kTb, vtb);

  attn_pass1_kernel<<<512, 256, 0, stream>>>(qTb, kTb, vtb, y1u, Mb, Lb, mix1, mix2);
  attn_pass2_kernel<<<512, 256, 0, stream>>>(qTb, kTb, y1u, Mb, Lb, ymix);

  gemm_bf16_kernel<<<512, 256, 0, stream>>>(ymix, WpT, out, 4096, 2048, 2048);
}

// Round 14
// 237.486 us; speedup vs baseline: 1.2927x; 1.0268x over previous
//
#include <hip/hip_runtime.h>
#include <hip/hip_bf16.h>
#include <cstdint>
#include <cstddef>

#define AS1 __attribute__((address_space(1)))
#define AS3 __attribute__((address_space(3)))

typedef __attribute__((ext_vector_type(8))) short bf16x8;
typedef __attribute__((ext_vector_type(4))) float f32x4;

__device__ __forceinline__ void gload_lds16(const void* g, void* l) {
  __builtin_amdgcn_global_load_lds((const AS1 void*)g, (AS3 void*)l, 16, 0, 0);
}

#define MFMA_BF16(A, B, C) __builtin_amdgcn_mfma_f32_16x16x32_bf16((A), (B), (C), 0, 0, 0)

// (1/sqrt(128)) * log2(e) — folded into q at rope time; softmax runs in exp2 domain.
#define QSCALE 0.12751744f

__device__ __forceinline__ uint32_t pk2(float a, float b) {
  uint32_t ua = (uint32_t)__builtin_bit_cast(unsigned short, __float2bfloat16(a));
  uint32_t ub = (uint32_t)__builtin_bit_cast(unsigned short, __float2bfloat16(b));
  return ua | (ub << 16);
}
__device__ __forceinline__ float b2f(unsigned short u) {
  return __builtin_bit_cast(float, (uint32_t)u << 16);
}

// sum over 8 consecutive lanes (group-aligned): DPP xor1, xor2, half-mirror
__device__ __forceinline__ float red8_sum(float v) {
  int x;
  x = __builtin_amdgcn_update_dpp(0, __builtin_bit_cast(int, v), 0xB1, 0xF, 0xF, true);
  v += __builtin_bit_cast(float, x);
  x = __builtin_amdgcn_update_dpp(0, __builtin_bit_cast(int, v), 0x4E, 0xF, 0xF, true);
  v += __builtin_bit_cast(float, x);
  x = __builtin_amdgcn_update_dpp(0, __builtin_bit_cast(int, v), 0x141, 0xF, 0xF, true);
  v += __builtin_bit_cast(float, x);
  return v;
}

// ---------------- merged prep: x cast + weight transposes in one launch ----------------
__global__ __launch_bounds__(256) void prep_kernel(const float* __restrict__ x,
                                                   __hip_bfloat16* __restrict__ xb,
                                                   const float* __restrict__ Wq,
                                                   const float* __restrict__ Wk,
                                                   const float* __restrict__ Wv,
                                                   const float* __restrict__ Wp,
                                                   __hip_bfloat16* __restrict__ WTa,
                                                   __hip_bfloat16* __restrict__ WpT) {
  __shared__ float tile[32][33];
  int id = blockIdx.x;
  int tx = threadIdx.x, ty = threadIdx.y;
  if (id < 8192) {             // cast: 8192 blocks x 256 f32x4
    int i = id * 256 + ty * 32 + tx;
    float4 v = ((const float4*)x)[i];
    __hip_bfloat16* o = xb + (size_t)i * 4;
    o[0] = __float2bfloat16(v.x);
    o[1] = __float2bfloat16(v.y);
    o[2] = __float2bfloat16(v.z);
    o[3] = __float2bfloat16(v.w);
    return;
  }
  id -= 8192;
  const float* in; __hip_bfloat16* out; int is, os, bx, by;
  if (id < 4096)      { in = Wq; out = WTa;                          is = 2048; os = 2048; bx = id & 63; by = id >> 6; }
  else if (id < 5120) { int t = id - 4096; in = Wk; out = WTa + (size_t)2048 * 2048; is = 512; os = 2048; bx = t & 15; by = t >> 4; }
  else if (id < 6144) { int t = id - 5120; in = Wv; out = WTa + (size_t)2560 * 2048; is = 512; os = 2048; bx = t & 15; by = t >> 4; }
  else                { int t = id - 6144; in = Wp; out = WpT;       is = 2048; os = 2048; bx = t & 63; by = t >> 6; }
  int c0 = bx * 32, r0 = by * 32;
#pragma unroll
  for (int i = 0; i < 32; i += 8)
    tile[ty + i][tx] = in[(size_t)(r0 + ty + i) * is + c0 + tx];
  __syncthreads();
#pragma unroll
  for (int i = 0; i < 32; i += 8)
    out[(size_t)(c0 + ty + i) * os + r0 + tx] = __float2bfloat16(tile[tx][ty + i]);
}

// ---------------- qkv GEMM: 128x128 tile, BK=64, 4 waves, 2-phase counted-vmcnt ----------------
__global__ __launch_bounds__(256, 2) void gemm_qkv_rope_kernel(
    const __hip_bfloat16* __restrict__ A,
    const __hip_bfloat16* __restrict__ Bt,
    const float* __restrict__ cosb,
    const float* __restrict__ sinb,
    __hip_bfloat16* __restrict__ qT,
    __hip_bfloat16* __restrict__ kT,
    __hip_bfloat16* __restrict__ vt) {
  __shared__ __align__(16) char smem[65536];
  __hip_bfloat16* CL4 = (__hip_bfloat16*)smem;    // elem idx = (q4*133+col)*4 + rr
  const int K = 2048;
  const int tid = threadIdx.x;
  const int lane = tid & 63;
  const int wid = tid >> 6;
  const int wm = wid >> 1, wn = wid & 1;
  const int bid = blockIdx.x;
  const int swz = (bid & 7) * 96 + (bid >> 3);
  const int tm = swz / 24, tn = swz % 24;
  const int row0 = tm << 7, col0 = tn << 7;
  const int fr = lane & 15, hi = lane >> 4;

  auto STAGE = [&](int buf, int k0) {
#pragma unroll
    for (int i = 0; i < 4; ++i) {
      int f = i * 256 + tid;
      int r = f >> 3, s = f & 7, sx = s ^ (r & 7);
      gload_lds16(A + (size_t)(row0 + r) * K + k0 + sx * 8,
                  smem + buf * 16384 + f * 16);
    }
#pragma unroll
    for (int i = 0; i < 4; ++i) {
      int f = i * 256 + tid;
      int r = f >> 3, s = f & 7, sx = s ^ (r & 7);
      gload_lds16(Bt + (size_t)(col0 + r) * K + k0 + sx * 8,
                  smem + 32768 + buf * 16384 + f * 16);
    }
  };

  f32x4 acc[4][4] = {};
  STAGE(0, 0);
  int cur = 0;
  for (int kk = 0; kk < 32; ++kk) {
    if (kk > 0) __builtin_amdgcn_s_barrier();
    __builtin_amdgcn_sched_barrier(0);
    if (kk + 1 < 32) STAGE(cur ^ 1, (kk + 1) * 64);
    __builtin_amdgcn_sched_barrier(0);
    if (kk + 1 < 32) asm volatile("s_waitcnt vmcnt(8)" ::: "memory");
    else             asm volatile("s_waitcnt vmcnt(0)" ::: "memory");
    __builtin_amdgcn_s_barrier();
    __builtin_amdgcn_sched_barrier(0);
    const char* Ac = smem + cur * 16384;
    const char* Bc = smem + 32768 + cur * 16384;
#pragma unroll
    for (int kh = 0; kh < 2; ++kh) {
      bf16x8 af[4], bfr[4];
#pragma unroll
      for (int n = 0; n < 4; ++n) {
        int rowb = wn * 64 + n * 16 + fr;
        int sl = (kh * 4 + hi) ^ (rowb & 7);
        bfr[n] = *(const bf16x8*)(Bc + rowb * 128 + sl * 16);
      }
#pragma unroll
      for (int m = 0; m < 4; ++m) {
        int rowa = wm * 64 + m * 16 + fr;
        int sl = (kh * 4 + hi) ^ (rowa & 7);
        af[m] = *(const bf16x8*)(Ac + rowa * 128 + sl * 16);
      }
      __builtin_amdgcn_s_setprio(1);
#pragma unroll
      for (int m = 0; m < 4; ++m)
#pragma unroll
        for (int n = 0; n < 4; ++n)
          acc[m][n] = MFMA_BF16(af[m], bfr[n], acc[m][n]);
      __builtin_amdgcn_s_setprio(0);
    }
    cur ^= 1;
  }
  __syncthreads();

  // ---- pack acc -> CL4 ----
#pragma unroll
  for (int m = 0; m < 4; ++m)
#pragma unroll
    for (int n = 0; n < 4; ++n) {
      int q4 = wm * 16 + m * 4 + hi;
      int col = wn * 64 + n * 16 + fr;
      *(uint2*)(CL4 + ((q4 * 133 + col) << 2)) =
          make_uint2(pk2(acc[m][n][0], acc[m][n][1]), pk2(acc[m][n][2], acc[m][n][3]));
    }
  __syncthreads();

  const int b = row0 >> 11;
  const int t0 = row0 & 2047;

  if (col0 >= 2560) {
    const int hv = (col0 - 2560) >> 7;
    __hip_bfloat16* vb = vt + (size_t)(b * 4 + hv) * 128 * 2048;
    const int col = tid >> 1, th = tid & 1;
    uint2 w[16];
#pragma unroll
    for (int qq = 0; qq < 16; ++qq)
      w[qq] = *(const uint2*)(CL4 + (((th * 16 + qq) * 133 + col) << 2));
    __hip_bfloat16* dstv = vb + (size_t)col * 2048 + t0 + th * 64;
#pragma unroll
    for (int e = 0; e < 8; ++e)
      *(uint4*)(dstv + e * 8) = make_uint4(w[2 * e].x, w[2 * e].y, w[2 * e + 1].x, w[2 * e + 1].y);
    return;
  }

  const int quad = tid >> 3, cp = tid & 7;
  const int tb = t0 + quad * 4;
  bf16x8 lov[4], hiv[4];
#pragma unroll
  for (int e = 0; e < 4; ++e) {
    lov[e] = *(const bf16x8*)(CL4 + ((quad * 133 + cp * 8 + e * 2) << 2));
    hiv[e] = *(const bf16x8*)(CL4 + ((quad * 133 + 64 + cp * 8 + e * 2) << 2));
  }
  const float oscale = (col0 < 2048) ? QSCALE : 1.0f;
  __hip_bfloat16* dstq = (col0 < 2048)
      ? qT + (size_t)(b * 16 + (col0 >> 7)) * 2048 * 128
      : kT + (size_t)(b * 4 + ((col0 - 2048) >> 7)) * 2048 * 128;

  float o1v[4][8], o2v[4][8], ssum[4];
#pragma unroll
  for (int rr = 0; rr < 4; ++rr) {
    const float* cb = cosb + (size_t)(tb + rr) * 64 + cp * 8;
    const float* sb = sinb + (size_t)(tb + rr) * 64 + cp * 8;
    float4 c0 = *(const float4*)cb, c1 = *(const float4*)(cb + 4);
    float4 s0 = *(const float4*)sb, s1 = *(const float4*)(sb + 4);
    float cc[8] = {c0.x, c0.y, c0.z, c0.w, c1.x, c1.y, c1.z, c1.w};
    float sn[8] = {s0.x, s0.y, s0.z, s0.w, s1.x, s1.y, s1.z, s1.w};
    float ss = 0.f;
#pragma unroll
    for (int e = 0; e < 4; ++e)
#pragma unroll
      for (int w2 = 0; w2 < 2; ++w2) {
        int pd = e * 2 + w2;
        float x1 = b2f((unsigned short)lov[e][w2 * 4 + rr]);
        float x2 = b2f((unsigned short)hiv[e][w2 * 4 + rr]);
        float a = x1 * cc[pd] - x2 * sn[pd];
        float bb = x1 * sn[pd] + x2 * cc[pd];
        o1v[rr][pd] = a;
        o2v[rr][pd] = bb;
        ss += a * a + bb * bb;
      }
    ssum[rr] = ss;
  }
#pragma unroll
  for (int rr = 0; rr < 4; ++rr) {
    float rn = rsqrtf(red8_sum(ssum[rr]) * (1.f / 128.f) + 1e-6f) * oscale;
    __hip_bfloat16* dr = dstq + (size_t)(tb + rr) * 128 + cp * 8;
    *(uint4*)dr = make_uint4(pk2(o1v[rr][0] * rn, o1v[rr][1] * rn),
                             pk2(o1v[rr][2] * rn, o1v[rr][3] * rn),
                             pk2(o1v[rr][4] * rn, o1v[rr][5] * rn),
                             pk2(o1v[rr][6] * rn, o1v[rr][7] * rn));
    *(uint4*)(dr + 64) = make_uint4(pk2(o2v[rr][0] * rn, o2v[rr][1] * rn),
                                    pk2(o2v[rr][2] * rn, o2v[rr][3] * rn),
                                    pk2(o2v[rr][4] * rn, o2v[rr][5] * rn),
                                    pk2(o2v[rr][6] * rn, o2v[rr][7] * rn));
  }
}

// ---------------- generic bf16 GEMM: 128x128 tile, BK=64, swizzled (f32 out) ----------------
__global__ __launch_bounds__(256, 2) void gemm_bf16_kernel(const __hip_bfloat16* __restrict__ A,
                                                           const __hip_bfloat16* __restrict__ Bt,
                                                           float* __restrict__ C,
                                                           int M, int N, int K) {
  __shared__ __align__(16) char smem[65536];
  const int tid = threadIdx.x;
  const int lane = tid & 63;
  const int wid = tid >> 6;
  const int wm = wid >> 1, wn = wid & 1;
  const int nwg = gridDim.x;
  const int bid = blockIdx.x;
  const int swz = (bid & 7) * (nwg >> 3) + (bid >> 3);
  const int ntile = N >> 7;
  const int tm = swz / ntile, tn = swz % ntile;
  const int row0 = tm << 7, col0 = tn << 7;
  const int fr = lane & 15, hi = lane >> 4;

  auto STAGE = [&](int buf, int k0) {
#pragma unroll
    for (int i = 0; i < 4; ++i) {
      int f = i * 256 + tid;
      int r = f >> 3, s = f & 7, sx = s ^ (r & 7);
      gload_lds16(A + (size_t)(row0 + r) * K + k0 + sx * 8,
                  smem + buf * 16384 + f * 16);
    }
#pragma unroll
    for (int i = 0; i < 4; ++i) {
      int f = i * 256 + tid;
      int r = f >> 3, s = f & 7, sx = s ^ (r & 7);
      gload_lds16(Bt + (size_t)(col0 + r) * K + k0 + sx * 8,
                  smem + 32768 + buf * 16384 + f * 16);
    }
  };

  f32x4 acc[4][4] = {};
  const int nk = K >> 6;
  STAGE(0, 0);
  int cur = 0;
  for (int kk = 0; kk < nk; ++kk) {
    if (kk > 0) __builtin_amdgcn_s_barrier();
    __builtin_amdgcn_sched_barrier(0);
    if (kk + 1 < nk) STAGE(cur ^ 1, (kk + 1) * 64);
    __builtin_amdgcn_sched_barrier(0);
    if (kk + 1 < nk) asm volatile("s_waitcnt vmcnt(8)" ::: "memory");
    else             asm volatile("s_waitcnt vmcnt(0)" ::: "memory");
    __builtin_amdgcn_s_barrier();
    __builtin_amdgcn_sched_barrier(0);
    const char* Ac = smem + cur * 16384;
    const char* Bc = smem + 32768 + cur * 16384;
#pragma unroll
    for (int kh = 0; kh < 2; ++kh) {
      bf16x8 af[4], bfr[4];
#pragma unroll
      for (int n = 0; n < 4; ++n) {
        int rowb = wn * 64 + n * 16 + fr;
        int sl = (kh * 4 + hi) ^ (rowb & 7);
        bfr[n] = *(const bf16x8*)(Bc + rowb * 128 + sl * 16);
      }
#pragma unroll
      for (int m = 0; m < 4; ++m) {
        int rowa = wm * 64 + m * 16 + fr;
        int sl = (kh * 4 + hi) ^ (rowa & 7);
        af[m] = *(const bf16x8*)(Ac + rowa * 128 + sl * 16);
      }
      __builtin_amdgcn_s_setprio(1);
#pragma unroll
      for (int m = 0; m < 4; ++m)
#pragma unroll
        for (int n = 0; n < 4; ++n)
          acc[m][n] = MFMA_BF16(af[m], bfr[n], acc[m][n]);
      __builtin_amdgcn_s_setprio(0);
    }
    cur ^= 1;
  }

  const int cr = hi * 4;
#pragma unroll
  for (int m = 0; m < 4; ++m)
#pragma unroll
    for (int n = 0; n < 4; ++n) {
      int col = col0 + wn * 64 + n * 16 + fr;
#pragma unroll
      for (int r = 0; r < 4; ++r) {
        int row = row0 + wm * 64 + m * 16 + cr + r;
        C[(size_t)row * N + col] = acc[m][n][r];
      }
    }
}

// block decode (both passes): bi in [0,512): u=bi&255, half=bi>>8. g=u&7 = (b*4+kvh).
// bi and bi+256 (two halves of a balanced 34-step pair) land on the same CU under rr
// dispatch: per-CU balance at 2 blocks/CU.
//
// QK-AHEAD PIPELINE: iter s computes QK(s+1) into sfN while softmax(s)+P+PV(s) run
// on sfC (ping-pong sfA/sfB; nt always even -> 2-unrolled loop, no copies).
// Staging: K two-ahead (K(s+2) -> Ks[s&1]), V one-ahead (V(s+1) -> Vs[(s+1)&1]);
// counted vmcnt(8/4/0) keeps prefetches in flight across barriers.

// ---------------- attention pass 1: y1 = softmax(qk^T) v ; writes u = mix1*v + mix2*y1 ----------------
__global__ __launch_bounds__(256, 2) void attn_pass1_kernel(
    const __hip_bfloat16* __restrict__ qT,   // (B,H,T,HD), q pre-scaled
    const __hip_bfloat16* __restrict__ kT,   // (B,HK,T,HD)
    const __hip_bfloat16* __restrict__ vt,   // (B,HK,HD,T)
    __hip_bfloat16* __restrict__ y1u,        // (B,H,HD,T)  u = mix1*v + mix2*y1
    float* __restrict__ Mb,                  // (B,H,T)  (exp2 domain)
    float* __restrict__ Lb,
    const float* __restrict__ mix1p,
    const float* __restrict__ mix2p) {
  __shared__ __align__(16) __hip_bfloat16 Ks[2][64 * 128];
  __shared__ __align__(16) __hip_bfloat16 Vs[2][128 * 64];
  __shared__ __align__(16) char Ps[4][32 * 128];
  const int tid = threadIdx.x, lane = tid & 63, wid = tid >> 6;   // wid 0..3
  const int bi = blockIdx.x;
  const int u = bi & 255, half = bi >> 8;
  const int g = u & 7;
  const int pslot = (u >> 3) & 7;
  const int bh = g * 4 + (u >> 6);
  const int j = half ? (15 - pslot) : pslot;
  const int q0 = j * 128;
  const int nt = 2 * j + 2;                  // even
  const int sd = 2 * j + (wid >> 1);
  const __hip_bfloat16* Kp = kT + (size_t)g * 2048 * 128;
  const __hip_bfloat16* Vp = vt + (size_t)g * 128 * 2048;
  const int fr = lane & 15, hi = lane >> 4;

  bf16x8 qf[2][4];
  {
    const __hip_bfloat16* Qp = qT + ((size_t)bh * 2048 + q0 + wid * 32) * 128;
#pragma unroll
    for (int rr = 0; rr < 2; ++rr)
#pragma unroll
      for (int dc = 0; dc < 4; ++dc)
        qf[rr][dc] = *(const bf16x8*)(Qp + (rr * 16 + fr) * 128 + dc * 32 + hi * 8);
  }

  f32x4 accO[2][8] = {};
  float m[2], l[2];
  m[0] = m[1] = -1e30f; l[0] = l[1] = 0.f;

  char* Pb = Ps[wid];

  auto STAGE_K = [&](int buf, int kt) {      // 4 loads/thread
    const int k0 = kt * 64;
#pragma unroll
    for (int i = 0; i < 4; ++i) {
      int f = i * 256 + tid;
      int r = f >> 4, s = f & 15, sx = s ^ (r & 7);
      gload_lds16(Kp + (size_t)(k0 + r) * 128 + sx * 8,
                  (char*)Ks[buf] + (i * 256 + wid * 64) * 16);
    }
  };
  auto STAGE_V = [&](int buf, int kt) {      // 4 loads/thread
    const int k0 = kt * 64;
#pragma unroll
    for (int i = 0; i < 4; ++i) {
      int f = i * 256 + tid;
      int r = f >> 3, s = f & 7, sx = s ^ (r & 7);
      gload_lds16(Vp + (size_t)r * 2048 + k0 + sx * 8,
                  (char*)Vs[buf] + (i * 256 + wid * 64) * 16);
    }
  };

  auto QK = [&](int t, f32x4 (&sf)[2][4]) {  // S(t) from Ks[t&1]
    const char* Kc = (const char*)Ks[t & 1];
#pragma unroll
    for (int rr = 0; rr < 2; ++rr)
#pragma unroll
      for (int c = 0; c < 4; ++c) sf[rr][c] = (f32x4){0.f, 0.f, 0.f, 0.f};
    __builtin_amdgcn_s_setprio(1);
#pragma unroll
    for (int c = 0; c < 4; ++c) {
      const int krow = c * 16 + fr;
#pragma unroll
      for (int dc = 0; dc < 4; ++dc) {
        int slot = (dc * 4 + hi) ^ (krow & 7);
        bf16x8 kf = *(const bf16x8*)(Kc + krow * 256 + slot * 16);
        sf[0][c] = MFMA_BF16(kf, qf[0][dc], sf[0][c]);
        sf[1][c] = MFMA_BF16(kf, qf[1][dc], sf[1][c]);
      }
    }
    __builtin_amdgcn_s_setprio(0);
  };

  auto STEP = [&](int s, f32x4 (&sfC)[2][4], f32x4 (&sfN)[2][4]) {
    __builtin_amdgcn_s_barrier();            // G: compute(s-1)/prologue-QK closed
    __builtin_amdgcn_sched_barrier(0);
    if (s + 2 < nt) STAGE_K(s & 1, s + 2);
    if (s + 1 < nt) STAGE_V((s + 1) & 1, s + 1);
    __builtin_amdgcn_sched_barrier(0);
    if (s + 2 < nt)      asm volatile("s_waitcnt vmcnt(8)" ::: "memory");
    else if (s + 1 < nt) asm volatile("s_waitcnt vmcnt(4)" ::: "memory");
    else                 asm volatile("s_waitcnt vmcnt(0)" ::: "memory");
    __builtin_amdgcn_s_barrier();            // C: K(s+1), V(s) landed for all waves
    __builtin_amdgcn_sched_barrier(0);

    if (s + 1 <= sd) QK(s + 1, sfN);         // pipeline: next tile's scores

    if (s <= sd) {
      // ---- mask (diagonal) + in-lane max ----
      float lmax[2];
#pragma unroll
      for (int rr = 0; rr < 2; ++rr) {
        if (s == sd) {
          const int qq = q0 + wid * 32 + rr * 16 + fr;
#pragma unroll
          for (int c = 0; c < 4; ++c) {
            const int kb = s * 64 + c * 16 + hi * 4;
#pragma unroll
            for (int r = 0; r < 4; ++r)
              if (kb + r > qq) sfC[rr][c][r] = -1e30f;
          }
        }
        float v = -1e30f;
#pragma unroll
        for (int c = 0; c < 4; ++c)
#pragma unroll
          for (int r = 0; r < 4; ++r) v = fmaxf(v, sfC[rr][c][r]);
        lmax[rr] = v;
      }
      // ---- T13 defer-max + lazy reduction ----
      bool grow = (lmax[0] > m[0] + 8.f) | (lmax[1] > m[1] + 8.f);
      if (__any(grow)) {
        float a[2];
#pragma unroll
        for (int rr = 0; rr < 2; ++rr) {
          float v = lmax[rr];
          v = fmaxf(v, __shfl_xor(v, 16));
          v = fmaxf(v, __shfl_xor(v, 32));
          float mn = fmaxf(m[rr], v);
          a[rr] = __builtin_amdgcn_exp2f(m[rr] - mn);
          m[rr] = mn;
          l[rr] *= a[rr];
        }
#pragma unroll
        for (int rr = 0; rr < 2; ++rr)
#pragma unroll
          for (int r = 0; r < 4; ++r) {
            float aq = __shfl(a[rr], hi * 4 + r);
#pragma unroll
            for (int f = 0; f < 8; ++f) accO[rr][f][r] *= aq;
          }
      }
      // ---- exp2 + per-lane partial sum ----
#pragma unroll
      for (int rr = 0; rr < 2; ++rr) {
        float rs = 0.f;
#pragma unroll
        for (int c = 0; c < 4; ++c)
#pragma unroll
          for (int r = 0; r < 4; ++r) {
            float p = __builtin_amdgcn_exp2f(sfC[rr][c][r] - m[rr]);
            sfC[rr][c][r] = p;
            rs += p;
          }
        l[rr] += rs;
      }
      // ---- P -> LDS (packed b64, swizzled) + A-frag readback ----
#pragma unroll
      for (int rr = 0; rr < 2; ++rr) {
        const int row = rr * 16 + fr;
        char* Prow = Pb + row * 128;
#pragma unroll
        for (int c = 0; c < 4; ++c) {
          uint32_t w0 = pk2(sfC[rr][c][0], sfC[rr][c][1]);
          uint32_t w1 = pk2(sfC[rr][c][2], sfC[rr][c][3]);
          int sl = (c * 2 + (hi >> 1)) ^ (row & 7);
          *(uint2*)(Prow + sl * 16 + (hi & 1) * 8) = make_uint2(w0, w1);
        }
      }
      bf16x8 pf[2][2];
#pragma unroll
      for (int rr = 0; rr < 2; ++rr) {
        const int row = rr * 16 + fr;
#pragma unroll
        for (int kc = 0; kc < 2; ++kc) {
          int sl = (kc * 4 + hi) ^ (row & 7);
          pf[rr][kc] = *(const bf16x8*)(Pb + row * 128 + sl * 16);
        }
      }
      // ---- PV from Vs[s&1] ----
      const __hip_bfloat16* Vc = Vs[s & 1];
      __builtin_amdgcn_s_setprio(1);
#pragma unroll
      for (int kc = 0; kc < 2; ++kc)
#pragma unroll
        for (int f = 0; f < 8; ++f) {
          int vrow = f * 16 + fr;
          int vslot = (kc * 4 + hi) ^ (fr & 7);
          bf16x8 vf = *(const bf16x8*)(Vc + vrow * 64 + vslot * 8);
          accO[0][f] = MFMA_BF16(pf[0][kc], vf, accO[0][f]);
          accO[1][f] = MFMA_BF16(pf[1][kc], vf, accO[1][f]);
        }
      __builtin_amdgcn_s_setprio(0);
    }
  };

  // prologue: K0, V0, K1 staged; QK(0)
  f32x4 sfA[2][4], sfB[2][4];
  STAGE_K(0, 0);
  STAGE_V(0, 0);
  STAGE_K(1, 1);
  asm volatile("s_waitcnt vmcnt(8)" ::: "memory");   // K0 landed (V0, K1 in flight)
  __builtin_amdgcn_s_barrier();
  __builtin_amdgcn_sched_barrier(0);
  QK(0, sfA);

  for (int s2 = 0; s2 < nt; s2 += 2) {
    STEP(s2, sfA, sfB);
    STEP(s2 + 1, sfB, sfA);
  }

  // ---- epilogue: reduce per-lane l once; u = mix1*v + mix2*(accO/l); store m,l ----
  float lsum[2];
#pragma unroll
  for (int rr = 0; rr < 2; ++rr) {
    float v = l[rr];
    v += __shfl_xor(v, 16);
    v += __shfl_xor(v, 32);
    lsum[rr] = v;
  }
  const float m1v = mix1p[0], m2v = mix2p[0];
  float rlq[2][4];
#pragma unroll
  for (int rr = 0; rr < 2; ++rr) {
    float inv = 1.f / lsum[rr];
#pragma unroll
    for (int r = 0; r < 4; ++r) rlq[rr][r] = __shfl(inv, hi * 4 + r);
  }
  const int t0 = q0 + wid * 32;
#pragma unroll
  for (int rr = 0; rr < 2; ++rr) {
    const int tb = t0 + rr * 16 + hi * 4;
#pragma unroll
    for (int f = 0; f < 8; ++f) {
      const int d = f * 16 + fr;
      const ushort4 v4 = *(const ushort4*)(vt + ((size_t)g * 128 + d) * 2048 + tb);
      float u0 = m1v * b2f(v4.x) + m2v * (accO[rr][f][0] * rlq[rr][0]);
      float u1 = m1v * b2f(v4.y) + m2v * (accO[rr][f][1] * rlq[rr][1]);
      float u2 = m1v * b2f(v4.z) + m2v * (accO[rr][f][2] * rlq[rr][2]);
      float u3 = m1v * b2f(v4.w) + m2v * (accO[rr][f][3] * rlq[rr][3]);
      *(uint2*)(y1u + ((size_t)bh * 128 + d) * 2048 + tb) =
          make_uint2(pk2(u0, u1), pk2(u2, u3));
    }
  }
  if (hi == 0) {
#pragma unroll
    for (int rr = 0; rr < 2; ++rr) {
      Mb[(size_t)bh * 2048 + t0 + rr * 16 + fr] = m[rr];
      Lb[(size_t)bh * 2048 + t0 + rr * 16 + fr] = lsum[rr];
    }
  }
}

// ---------------- attention pass 2: ymix = att @ u  (direct final output) ----------------
__global__ __launch_bounds__(256, 2) void attn_pass2_kernel(
    const __hip_bfloat16* __restrict__ qT,
    const __hip_bfloat16* __restrict__ kT,
    const __hip_bfloat16* __restrict__ y1u,  // (B,H,HD,T)
    const float* __restrict__ Mb,
    const float* __restrict__ Lb,
    __hip_bfloat16* __restrict__ ymix) {     // (B,T,C)
  __shared__ __align__(16) __hip_bfloat16 Ks[2][64 * 128];
  __shared__ __align__(16) __hip_bfloat16 Vs[2][128 * 64];
  __shared__ __align__(16) char Ps[4][32 * 128];
  const int tid = threadIdx.x, lane = tid & 63, wid = tid >> 6;
  const int bi = blockIdx.x;
  const int u = bi & 255, half = bi >> 8;
  const int g = u & 7;
  const int pslot = (u >> 3) & 7;
  const int bh = g * 4 + (u >> 6);
  const int h = bh & 15, b = bh >> 4;
  const int j = half ? (15 - pslot) : pslot;
  const int q0 = j * 128;
  const int nt = 2 * j + 2;
  const int sd = 2 * j + (wid >> 1);
  const __hip_bfloat16* Kp = kT + (size_t)g * 2048 * 128;
  const __hip_bfloat16* Yp = y1u + (size_t)bh * 128 * 2048;
  const int fr = lane & 15, hi = lane >> 4;

  bf16x8 qf[2][4];
  float mr[2], rl[2];
  {
    const __hip_bfloat16* Qp = qT + ((size_t)bh * 2048 + q0 + wid * 32) * 128;
#pragma unroll
    for (int rr = 0; rr < 2; ++rr)
#pragma unroll
      for (int dc = 0; dc < 4; ++dc)
        qf[rr][dc] = *(const bf16x8*)(Qp + (rr * 16 + fr) * 128 + dc * 32 + hi * 8);
    const size_t qb = (size_t)bh * 2048 + q0 + wid * 32;
    mr[0] = Mb[qb + fr];        mr[1] = Mb[qb + 16 + fr];
    rl[0] = 1.f / Lb[qb + fr];  rl[1] = 1.f / Lb[qb + 16 + fr];
  }

  f32x4 accO[2][8] = {};
  char* Pb = Ps[wid];

  auto STAGE_K = [&](int buf, int kt) {
    const int k0 = kt * 64;
#pragma unroll
    for (int i = 0; i < 4; ++i) {
      int f = i * 256 + tid;
      int r = f >> 4, s = f & 15, sx = s ^ (r & 7);
      gload_lds16(Kp + (size_t)(k0 + r) * 128 + sx * 8,
                  (char*)Ks[buf] + (i * 256 + wid * 64) * 16);
    }
  };
  auto STAGE_V = [&](int buf, int kt) {
    const int k0 = kt * 64;
#pragma unroll
    for (int i = 0; i < 4; ++i) {
      int f = i * 256 + tid;
      int r = f >> 3, s = f & 7, sx = s ^ (r & 7);
      gload_lds16(Yp + (size_t)r * 2048 + k0 + sx * 8,
                  (char*)Vs[buf] + (i * 256 + wid * 64) * 16);
    }
  };

  auto QK = [&](int t, f32x4 (&sf)[2][4]) {
    const char* Kc = (const char*)Ks[t & 1];
#pragma unroll
    for (int rr = 0; rr < 2; ++rr)
#pragma unroll
      for (int c = 0; c < 4; ++c) sf[rr][c] = (f32x4){0.f, 0.f, 0.f, 0.f};
    __builtin_amdgcn_s_setprio(1);
#pragma unroll
    for (int c = 0; c < 4; ++c) {
      const int krow = c * 16 + fr;
#pragma unroll
      for (int dc = 0; dc < 4; ++dc) {
        int slot = (dc * 4 + hi) ^ (krow & 7);
        bf16x8 kf = *(const bf16x8*)(Kc + krow * 256 + slot * 16);
        sf[0][c] = MFMA_BF16(kf, qf[0][dc], sf[0][c]);
        sf[1][c] = MFMA_BF16(kf, qf[1][dc], sf[1][c]);
      }
    }
    __builtin_amdgcn_s_setprio(0);
  };

  auto STEP = [&](int s, f32x4 (&sfC)[2][4], f32x4 (&sfN)[2][4]) {
    __builtin_amdgcn_s_barrier();
    __builtin_amdgcn_sched_barrier(0);
    if (s + 2 < nt) STAGE_K(s & 1, s + 2);
    if (s + 1 < nt) STAGE_V((s + 1) & 1, s + 1);
    __builtin_amdgcn_sched_barrier(0);
    if (s + 2 < nt)      asm volatile("s_waitcnt vmcnt(8)" ::: "memory");
    else if (s + 1 < nt) asm volatile("s_waitcnt vmcnt(4)" ::: "memory");
    else                 asm volatile("s_waitcnt vmcnt(0)" ::: "memory");
    __builtin_amdgcn_s_barrier();
    __builtin_amdgcn_sched_barrier(0);

    if (s + 1 <= sd) QK(s + 1, sfN);

    if (s <= sd) {
      // normalize P from stored stats (all fr-indexed)
#pragma unroll
      for (int rr = 0; rr < 2; ++rr) {
        if (s == sd) {
          const int qq = q0 + wid * 32 + rr * 16 + fr;
#pragma unroll
          for (int c = 0; c < 4; ++c) {
            const int kb = s * 64 + c * 16 + hi * 4;
#pragma unroll
            for (int r = 0; r < 4; ++r)
              if (kb + r > qq) sfC[rr][c][r] = -1e30f;
          }
        }
#pragma unroll
        for (int c = 0; c < 4; ++c)
#pragma unroll
          for (int r = 0; r < 4; ++r)
            sfC[rr][c][r] = __builtin_amdgcn_exp2f(sfC[rr][c][r] - mr[rr]) * rl[rr];
      }
#pragma unroll
      for (int rr = 0; rr < 2; ++rr) {
        const int row = rr * 16 + fr;
        char* Prow = Pb + row * 128;
#pragma unroll
        for (int c = 0; c < 4; ++c) {
          uint32_t w0 = pk2(sfC[rr][c][0], sfC[rr][c][1]);
          uint32_t w1 = pk2(sfC[rr][c][2], sfC[rr][c][3]);
          int sl = (c * 2 + (hi >> 1)) ^ (row & 7);
          *(uint2*)(Prow + sl * 16 + (hi & 1) * 8) = make_uint2(w0, w1);
        }
      }
      bf16x8 pf[2][2];
#pragma unroll
      for (int rr = 0; rr < 2; ++rr) {
        const int row = rr * 16 + fr;
#pragma unroll
        for (int kc = 0; kc < 2; ++kc) {
          int sl = (kc * 4 + hi) ^ (row & 7);
          pf[rr][kc] = *(const bf16x8*)(Pb + row * 128 + sl * 16);
        }
      }
      const __hip_bfloat16* Vc = Vs[s & 1];
      __builtin_amdgcn_s_setprio(1);
#pragma unroll
      for (int kc = 0; kc < 2; ++kc)
#pragma unroll
        for (int f = 0; f < 8; ++f) {
          int vrow = f * 16 + fr;
          int vslot = (kc * 4 + hi) ^ (fr & 7);
          bf16x8 vf = *(const bf16x8*)(Vc + vrow * 64 + vslot * 8);
          accO[0][f] = MFMA_BF16(pf[0][kc], vf, accO[0][f]);
          accO[1][f] = MFMA_BF16(pf[1][kc], vf, accO[1][f]);
        }
      __builtin_amdgcn_s_setprio(0);
    }
  };

  f32x4 sfA[2][4], sfB[2][4];
  STAGE_K(0, 0);
  STAGE_V(0, 0);
  STAGE_K(1, 1);
  asm volatile("s_waitcnt vmcnt(8)" ::: "memory");
  __builtin_amdgcn_s_barrier();
  __builtin_amdgcn_sched_barrier(0);
  QK(0, sfA);

  for (int s2 = 0; s2 < nt; s2 += 2) {
    STEP(s2, sfA, sfB);
    STEP(s2 + 1, sfB, sfA);
  }

  // accO already IS the final mixed output (P pre-normalized, u pre-mixed)
#pragma unroll
  for (int rr = 0; rr < 2; ++rr) {
#pragma unroll
    for (int f = 0; f < 8; ++f) {
      const int d = f * 16 + fr;
#pragma unroll
      for (int r = 0; r < 4; ++r) {
        int q = q0 + wid * 32 + rr * 16 + hi * 4 + r;
        ymix[((size_t)b * 2048 + q) * 2048 + h * 128 + d] = __float2bfloat16(accO[rr][f][r]);
      }
    }
  }
}

// ---------------- launch ----------------
extern "C" void kernel_launch(void* const* d_in, const int* in_sizes, int n_in,
                              void* d_out, int out_size, void* d_ws, size_t ws_size,
                              hipStream_t stream) {
  const float* x    = (const float*)d_in[0];
  const float* cosb = (const float*)d_in[1];
  const float* sinb = (const float*)d_in[2];
  const float* Wq   = (const float*)d_in[3];
  const float* Wk   = (const float*)d_in[4];
  const float* Wv   = (const float*)d_in[5];
  const float* Wp   = (const float*)d_in[6];
  const float* mix1 = (const float*)d_in[7];
  const float* mix2 = (const float*)d_in[8];
  float* out = (float*)d_out;
  char* ws = (char*)d_ws;

  // workspace layout (bytes), peak ~80.2 MB
  __hip_bfloat16* xb   = (__hip_bfloat16*)(ws + 0);            // 16.78 MB; reused as ymix
  __hip_bfloat16* WTa  = (__hip_bfloat16*)(ws + 16777216);     // 12.58 MB
  __hip_bfloat16* WpT  = (__hip_bfloat16*)(ws + 29360128);     // 8.39 MB
  __hip_bfloat16* y1u  = (__hip_bfloat16*)(ws + 37748736);     // 16.78 MB
  float*          Mb   = (float*)(ws + 54525952);              // 0.26 MB
  float*          Lb   = (float*)(ws + 54788096);              // 0.26 MB
  __hip_bfloat16* qTb  = (__hip_bfloat16*)(ws + 55050240);     // 16.78 MB
  __hip_bfloat16* kTb  = (__hip_bfloat16*)(ws + 71827456);     // 4.19 MB
  __hip_bfloat16* vtb  = (__hip_bfloat16*)(ws + 76021760);     // 4.19 MB
  __hip_bfloat16* ymix = (__hip_bfloat16*)(ws + 0);

  dim3 tb(32, 8);
  prep_kernel<<<18432, tb, 0, stream>>>(x, xb, Wq, Wk, Wv, Wp, WTa, WpT);

  // fused QKV projection + RoPE + RMS + V-transpose (128x128 tiles, BK=64, 768 blocks)
  gemm_qkv_rope_kernel<<<768, 256, 0, stream>>>(xb, WTa, cosb, sinb, qTb, kTb, vtb);

  attn_pass1_kernel<<<512, 256, 0, stream>>>(qTb, kTb, vtb, y1u, Mb, Lb, mix1, mix2);
  attn_pass2_kernel<<<512, 256, 0, stream>>>(qTb, kTb, y1u, Mb, Lb, ymix);

  gemm_bf16_kernel<<<512, 256, 0, stream>>>(ymix, WpT, out, 4096, 2048, 2048);
}

// Round 15
// 232.762 us; speedup vs baseline: 1.3189x; 1.0203x over previous
//
#include <hip/hip_runtime.h>
#include <hip/hip_bf16.h>
#include <cstdint>
#include <cstddef>

#define AS1 __attribute__((address_space(1)))
#define AS3 __attribute__((address_space(3)))

typedef __attribute__((ext_vector_type(8))) short bf16x8;
typedef __attribute__((ext_vector_type(4))) float f32x4;

__device__ __forceinline__ void gload_lds16(const void* g, void* l) {
  __builtin_amdgcn_global_load_lds((const AS1 void*)g, (AS3 void*)l, 16, 0, 0);
}

#define MFMA_BF16(A, B, C) __builtin_amdgcn_mfma_f32_16x16x32_bf16((A), (B), (C), 0, 0, 0)

// (1/sqrt(128)) * log2(e) — folded into q at rope time; softmax runs in exp2 domain.
#define QSCALE 0.12751744f
// STATIC softmax max: q,k RMS-normalized => |q.k|_exp2 <= sqrt(128)*log2(e) = 16.32.
// exp2(s - SMAX) <= 1 always, so online max tracking is unnecessary (exact softmax).
#define SMAX 16.5f

__device__ __forceinline__ uint32_t pk2(float a, float b) {
  uint32_t ua = (uint32_t)__builtin_bit_cast(unsigned short, __float2bfloat16(a));
  uint32_t ub = (uint32_t)__builtin_bit_cast(unsigned short, __float2bfloat16(b));
  return ua | (ub << 16);
}
__device__ __forceinline__ float b2f(unsigned short u) {
  return __builtin_bit_cast(float, (uint32_t)u << 16);
}

// sum over 8 consecutive lanes (group-aligned): DPP xor1, xor2, half-mirror
__device__ __forceinline__ float red8_sum(float v) {
  int x;
  x = __builtin_amdgcn_update_dpp(0, __builtin_bit_cast(int, v), 0xB1, 0xF, 0xF, true);
  v += __builtin_bit_cast(float, x);
  x = __builtin_amdgcn_update_dpp(0, __builtin_bit_cast(int, v), 0x4E, 0xF, 0xF, true);
  v += __builtin_bit_cast(float, x);
  x = __builtin_amdgcn_update_dpp(0, __builtin_bit_cast(int, v), 0x141, 0xF, 0xF, true);
  v += __builtin_bit_cast(float, x);
  return v;
}

// ---------------- merged prep: x cast + weight transposes in one launch ----------------
__global__ __launch_bounds__(256) void prep_kernel(const float* __restrict__ x,
                                                   __hip_bfloat16* __restrict__ xb,
                                                   const float* __restrict__ Wq,
                                                   const float* __restrict__ Wk,
                                                   const float* __restrict__ Wv,
                                                   const float* __restrict__ Wp,
                                                   __hip_bfloat16* __restrict__ WTa,
                                                   __hip_bfloat16* __restrict__ WpT) {
  __shared__ float tile[32][33];
  int id = blockIdx.x;
  int tx = threadIdx.x, ty = threadIdx.y;
  if (id < 8192) {             // cast: 8192 blocks x 256 f32x4
    int i = id * 256 + ty * 32 + tx;
    float4 v = ((const float4*)x)[i];
    __hip_bfloat16* o = xb + (size_t)i * 4;
    o[0] = __float2bfloat16(v.x);
    o[1] = __float2bfloat16(v.y);
    o[2] = __float2bfloat16(v.z);
    o[3] = __float2bfloat16(v.w);
    return;
  }
  id -= 8192;
  const float* in; __hip_bfloat16* out; int is, os, bx, by;
  if (id < 4096)      { in = Wq; out = WTa;                          is = 2048; os = 2048; bx = id & 63; by = id >> 6; }
  else if (id < 5120) { int t = id - 4096; in = Wk; out = WTa + (size_t)2048 * 2048; is = 512; os = 2048; bx = t & 15; by = t >> 4; }
  else if (id < 6144) { int t = id - 5120; in = Wv; out = WTa + (size_t)2560 * 2048; is = 512; os = 2048; bx = t & 15; by = t >> 4; }
  else                { int t = id - 6144; in = Wp; out = WpT;       is = 2048; os = 2048; bx = t & 63; by = t >> 6; }
  int c0 = bx * 32, r0 = by * 32;
#pragma unroll
  for (int i = 0; i < 32; i += 8)
    tile[ty + i][tx] = in[(size_t)(r0 + ty + i) * is + c0 + tx];
  __syncthreads();
#pragma unroll
  for (int i = 0; i < 32; i += 8)
    out[(size_t)(c0 + ty + i) * os + r0 + tx] = __float2bfloat16(tile[tx][ty + i]);
}

// ---------------- qkv GEMM: 128x128 tile, BK=64, 4 waves, 2-phase counted-vmcnt ----------------
__global__ __launch_bounds__(256, 2) void gemm_qkv_rope_kernel(
    const __hip_bfloat16* __restrict__ A,
    const __hip_bfloat16* __restrict__ Bt,
    const float* __restrict__ cosb,
    const float* __restrict__ sinb,
    __hip_bfloat16* __restrict__ qT,
    __hip_bfloat16* __restrict__ kT,
    __hip_bfloat16* __restrict__ vt) {
  __shared__ __align__(16) char smem[65536];
  __hip_bfloat16* CL4 = (__hip_bfloat16*)smem;    // elem idx = (q4*133+col)*4 + rr
  const int K = 2048;
  const int tid = threadIdx.x;
  const int lane = tid & 63;
  const int wid = tid >> 6;
  const int wm = wid >> 1, wn = wid & 1;
  const int bid = blockIdx.x;
  const int swz = (bid & 7) * 96 + (bid >> 3);
  const int tm = swz / 24, tn = swz % 24;
  const int row0 = tm << 7, col0 = tn << 7;
  const int fr = lane & 15, hi = lane >> 4;

  auto STAGE = [&](int buf, int k0) {
#pragma unroll
    for (int i = 0; i < 4; ++i) {
      int f = i * 256 + tid;
      int r = f >> 3, s = f & 7, sx = s ^ (r & 7);
      gload_lds16(A + (size_t)(row0 + r) * K + k0 + sx * 8,
                  smem + buf * 16384 + f * 16);
    }
#pragma unroll
    for (int i = 0; i < 4; ++i) {
      int f = i * 256 + tid;
      int r = f >> 3, s = f & 7, sx = s ^ (r & 7);
      gload_lds16(Bt + (size_t)(col0 + r) * K + k0 + sx * 8,
                  smem + 32768 + buf * 16384 + f * 16);
    }
  };

  f32x4 acc[4][4] = {};
  STAGE(0, 0);
  int cur = 0;
  for (int kk = 0; kk < 32; ++kk) {
    if (kk > 0) __builtin_amdgcn_s_barrier();
    __builtin_amdgcn_sched_barrier(0);
    if (kk + 1 < 32) STAGE(cur ^ 1, (kk + 1) * 64);
    __builtin_amdgcn_sched_barrier(0);
    if (kk + 1 < 32) asm volatile("s_waitcnt vmcnt(8)" ::: "memory");
    else             asm volatile("s_waitcnt vmcnt(0)" ::: "memory");
    __builtin_amdgcn_s_barrier();
    __builtin_amdgcn_sched_barrier(0);
    const char* Ac = smem + cur * 16384;
    const char* Bc = smem + 32768 + cur * 16384;
#pragma unroll
    for (int kh = 0; kh < 2; ++kh) {
      bf16x8 af[4], bfr[4];
#pragma unroll
      for (int n = 0; n < 4; ++n) {
        int rowb = wn * 64 + n * 16 + fr;
        int sl = (kh * 4 + hi) ^ (rowb & 7);
        bfr[n] = *(const bf16x8*)(Bc + rowb * 128 + sl * 16);
      }
#pragma unroll
      for (int m = 0; m < 4; ++m) {
        int rowa = wm * 64 + m * 16 + fr;
        int sl = (kh * 4 + hi) ^ (rowa & 7);
        af[m] = *(const bf16x8*)(Ac + rowa * 128 + sl * 16);
      }
      __builtin_amdgcn_s_setprio(1);
#pragma unroll
      for (int m = 0; m < 4; ++m)
#pragma unroll
        for (int n = 0; n < 4; ++n)
          acc[m][n] = MFMA_BF16(af[m], bfr[n], acc[m][n]);
      __builtin_amdgcn_s_setprio(0);
    }
    cur ^= 1;
  }
  __syncthreads();

  // ---- pack acc -> CL4 ----
#pragma unroll
  for (int m = 0; m < 4; ++m)
#pragma unroll
    for (int n = 0; n < 4; ++n) {
      int q4 = wm * 16 + m * 4 + hi;
      int col = wn * 64 + n * 16 + fr;
      *(uint2*)(CL4 + ((q4 * 133 + col) << 2)) =
          make_uint2(pk2(acc[m][n][0], acc[m][n][1]), pk2(acc[m][n][2], acc[m][n][3]));
    }
  __syncthreads();

  const int b = row0 >> 11;
  const int t0 = row0 & 2047;

  if (col0 >= 2560) {
    const int hv = (col0 - 2560) >> 7;
    __hip_bfloat16* vb = vt + (size_t)(b * 4 + hv) * 128 * 2048;
    const int col = tid >> 1, th = tid & 1;
    uint2 w[16];
#pragma unroll
    for (int qq = 0; qq < 16; ++qq)
      w[qq] = *(const uint2*)(CL4 + (((th * 16 + qq) * 133 + col) << 2));
    __hip_bfloat16* dstv = vb + (size_t)col * 2048 + t0 + th * 64;
#pragma unroll
    for (int e = 0; e < 8; ++e)
      *(uint4*)(dstv + e * 8) = make_uint4(w[2 * e].x, w[2 * e].y, w[2 * e + 1].x, w[2 * e + 1].y);
    return;
  }

  const int quad = tid >> 3, cp = tid & 7;
  const int tb = t0 + quad * 4;
  bf16x8 lov[4], hiv[4];
#pragma unroll
  for (int e = 0; e < 4; ++e) {
    lov[e] = *(const bf16x8*)(CL4 + ((quad * 133 + cp * 8 + e * 2) << 2));
    hiv[e] = *(const bf16x8*)(CL4 + ((quad * 133 + 64 + cp * 8 + e * 2) << 2));
  }
  const float oscale = (col0 < 2048) ? QSCALE : 1.0f;
  __hip_bfloat16* dstq = (col0 < 2048)
      ? qT + (size_t)(b * 16 + (col0 >> 7)) * 2048 * 128
      : kT + (size_t)(b * 4 + ((col0 - 2048) >> 7)) * 2048 * 128;

  float o1v[4][8], o2v[4][8], ssum[4];
#pragma unroll
  for (int rr = 0; rr < 4; ++rr) {
    const float* cb = cosb + (size_t)(tb + rr) * 64 + cp * 8;
    const float* sb = sinb + (size_t)(tb + rr) * 64 + cp * 8;
    float4 c0 = *(const float4*)cb, c1 = *(const float4*)(cb + 4);
    float4 s0 = *(const float4*)sb, s1 = *(const float4*)(sb + 4);
    float cc[8] = {c0.x, c0.y, c0.z, c0.w, c1.x, c1.y, c1.z, c1.w};
    float sn[8] = {s0.x, s0.y, s0.z, s0.w, s1.x, s1.y, s1.z, s1.w};
    float ss = 0.f;
#pragma unroll
    for (int e = 0; e < 4; ++e)
#pragma unroll
      for (int w2 = 0; w2 < 2; ++w2) {
        int pd = e * 2 + w2;
        float x1 = b2f((unsigned short)lov[e][w2 * 4 + rr]);
        float x2 = b2f((unsigned short)hiv[e][w2 * 4 + rr]);
        float a = x1 * cc[pd] - x2 * sn[pd];
        float bb = x1 * sn[pd] + x2 * cc[pd];
        o1v[rr][pd] = a;
        o2v[rr][pd] = bb;
        ss += a * a + bb * bb;
      }
    ssum[rr] = ss;
  }
#pragma unroll
  for (int rr = 0; rr < 4; ++rr) {
    float rn = rsqrtf(red8_sum(ssum[rr]) * (1.f / 128.f) + 1e-6f) * oscale;
    __hip_bfloat16* dr = dstq + (size_t)(tb + rr) * 128 + cp * 8;
    *(uint4*)dr = make_uint4(pk2(o1v[rr][0] * rn, o1v[rr][1] * rn),
                             pk2(o1v[rr][2] * rn, o1v[rr][3] * rn),
                             pk2(o1v[rr][4] * rn, o1v[rr][5] * rn),
                             pk2(o1v[rr][6] * rn, o1v[rr][7] * rn));
    *(uint4*)(dr + 64) = make_uint4(pk2(o2v[rr][0] * rn, o2v[rr][1] * rn),
                                    pk2(o2v[rr][2] * rn, o2v[rr][3] * rn),
                                    pk2(o2v[rr][4] * rn, o2v[rr][5] * rn),
                                    pk2(o2v[rr][6] * rn, o2v[rr][7] * rn));
  }
}

// ---------------- generic bf16 GEMM: 128x128 tile, BK=64, swizzled (f32 out) ----------------
__global__ __launch_bounds__(256, 2) void gemm_bf16_kernel(const __hip_bfloat16* __restrict__ A,
                                                           const __hip_bfloat16* __restrict__ Bt,
                                                           float* __restrict__ C,
                                                           int M, int N, int K) {
  __shared__ __align__(16) char smem[65536];
  const int tid = threadIdx.x;
  const int lane = tid & 63;
  const int wid = tid >> 6;
  const int wm = wid >> 1, wn = wid & 1;
  const int nwg = gridDim.x;
  const int bid = blockIdx.x;
  const int swz = (bid & 7) * (nwg >> 3) + (bid >> 3);
  const int ntile = N >> 7;
  const int tm = swz / ntile, tn = swz % ntile;
  const int row0 = tm << 7, col0 = tn << 7;
  const int fr = lane & 15, hi = lane >> 4;

  auto STAGE = [&](int buf, int k0) {
#pragma unroll
    for (int i = 0; i < 4; ++i) {
      int f = i * 256 + tid;
      int r = f >> 3, s = f & 7, sx = s ^ (r & 7);
      gload_lds16(A + (size_t)(row0 + r) * K + k0 + sx * 8,
                  smem + buf * 16384 + f * 16);
    }
#pragma unroll
    for (int i = 0; i < 4; ++i) {
      int f = i * 256 + tid;
      int r = f >> 3, s = f & 7, sx = s ^ (r & 7);
      gload_lds16(Bt + (size_t)(col0 + r) * K + k0 + sx * 8,
                  smem + 32768 + buf * 16384 + f * 16);
    }
  };

  f32x4 acc[4][4] = {};
  const int nk = K >> 6;
  STAGE(0, 0);
  int cur = 0;
  for (int kk = 0; kk < nk; ++kk) {
    if (kk > 0) __builtin_amdgcn_s_barrier();
    __builtin_amdgcn_sched_barrier(0);
    if (kk + 1 < nk) STAGE(cur ^ 1, (kk + 1) * 64);
    __builtin_amdgcn_sched_barrier(0);
    if (kk + 1 < nk) asm volatile("s_waitcnt vmcnt(8)" ::: "memory");
    else             asm volatile("s_waitcnt vmcnt(0)" ::: "memory");
    __builtin_amdgcn_s_barrier();
    __builtin_amdgcn_sched_barrier(0);
    const char* Ac = smem + cur * 16384;
    const char* Bc = smem + 32768 + cur * 16384;
#pragma unroll
    for (int kh = 0; kh < 2; ++kh) {
      bf16x8 af[4], bfr[4];
#pragma unroll
      for (int n = 0; n < 4; ++n) {
        int rowb = wn * 64 + n * 16 + fr;
        int sl = (kh * 4 + hi) ^ (rowb & 7);
        bfr[n] = *(const bf16x8*)(Bc + rowb * 128 + sl * 16);
      }
#pragma unroll
      for (int m = 0; m < 4; ++m) {
        int rowa = wm * 64 + m * 16 + fr;
        int sl = (kh * 4 + hi) ^ (rowa & 7);
        af[m] = *(const bf16x8*)(Ac + rowa * 128 + sl * 16);
      }
      __builtin_amdgcn_s_setprio(1);
#pragma unroll
      for (int m = 0; m < 4; ++m)
#pragma unroll
        for (int n = 0; n < 4; ++n)
          acc[m][n] = MFMA_BF16(af[m], bfr[n], acc[m][n]);
      __builtin_amdgcn_s_setprio(0);
    }
    cur ^= 1;
  }

  const int cr = hi * 4;
#pragma unroll
  for (int m = 0; m < 4; ++m)
#pragma unroll
    for (int n = 0; n < 4; ++n) {
      int col = col0 + wn * 64 + n * 16 + fr;
#pragma unroll
      for (int r = 0; r < 4; ++r) {
        int row = row0 + wm * 64 + m * 16 + cr + r;
        C[(size_t)row * N + col] = acc[m][n][r];
      }
    }
}

// block decode (both passes): bi in [0,512): u=bi&255, half=bi>>8. g=u&7 = (b*4+kvh).
// bi and bi+256 (two halves of a balanced 34-step pair) land on the same CU under rr
// dispatch: per-CU balance at 2 blocks/CU.
//
// STATIC-MAX SOFTMAX: no online max tracking (scores bounded by SMAX); P = exp2(s-SMAX),
// l accumulated per-lane, reduced once in the epilogue. Zero cross-lane ops in the loop.
// QK-AHEAD PIPELINE: iter s computes QK(s+1) into sfN while softmax(s)+P+PV(s) run.

// ---------------- attention pass 1: y1 = softmax(qk^T) v ; writes u = mix1*v + mix2*y1 ----------------
__global__ __launch_bounds__(256, 2) void attn_pass1_kernel(
    const __hip_bfloat16* __restrict__ qT,   // (B,H,T,HD), q pre-scaled
    const __hip_bfloat16* __restrict__ kT,   // (B,HK,T,HD)
    const __hip_bfloat16* __restrict__ vt,   // (B,HK,HD,T)
    __hip_bfloat16* __restrict__ y1u,        // (B,H,HD,T)  u = mix1*v + mix2*y1
    float* __restrict__ Lb,                  // (B,H,T)
    const float* __restrict__ mix1p,
    const float* __restrict__ mix2p) {
  __shared__ __align__(16) __hip_bfloat16 Ks[2][64 * 128];
  __shared__ __align__(16) __hip_bfloat16 Vs[2][128 * 64];
  __shared__ __align__(16) char Ps[4][32 * 128];
  const int tid = threadIdx.x, lane = tid & 63, wid = tid >> 6;   // wid 0..3
  const int bi = blockIdx.x;
  const int u = bi & 255, half = bi >> 8;
  const int g = u & 7;
  const int pslot = (u >> 3) & 7;
  const int bh = g * 4 + (u >> 6);
  const int j = half ? (15 - pslot) : pslot;
  const int q0 = j * 128;
  const int nt = 2 * j + 2;                  // even
  const int sd = 2 * j + (wid >> 1);
  const __hip_bfloat16* Kp = kT + (size_t)g * 2048 * 128;
  const __hip_bfloat16* Vp = vt + (size_t)g * 128 * 2048;
  const int fr = lane & 15, hi = lane >> 4;

  bf16x8 qf[2][4];
  {
    const __hip_bfloat16* Qp = qT + ((size_t)bh * 2048 + q0 + wid * 32) * 128;
#pragma unroll
    for (int rr = 0; rr < 2; ++rr)
#pragma unroll
      for (int dc = 0; dc < 4; ++dc)
        qf[rr][dc] = *(const bf16x8*)(Qp + (rr * 16 + fr) * 128 + dc * 32 + hi * 8);
  }

  f32x4 accO[2][8] = {};
  float l[2] = {0.f, 0.f};                   // per-lane partial denominators

  char* Pb = Ps[wid];

  auto STAGE_K = [&](int buf, int kt) {
    const int k0 = kt * 64;
#pragma unroll
    for (int i = 0; i < 4; ++i) {
      int f = i * 256 + tid;
      int r = f >> 4, s = f & 15, sx = s ^ (r & 7);
      gload_lds16(Kp + (size_t)(k0 + r) * 128 + sx * 8,
                  (char*)Ks[buf] + (i * 256 + wid * 64) * 16);
    }
  };
  auto STAGE_V = [&](int buf, int kt) {
    const int k0 = kt * 64;
#pragma unroll
    for (int i = 0; i < 4; ++i) {
      int f = i * 256 + tid;
      int r = f >> 3, s = f & 7, sx = s ^ (r & 7);
      gload_lds16(Vp + (size_t)r * 2048 + k0 + sx * 8,
                  (char*)Vs[buf] + (i * 256 + wid * 64) * 16);
    }
  };

  auto QK = [&](int t, f32x4 (&sf)[2][4]) {
    const char* Kc = (const char*)Ks[t & 1];
#pragma unroll
    for (int rr = 0; rr < 2; ++rr)
#pragma unroll
      for (int c = 0; c < 4; ++c) sf[rr][c] = (f32x4){0.f, 0.f, 0.f, 0.f};
    __builtin_amdgcn_s_setprio(1);
#pragma unroll
    for (int c = 0; c < 4; ++c) {
      const int krow = c * 16 + fr;
#pragma unroll
      for (int dc = 0; dc < 4; ++dc) {
        int slot = (dc * 4 + hi) ^ (krow & 7);
        bf16x8 kf = *(const bf16x8*)(Kc + krow * 256 + slot * 16);
        sf[0][c] = MFMA_BF16(kf, qf[0][dc], sf[0][c]);
        sf[1][c] = MFMA_BF16(kf, qf[1][dc], sf[1][c]);
      }
    }
    __builtin_amdgcn_s_setprio(0);
  };

  auto STEP = [&](int s, f32x4 (&sfC)[2][4], f32x4 (&sfN)[2][4]) {
    __builtin_amdgcn_s_barrier();
    __builtin_amdgcn_sched_barrier(0);
    if (s + 2 < nt) STAGE_K(s & 1, s + 2);
    if (s + 1 < nt) STAGE_V((s + 1) & 1, s + 1);
    __builtin_amdgcn_sched_barrier(0);
    if (s + 2 < nt)      asm volatile("s_waitcnt vmcnt(8)" ::: "memory");
    else if (s + 1 < nt) asm volatile("s_waitcnt vmcnt(4)" ::: "memory");
    else                 asm volatile("s_waitcnt vmcnt(0)" ::: "memory");
    __builtin_amdgcn_s_barrier();
    __builtin_amdgcn_sched_barrier(0);

    if (s + 1 <= sd) QK(s + 1, sfN);

    if (s <= sd) {
      // ---- mask (diagonal only) + static-max exp2 + per-lane partial sum ----
      if (s == sd) {
#pragma unroll
        for (int rr = 0; rr < 2; ++rr) {
          const int qq = q0 + wid * 32 + rr * 16 + fr;
#pragma unroll
          for (int c = 0; c < 4; ++c) {
            const int kb = s * 64 + c * 16 + hi * 4;
#pragma unroll
            for (int r = 0; r < 4; ++r)
              if (kb + r > qq) sfC[rr][c][r] = -1e30f;
          }
        }
      }
#pragma unroll
      for (int rr = 0; rr < 2; ++rr) {
        float rs = 0.f;
#pragma unroll
        for (int c = 0; c < 4; ++c)
#pragma unroll
          for (int r = 0; r < 4; ++r) {
            float p = __builtin_amdgcn_exp2f(sfC[rr][c][r] - SMAX);
            sfC[rr][c][r] = p;
            rs += p;
          }
        l[rr] += rs;
      }
      // ---- P -> LDS (packed b64, swizzled) + A-frag readback ----
#pragma unroll
      for (int rr = 0; rr < 2; ++rr) {
        const int row = rr * 16 + fr;
        char* Prow = Pb + row * 128;
#pragma unroll
        for (int c = 0; c < 4; ++c) {
          uint32_t w0 = pk2(sfC[rr][c][0], sfC[rr][c][1]);
          uint32_t w1 = pk2(sfC[rr][c][2], sfC[rr][c][3]);
          int sl = (c * 2 + (hi >> 1)) ^ (row & 7);
          *(uint2*)(Prow + sl * 16 + (hi & 1) * 8) = make_uint2(w0, w1);
        }
      }
      bf16x8 pf[2][2];
#pragma unroll
      for (int rr = 0; rr < 2; ++rr) {
        const int row = rr * 16 + fr;
#pragma unroll
        for (int kc = 0; kc < 2; ++kc) {
          int sl = (kc * 4 + hi) ^ (row & 7);
          pf[rr][kc] = *(const bf16x8*)(Pb + row * 128 + sl * 16);
        }
      }
      // ---- PV from Vs[s&1] ----
      const __hip_bfloat16* Vc = Vs[s & 1];
      __builtin_amdgcn_s_setprio(1);
#pragma unroll
      for (int kc = 0; kc < 2; ++kc)
#pragma unroll
        for (int f = 0; f < 8; ++f) {
          int vrow = f * 16 + fr;
          int vslot = (kc * 4 + hi) ^ (fr & 7);
          bf16x8 vf = *(const bf16x8*)(Vc + vrow * 64 + vslot * 8);
          accO[0][f] = MFMA_BF16(pf[0][kc], vf, accO[0][f]);
          accO[1][f] = MFMA_BF16(pf[1][kc], vf, accO[1][f]);
        }
      __builtin_amdgcn_s_setprio(0);
    }
  };

  // prologue: K0, V0, K1 staged; QK(0)
  f32x4 sfA[2][4], sfB[2][4];
  STAGE_K(0, 0);
  STAGE_V(0, 0);
  STAGE_K(1, 1);
  asm volatile("s_waitcnt vmcnt(8)" ::: "memory");
  __builtin_amdgcn_s_barrier();
  __builtin_amdgcn_sched_barrier(0);
  QK(0, sfA);

  for (int s2 = 0; s2 < nt; s2 += 2) {
    STEP(s2, sfA, sfB);
    STEP(s2 + 1, sfB, sfA);
  }

  // ---- epilogue: reduce per-lane l once; u = mix1*v + mix2*(accO/l); store l ----
  float lsum[2];
#pragma unroll
  for (int rr = 0; rr < 2; ++rr) {
    float v = l[rr];
    v += __shfl_xor(v, 16);
    v += __shfl_xor(v, 32);
    lsum[rr] = v;
  }
  const float m1v = mix1p[0], m2v = mix2p[0];
  float rlq[2][4];
#pragma unroll
  for (int rr = 0; rr < 2; ++rr) {
    float inv = 1.f / lsum[rr];
#pragma unroll
    for (int r = 0; r < 4; ++r) rlq[rr][r] = __shfl(inv, hi * 4 + r);
  }
  const int t0 = q0 + wid * 32;
#pragma unroll
  for (int rr = 0; rr < 2; ++rr) {
    const int tb = t0 + rr * 16 + hi * 4;
#pragma unroll
    for (int f = 0; f < 8; ++f) {
      const int d = f * 16 + fr;
      const ushort4 v4 = *(const ushort4*)(vt + ((size_t)g * 128 + d) * 2048 + tb);
      float u0 = m1v * b2f(v4.x) + m2v * (accO[rr][f][0] * rlq[rr][0]);
      float u1 = m1v * b2f(v4.y) + m2v * (accO[rr][f][1] * rlq[rr][1]);
      float u2 = m1v * b2f(v4.z) + m2v * (accO[rr][f][2] * rlq[rr][2]);
      float u3 = m1v * b2f(v4.w) + m2v * (accO[rr][f][3] * rlq[rr][3]);
      *(uint2*)(y1u + ((size_t)bh * 128 + d) * 2048 + tb) =
          make_uint2(pk2(u0, u1), pk2(u2, u3));
    }
  }
  if (hi == 0) {
#pragma unroll
    for (int rr = 0; rr < 2; ++rr)
      Lb[(size_t)bh * 2048 + t0 + rr * 16 + fr] = lsum[rr];
  }
}

// ---------------- attention pass 2: ymix = att @ u  (direct final output) ----------------
__global__ __launch_bounds__(256, 2) void attn_pass2_kernel(
    const __hip_bfloat16* __restrict__ qT,
    const __hip_bfloat16* __restrict__ kT,
    const __hip_bfloat16* __restrict__ y1u,  // (B,H,HD,T)
    const float* __restrict__ Lb,
    __hip_bfloat16* __restrict__ ymix) {     // (B,T,C)
  __shared__ __align__(16) __hip_bfloat16 Ks[2][64 * 128];
  __shared__ __align__(16) __hip_bfloat16 Vs[2][128 * 64];
  __shared__ __align__(16) char Ps[4][32 * 128];
  const int tid = threadIdx.x, lane = tid & 63, wid = tid >> 6;
  const int bi = blockIdx.x;
  const int u = bi & 255, half = bi >> 8;
  const int g = u & 7;
  const int pslot = (u >> 3) & 7;
  const int bh = g * 4 + (u >> 6);
  const int h = bh & 15, b = bh >> 4;
  const int j = half ? (15 - pslot) : pslot;
  const int q0 = j * 128;
  const int nt = 2 * j + 2;
  const int sd = 2 * j + (wid >> 1);
  const __hip_bfloat16* Kp = kT + (size_t)g * 2048 * 128;
  const __hip_bfloat16* Yp = y1u + (size_t)bh * 128 * 2048;
  const int fr = lane & 15, hi = lane >> 4;

  bf16x8 qf[2][4];
  float rl[2];
  {
    const __hip_bfloat16* Qp = qT + ((size_t)bh * 2048 + q0 + wid * 32) * 128;
#pragma unroll
    for (int rr = 0; rr < 2; ++rr)
#pragma unroll
      for (int dc = 0; dc < 4; ++dc)
        qf[rr][dc] = *(const bf16x8*)(Qp + (rr * 16 + fr) * 128 + dc * 32 + hi * 8);
    const size_t qb = (size_t)bh * 2048 + q0 + wid * 32;
    rl[0] = 1.f / Lb[qb + fr];
    rl[1] = 1.f / Lb[qb + 16 + fr];
  }

  f32x4 accO[2][8] = {};
  char* Pb = Ps[wid];

  auto STAGE_K = [&](int buf, int kt) {
    const int k0 = kt * 64;
#pragma unroll
    for (int i = 0; i < 4; ++i) {
      int f = i * 256 + tid;
      int r = f >> 4, s = f & 15, sx = s ^ (r & 7);
      gload_lds16(Kp + (size_t)(k0 + r) * 128 + sx * 8,
                  (char*)Ks[buf] + (i * 256 + wid * 64) * 16);
    }
  };
  auto STAGE_V = [&](int buf, int kt) {
    const int k0 = kt * 64;
#pragma unroll
    for (int i = 0; i < 4; ++i) {
      int f = i * 256 + tid;
      int r = f >> 3, s = f & 7, sx = s ^ (r & 7);
      gload_lds16(Yp + (size_t)r * 2048 + k0 + sx * 8,
                  (char*)Vs[buf] + (i * 256 + wid * 64) * 16);
    }
  };

  auto QK = [&](int t, f32x4 (&sf)[2][4]) {
    const char* Kc = (const char*)Ks[t & 1];
#pragma unroll
    for (int rr = 0; rr < 2; ++rr)
#pragma unroll
      for (int c = 0; c < 4; ++c) sf[rr][c] = (f32x4){0.f, 0.f, 0.f, 0.f};
    __builtin_amdgcn_s_setprio(1);
#pragma unroll
    for (int c = 0; c < 4; ++c) {
      const int krow = c * 16 + fr;
#pragma unroll
      for (int dc = 0; dc < 4; ++dc) {
        int slot = (dc * 4 + hi) ^ (krow & 7);
        bf16x8 kf = *(const bf16x8*)(Kc + krow * 256 + slot * 16);
        sf[0][c] = MFMA_BF16(kf, qf[0][dc], sf[0][c]);
        sf[1][c] = MFMA_BF16(kf, qf[1][dc], sf[1][c]);
      }
    }
    __builtin_amdgcn_s_setprio(0);
  };

  auto STEP = [&](int s, f32x4 (&sfC)[2][4], f32x4 (&sfN)[2][4]) {
    __builtin_amdgcn_s_barrier();
    __builtin_amdgcn_sched_barrier(0);
    if (s + 2 < nt) STAGE_K(s & 1, s + 2);
    if (s + 1 < nt) STAGE_V((s + 1) & 1, s + 1);
    __builtin_amdgcn_sched_barrier(0);
    if (s + 2 < nt)      asm volatile("s_waitcnt vmcnt(8)" ::: "memory");
    else if (s + 1 < nt) asm volatile("s_waitcnt vmcnt(4)" ::: "memory");
    else                 asm volatile("s_waitcnt vmcnt(0)" ::: "memory");
    __builtin_amdgcn_s_barrier();
    __builtin_amdgcn_sched_barrier(0);

    if (s + 1 <= sd) QK(s + 1, sfN);

    if (s <= sd) {
      // normalize P with static max + stored denominator (no shuffles)
      if (s == sd) {
#pragma unroll
        for (int rr = 0; rr < 2; ++rr) {
          const int qq = q0 + wid * 32 + rr * 16 + fr;
#pragma unroll
          for (int c = 0; c < 4; ++c) {
            const int kb = s * 64 + c * 16 + hi * 4;
#pragma unroll
            for (int r = 0; r < 4; ++r)
              if (kb + r > qq) sfC[rr][c][r] = -1e30f;
          }
        }
      }
#pragma unroll
      for (int rr = 0; rr < 2; ++rr)
#pragma unroll
        for (int c = 0; c < 4; ++c)
#pragma unroll
          for (int r = 0; r < 4; ++r)
            sfC[rr][c][r] = __builtin_amdgcn_exp2f(sfC[rr][c][r] - SMAX) * rl[rr];
#pragma unroll
      for (int rr = 0; rr < 2; ++rr) {
        const int row = rr * 16 + fr;
        char* Prow = Pb + row * 128;
#pragma unroll
        for (int c = 0; c < 4; ++c) {
          uint32_t w0 = pk2(sfC[rr][c][0], sfC[rr][c][1]);
          uint32_t w1 = pk2(sfC[rr][c][2], sfC[rr][c][3]);
          int sl = (c * 2 + (hi >> 1)) ^ (row & 7);
          *(uint2*)(Prow + sl * 16 + (hi & 1) * 8) = make_uint2(w0, w1);
        }
      }
      bf16x8 pf[2][2];
#pragma unroll
      for (int rr = 0; rr < 2; ++rr) {
        const int row = rr * 16 + fr;
#pragma unroll
        for (int kc = 0; kc < 2; ++kc) {
          int sl = (kc * 4 + hi) ^ (row & 7);
          pf[rr][kc] = *(const bf16x8*)(Pb + row * 128 + sl * 16);
        }
      }
      const __hip_bfloat16* Vc = Vs[s & 1];
      __builtin_amdgcn_s_setprio(1);
#pragma unroll
      for (int kc = 0; kc < 2; ++kc)
#pragma unroll
        for (int f = 0; f < 8; ++f) {
          int vrow = f * 16 + fr;
          int vslot = (kc * 4 + hi) ^ (fr & 7);
          bf16x8 vf = *(const bf16x8*)(Vc + vrow * 64 + vslot * 8);
          accO[0][f] = MFMA_BF16(pf[0][kc], vf, accO[0][f]);
          accO[1][f] = MFMA_BF16(pf[1][kc], vf, accO[1][f]);
        }
      __builtin_amdgcn_s_setprio(0);
    }
  };

  f32x4 sfA[2][4], sfB[2][4];
  STAGE_K(0, 0);
  STAGE_V(0, 0);
  STAGE_K(1, 1);
  asm volatile("s_waitcnt vmcnt(8)" ::: "memory");
  __builtin_amdgcn_s_barrier();
  __builtin_amdgcn_sched_barrier(0);
  QK(0, sfA);

  for (int s2 = 0; s2 < nt; s2 += 2) {
    STEP(s2, sfA, sfB);
    STEP(s2 + 1, sfB, sfA);
  }

  // accO already IS the final mixed output (P pre-normalized, u pre-mixed)
#pragma unroll
  for (int rr = 0; rr < 2; ++rr) {
#pragma unroll
    for (int f = 0; f < 8; ++f) {
      const int d = f * 16 + fr;
#pragma unroll
      for (int r = 0; r < 4; ++r) {
        int q = q0 + wid * 32 + rr * 16 + hi * 4 + r;
        ymix[((size_t)b * 2048 + q) * 2048 + h * 128 + d] = __float2bfloat16(accO[rr][f][r]);
      }
    }
  }
}

// ---------------- launch ----------------
extern "C" void kernel_launch(void* const* d_in, const int* in_sizes, int n_in,
                              void* d_out, int out_size, void* d_ws, size_t ws_size,
                              hipStream_t stream) {
  const float* x    = (const float*)d_in[0];
  const float* cosb = (const float*)d_in[1];
  const float* sinb = (const float*)d_in[2];
  const float* Wq   = (const float*)d_in[3];
  const float* Wk   = (const float*)d_in[4];
  const float* Wv   = (const float*)d_in[5];
  const float* Wp   = (const float*)d_in[6];
  const float* mix1 = (const float*)d_in[7];
  const float* mix2 = (const float*)d_in[8];
  float* out = (float*)d_out;
  char* ws = (char*)d_ws;

  // workspace layout (bytes), peak ~80 MB
  __hip_bfloat16* xb   = (__hip_bfloat16*)(ws + 0);            // 16.78 MB; reused as ymix
  __hip_bfloat16* WTa  = (__hip_bfloat16*)(ws + 16777216);     // 12.58 MB
  __hip_bfloat16* WpT  = (__hip_bfloat16*)(ws + 29360128);     // 8.39 MB
  __hip_bfloat16* y1u  = (__hip_bfloat16*)(ws + 37748736);     // 16.78 MB
  float*          Lb   = (float*)(ws + 54525952);              // 0.26 MB
  __hip_bfloat16* qTb  = (__hip_bfloat16*)(ws + 55050240);     // 16.78 MB
  __hip_bfloat16* kTb  = (__hip_bfloat16*)(ws + 71827456);     // 4.19 MB
  __hip_bfloat16* vtb  = (__hip_bfloat16*)(ws + 76021760);     // 4.19 MB
  __hip_bfloat16* ymix = (__hip_bfloat16*)(ws + 0);

  dim3 tb(32, 8);
  prep_kernel<<<18432, tb, 0, stream>>>(x, xb, Wq, Wk, Wv, Wp, WTa, WpT);

  // fused QKV projection + RoPE + RMS + V-transpose (128x128 tiles, BK=64, 768 blocks)
  gemm_qkv_rope_kernel<<<768, 256, 0, stream>>>(xb, WTa, cosb, sinb, qTb, kTb, vtb);

  attn_pass1_kernel<<<512, 256, 0, stream>>>(qTb, kTb, vtb, y1u, Lb, mix1, mix2);
  attn_pass2_kernel<<<512, 256, 0, stream>>>(qTb, kTb, y1u, Lb, ymix);

  gemm_bf16_kernel<<<512, 256, 0, stream>>>(ymix, WpT, out, 4096, 2048, 2048);
}